// Round 8
// baseline (2402.574 us; speedup 1.0000x reference)
//
#include <hip/hip_runtime.h>
#include <hip/hip_bf16.h>
#include <math.h>

// Problem constants (fixed by reference)
#define N_   65536
#define F_   64
#define H_   128
#define E_   30000
#define NT_  5
#define ET_  10
#define NG_  50
#define L_   3
#define TL_  2
#define NH_  4
#define DH_  32
#define NB_  1024
#define TT_  64
#define FF_  512
#define CH_  512         // temporal node chunk
#define GATTN_GRID 544

#define SCALE_ 0.17677669529663687f   // 1/sqrt(32)

__device__ __forceinline__ float gelu_exact(float x) {
    return 0.5f * x * (1.0f + erff(x * 0.70710678118654752f));
}
__device__ __forceinline__ void f4fma(float4& a, float s, const float4& b) {
    a.x += s * b.x; a.y += s * b.y; a.z += s * b.z; a.w += s * b.w;
}
__device__ __forceinline__ void f4scale(float4& a, float s) {
    a.x *= s; a.y *= s; a.z *= s; a.w *= s;
}
__device__ __forceinline__ float4 f4zero() { return make_float4(0.f, 0.f, 0.f, 0.f); }

// ---------------- grouping ----------------

__global__ void k_zero_cnt(int* cnt) {
    if (threadIdx.x < NG_) cnt[threadIdx.x] = 0;
}

__global__ void k_hist(const int* __restrict__ edge_index, const int* __restrict__ edge_type,
                       const int* __restrict__ node_type, int* __restrict__ gedge, int* __restrict__ cnt) {
    int e = blockIdx.x * blockDim.x + threadIdx.x;
    if (e >= E_) return;
    int dn = edge_index[E_ + e];
    int g = edge_type[e] * NT_ + node_type[dn];
    gedge[e] = g;
    atomicAdd(&cnt[g], 1);
}

__global__ void k_scan(const int* __restrict__ cnt, int* __restrict__ offs, int* __restrict__ curs) {
    if (threadIdx.x == 0 && blockIdx.x == 0) {
        int acc = 0;
        for (int g = 0; g < NG_; ++g) { offs[g] = acc; curs[g] = acc; acc += cnt[g]; }
        offs[NG_] = acc;
    }
}

__global__ void k_scatter(const int* __restrict__ gedge, int* __restrict__ curs,
                          int* __restrict__ sorted, int* __restrict__ gpos) {
    int e = blockIdx.x * blockDim.x + threadIdx.x;
    if (e >= E_) return;
    int g = gedge[e];
    int pos = atomicAdd(&curs[g], 1);
    sorted[pos] = e;
    gpos[pos] = g;
}

// descriptor lists: 64-edge tiles (qkv gemm + attention)
__global__ void k_desc(const int* __restrict__ offs, int2* __restrict__ desc64, int* __restrict__ nd64) {
    if (threadIdx.x || blockIdx.x) return;
    int n64 = 0;
    for (int g = 0; g < NG_; ++g) {
        int sz = offs[g + 1] - offs[g];
        for (int qs = 0; qs < sz; qs += 64) desc64[n64++] = make_int2(g, qs);
    }
    nd64[0] = n64;
}

// ---------------- input projection ----------------

__global__ void k_inproj(const float* __restrict__ x, const int* __restrict__ node_type,
                         const float* __restrict__ W_in, const float* __restrict__ b_in,
                         float* __restrict__ h) {
    int n = blockIdx.x;
    int j = threadIdx.x;  // 0..127
    __shared__ float sx[F_];
    if (j < F_) sx[j] = x[(size_t)n * F_ + j];
    __syncthreads();
    int nt = node_type[n];
    const float* W = W_in + (size_t)nt * F_ * H_;
    float acc = b_in[(size_t)nt * H_ + j];
    #pragma unroll 8
    for (int f = 0; f < F_; ++f) acc += sx[f] * W[(size_t)f * H_ + j];
    h[(size_t)n * H_ + j] = acc;
}

__global__ void k_zero(float* __restrict__ p, int n) {
    int i = blockIdx.x * blockDim.x + threadIdx.x;
    int stride = gridDim.x * blockDim.x;
    for (; i < n; i += stride) p[i] = 0.0f;
}

// ---------------- spatial qkv projection: tiled GEMM over 64-edge tiles ----------------
// grid = (544, 3); y: 0=q (dst rows), 1=k, 2=v (src rows)

__global__ __launch_bounds__(256) void k_sqkv_gemm(
    const float* __restrict__ h, const float* __restrict__ s_in_w, const float* __restrict__ s_in_b,
    const int* __restrict__ sorted, const int* __restrict__ offs, const int* __restrict__ edge_index,
    const int2* __restrict__ desc64, const int* __restrict__ nd64,
    float* __restrict__ qkv, int li) {
    int bx = blockIdx.x;
    if (bx >= nd64[0]) return;
    int2 dd = desc64[bx];
    int g = dd.x, qs = dd.y;
    int qbase = offs[g] + qs;
    int qcnt = min(64, offs[g + 1] - qbase);
    int et = g / NT_;
    int nt = blockIdx.y;
    __shared__ float s_a[64 * 132];
    __shared__ float s_b[32 * 132];
    int tid = threadIdx.x;
    // gather 64 input rows (dst for q, src for k/v)
    #pragma unroll
    for (int i = 0; i < 8; ++i) {
        int idx = i * 256 + tid;
        int r = idx >> 5, c4 = (idx & 31) * 4;
        int p = qbase + min(r, qcnt - 1);
        int e = sorted[p];
        int node = (nt == 0) ? edge_index[E_ + e] : edge_index[e];
        *reinterpret_cast<float4*>(&s_a[r * 132 + c4]) =
            *reinterpret_cast<const float4*>(&h[(size_t)node * H_ + c4]);
    }
    const float* B = s_in_w + ((size_t)(li * ET_ + et) * 3 * H_ + nt * H_) * H_;
    const float* bi = s_in_b + (size_t)(li * ET_ + et) * 3 * H_ + nt * H_;
    int rg = tid >> 4, cg = tid & 15;
    int r0 = rg * 4;
    float4 alo[4], ahi[4];
    #pragma unroll
    for (int rr = 0; rr < 4; ++rr) { alo[rr] = f4zero(); ahi[rr] = f4zero(); }
    for (int kci = 0; kci < 4; ++kci) {
        __syncthreads();
        #pragma unroll
        for (int i = 0; i < 4; ++i) {
            int idx = i * 256 + tid;
            int jj = idx >> 3, k4 = (idx & 7) * 4;
            float4 w = *reinterpret_cast<const float4*>(&B[(size_t)jj * H_ + kci * 32 + k4]);
            s_b[(k4 + 0) * 132 + jj] = w.x; s_b[(k4 + 1) * 132 + jj] = w.y;
            s_b[(k4 + 2) * 132 + jj] = w.z; s_b[(k4 + 3) * 132 + jj] = w.w;
        }
        __syncthreads();
        #pragma unroll
        for (int k4 = 0; k4 < 8; ++k4) {
            float4 a4[4];
            #pragma unroll
            for (int rr = 0; rr < 4; ++rr)
                a4[rr] = *reinterpret_cast<const float4*>(&s_a[(r0 + rr) * 132 + kci * 32 + k4 * 4]);
            #pragma unroll
            for (int jj = 0; jj < 4; ++jj) {
                float4 blo = *reinterpret_cast<const float4*>(&s_b[(k4 * 4 + jj) * 132 + cg * 4]);
                float4 bhi = *reinterpret_cast<const float4*>(&s_b[(k4 * 4 + jj) * 132 + 64 + cg * 4]);
                #pragma unroll
                for (int rr = 0; rr < 4; ++rr) {
                    float av = (jj == 0) ? a4[rr].x : (jj == 1) ? a4[rr].y : (jj == 2) ? a4[rr].z : a4[rr].w;
                    f4fma(alo[rr], av, blo);
                    f4fma(ahi[rr], av, bhi);
                }
            }
        }
    }
    float4 blo = *reinterpret_cast<const float4*>(&bi[cg * 4]);
    float4 bhi = *reinterpret_cast<const float4*>(&bi[64 + cg * 4]);
    #pragma unroll
    for (int rr = 0; rr < 4; ++rr) {
        int row = r0 + rr;
        if (row < qcnt) {
            float* op = qkv + (size_t)(qbase + row) * 384 + nt * H_;
            float4 lo = alo[rr], hi = ahi[rr];
            lo.x += blo.x; lo.y += blo.y; lo.z += blo.z; lo.w += blo.w;
            hi.x += bhi.x; hi.y += bhi.y; hi.z += bhi.z; hi.w += bhi.w;
            *reinterpret_cast<float4*>(op + cg * 4) = lo;
            *reinterpret_cast<float4*>(op + 64 + cg * 4) = hi;
        }
    }
}

// ---------------- grouped spatial attention + out-proj + scatter ----------------
// block = one (group, 64-query tile); 512 threads = 2 half-blocks (even/odd k-tiles)
// x 4 heads x 64 queries. Private online-softmax per half, LDS merge at the end.

__global__ __launch_bounds__(512, 2) void k_gattn(
    const float* __restrict__ qkv, const int* __restrict__ sorted,
    const int* __restrict__ offs, const int* __restrict__ edge_index,
    const int2* __restrict__ desc, const int* __restrict__ ndesc,
    const float* __restrict__ s_out_w, const float* __restrict__ s_out_b,
    float* __restrict__ h_new, int li) {
    int bx = blockIdx.x;
    if (bx >= ndesc[0]) return;
    int2 dd = desc[bx];
    int g = dd.x, qs = dd.y;
    int start = offs[g], end = offs[g + 1];
    int qbase = start + qs;
    int qcnt = min(64, end - qbase);
    int et = g / NT_;

    __shared__ float s_kv[4 * 32 * 128];   // kA, vA, kB, vB (64 KB)
    __shared__ float s_ms[2 * 256];        // merge m, ssum from half 0
    __shared__ int s_dn[64];
    float* s_mrg = s_kv;                   // [32 cols][256 threads] transposed merge buf (aliases kA,vA)
    float* s_o   = s_kv + 2 * 32 * 128;    // [64][128] (aliases kB,vB)

    int tid = threadIdx.x;
    int half = tid >> 8;                   // 0/1: even/odd k-tiles
    int htid = tid & 255;
    int head = htid >> 6;
    int qi = htid & 63;

    if (tid < 64) s_dn[tid] = edge_index[E_ + sorted[qbase + min(tid, qcnt - 1)]];

    int p0 = qbase + min(qi, qcnt - 1);
    float4 q[8];
    {
        const float4* qr = reinterpret_cast<const float4*>(&qkv[(size_t)p0 * 384 + head * DH_]);
        #pragma unroll
        for (int i = 0; i < 8; ++i) q[i] = qr[i];
    }
    float m = -1e30f, ssum = 0.0f;
    float4 o[8];
    #pragma unroll
    for (int i = 0; i < 8; ++i) o[i] = f4zero();

    float* s_k = s_kv + half * (2 * 32 * 128);
    float* s_v = s_k + 32 * 128;

    int nkt = (end - start + 31) >> 5;
    int nit = (nkt + 1) >> 1;
    for (int it = 0; it < nit; ++it) {
        int kt = 2 * it + half;
        int kb = start + kt * 32;
        int kcnt = min(32, end - kb);
        __syncthreads();
        if (kt < nkt) {
            // stage this half's k,v tile: 32 rows x 256 floats = 2048 float4, 8/thread
            #pragma unroll
            for (int i = 0; i < 8; ++i) {
                int idx = i * 256 + htid;
                int row = idx >> 6, c4 = idx & 63;
                if (row < kcnt) {
                    float4 w = *reinterpret_cast<const float4*>(&qkv[(size_t)(kb + row) * 384 + 128 + c4 * 4]);
                    int c = c4 * 4;
                    float* dp = (c < 128) ? &s_k[row * 128 + c] : &s_v[row * 128 + (c - 128)];
                    *reinterpret_cast<float4*>(dp) = w;
                }
            }
        }
        __syncthreads();
        if (kt >= nkt) continue;
        if (kcnt == 32) {
            // single pass: scores in statically-indexed registers
            float sc[32];
            float tmax = -1e30f;
            #pragma unroll
            for (int t2 = 0; t2 < 32; ++t2) {
                const float4* kr = reinterpret_cast<const float4*>(&s_k[t2 * 128 + head * DH_]);
                float s0 = 0, s1 = 0, s2 = 0, s3 = 0;
                #pragma unroll
                for (int i = 0; i < 8; ++i) {
                    float4 kk = kr[i];
                    s0 += q[i].x * kk.x; s1 += q[i].y * kk.y; s2 += q[i].z * kk.z; s3 += q[i].w * kk.w;
                }
                float dot = ((s0 + s1) + (s2 + s3)) * SCALE_;
                sc[t2] = dot;
                tmax = fmaxf(tmax, dot);
            }
            float mn = fmaxf(m, tmax);
            float f = __expf(m - mn);
            ssum *= f;
            #pragma unroll
            for (int i = 0; i < 8; ++i) f4scale(o[i], f);
            #pragma unroll
            for (int t2 = 0; t2 < 32; ++t2) {
                float p = __expf(sc[t2] - mn);
                ssum += p;
                const float4* vr = reinterpret_cast<const float4*>(&s_v[t2 * 128 + head * DH_]);
                #pragma unroll
                for (int i = 0; i < 8; ++i) f4fma(o[i], p, vr[i]);
            }
            m = mn;
        } else {
            // tail: two-pass recompute
            float tmax = -1e30f;
            for (int t2 = 0; t2 < kcnt; ++t2) {
                const float4* kr = reinterpret_cast<const float4*>(&s_k[t2 * 128 + head * DH_]);
                float s0 = 0, s1 = 0, s2 = 0, s3 = 0;
                #pragma unroll
                for (int i = 0; i < 8; ++i) {
                    float4 kk = kr[i];
                    s0 += q[i].x * kk.x; s1 += q[i].y * kk.y; s2 += q[i].z * kk.z; s3 += q[i].w * kk.w;
                }
                tmax = fmaxf(tmax, ((s0 + s1) + (s2 + s3)) * SCALE_);
            }
            float mn = fmaxf(m, tmax);
            float f = __expf(m - mn);
            ssum *= f;
            #pragma unroll
            for (int i = 0; i < 8; ++i) f4scale(o[i], f);
            for (int t2 = 0; t2 < kcnt; ++t2) {
                const float4* kr = reinterpret_cast<const float4*>(&s_k[t2 * 128 + head * DH_]);
                float s0 = 0, s1 = 0, s2 = 0, s3 = 0;
                #pragma unroll
                for (int i = 0; i < 8; ++i) {
                    float4 kk = kr[i];
                    s0 += q[i].x * kk.x; s1 += q[i].y * kk.y; s2 += q[i].z * kk.z; s3 += q[i].w * kk.w;
                }
                float p = __expf(((s0 + s1) + (s2 + s3)) * SCALE_ - mn);
                ssum += p;
                const float4* vr = reinterpret_cast<const float4*>(&s_v[t2 * 128 + head * DH_]);
                #pragma unroll
                for (int i = 0; i < 8; ++i) f4fma(o[i], p, vr[i]);
            }
            m = mn;
        }
    }
    __syncthreads();   // all k/v reads done; buffers reusable
    // half 0 publishes its state (transposed layout: col*256 + htid, conflict-free)
    if (half == 0) {
        s_ms[htid] = m;
        s_ms[256 + htid] = ssum;
        #pragma unroll
        for (int i = 0; i < 8; ++i) {
            s_mrg[(i * 4 + 0) * 256 + htid] = o[i].x;
            s_mrg[(i * 4 + 1) * 256 + htid] = o[i].y;
            s_mrg[(i * 4 + 2) * 256 + htid] = o[i].z;
            s_mrg[(i * 4 + 3) * 256 + htid] = o[i].w;
        }
    }
    __syncthreads();
    // half 1 merges and writes normalized output to s_o
    if (half == 1 && qi < qcnt) {
        float mA = s_ms[htid], sA = s_ms[256 + htid];
        float mm = fmaxf(mA, m);
        float fA = __expf(mA - mm), fB = __expf(m - mm);
        float inv = 1.0f / (sA * fA + ssum * fB);
        #pragma unroll
        for (int i = 0; i < 8; ++i) {
            float4 t;
            t.x = (s_mrg[(i * 4 + 0) * 256 + htid] * fA + o[i].x * fB) * inv;
            t.y = (s_mrg[(i * 4 + 1) * 256 + htid] * fA + o[i].y * fB) * inv;
            t.z = (s_mrg[(i * 4 + 2) * 256 + htid] * fA + o[i].z * fB) * inv;
            t.w = (s_mrg[(i * 4 + 3) * 256 + htid] * fA + o[i].w * fB) * inv;
            *reinterpret_cast<float4*>(&s_o[qi * 128 + head * DH_ + i * 4]) = t;
        }
    }
    __syncthreads();
    // out-projection: thread = (col j, query-quarter); 16 queries per thread
    {
        int j = tid & 127, qtr = tid >> 7;   // 0..3
        const float* Wo = s_out_w + ((size_t)(li * ET_ + et) * H_ + j) * H_;
        float bo = s_out_b[(size_t)(li * ET_ + et) * H_ + j];
        float acc[16];
        #pragma unroll
        for (int qq = 0; qq < 16; ++qq) acc[qq] = bo;
        #pragma unroll 8
        for (int k4 = 0; k4 < 32; ++k4) {
            float4 w = *reinterpret_cast<const float4*>(&Wo[k4 * 4]);
            #pragma unroll
            for (int qq = 0; qq < 16; ++qq) {
                float4 ov = *reinterpret_cast<const float4*>(&s_o[(qtr * 16 + qq) * 128 + k4 * 4]);
                acc[qq] += w.x * ov.x + w.y * ov.y + w.z * ov.z + w.w * ov.w;
            }
        }
        #pragma unroll
        for (int qq = 0; qq < 16; ++qq) {
            int qrow = qtr * 16 + qq;
            if (qrow < qcnt) {
                atomicAdd(&h_new[(size_t)s_dn[qrow] * H_ + j], acc[qq]);
            }
        }
    }
}

// ---------------- LN + exact GELU + residual (spatial); re-zeroes h_new for next layer ----------------

__global__ void k_lngelu(float* __restrict__ h_new, float* __restrict__ h,
                         const float* __restrict__ ln_g, const float* __restrict__ ln_b, int li) {
    int n = blockIdx.x;
    int l = threadIdx.x;  // 0..63
    float v0 = h_new[(size_t)n * H_ + l];
    float v1 = h_new[(size_t)n * H_ + 64 + l];
    h_new[(size_t)n * H_ + l] = 0.0f;
    h_new[(size_t)n * H_ + 64 + l] = 0.0f;
    float s = v0 + v1;
    #pragma unroll
    for (int off = 32; off; off >>= 1) s += __shfl_xor(s, off);
    float mean = s * (1.0f / H_);
    float d0 = v0 - mean, d1 = v1 - mean;
    float vs = d0 * d0 + d1 * d1;
    #pragma unroll
    for (int off = 32; off; off >>= 1) vs += __shfl_xor(vs, off);
    float rstd = rsqrtf(vs * (1.0f / H_) + 1e-5f);
    const float* gg = ln_g + (size_t)li * H_;
    const float* bb = ln_b + (size_t)li * H_;
    float t0 = gelu_exact(d0 * rstd * gg[l] + bb[l]);
    float t1 = gelu_exact(d1 * rstd * gg[64 + l] + bb[64 + l]);
    size_t o = (size_t)n * H_;
    if (li == 0) { h[o + l] = t0; h[o + 64 + l] = t1; }
    else         { h[o + l] += t0; h[o + 64 + l] += t1; }
}

// ---------------- temporal: positional encoding add (in place on h) ----------------

__global__ void k_peadd(float* __restrict__ h) {
    int i = blockIdx.x * blockDim.x + threadIdx.x;
    int stride = gridDim.x * blockDim.x;
    for (; i < N_ * H_; i += stride) {
        int j = i & 127;
        int t = (i >> 7) & 63;
        float dv = __expf((float)(j & ~1) * (-0.0719557841560639f));
        float ang = (float)t * dv;
        float pe = (j & 1) ? cosf(ang) : sinf(ang);
        h[i] += pe;
    }
}

// ---------------- temporal qkv GEMM: block = (node-in-chunk, {q,k,v}) ----------------

__global__ __launch_bounds__(256) void k_tqkv(const float* __restrict__ hs,
                                              const float* __restrict__ t_in_w, const float* __restrict__ t_in_b,
                                              float* __restrict__ qc, float* __restrict__ kc, float* __restrict__ vc,
                                              int li, int c0) {
    int nb = blockIdx.x;        // node in chunk
    int nt = blockIdx.y;        // 0=q 1=k 2=v
    int node = c0 + nb;
    __shared__ float s_a[64 * 132];
    __shared__ float s_b[32 * 132];
    int tid = threadIdx.x;
    #pragma unroll
    for (int i = 0; i < 8; ++i) {
        int idx = i * 256 + tid;
        int r = idx >> 5, c4 = (idx & 31) * 4;
        *reinterpret_cast<float4*>(&s_a[r * 132 + c4]) =
            *reinterpret_cast<const float4*>(&hs[((size_t)node * 64 + r) * 128 + c4]);
    }
    const float* B = t_in_w + ((size_t)li * 384 + nt * 128) * 128;
    const float* bi = t_in_b + (size_t)li * 384 + nt * 128;
    int rg = tid >> 4, cg = tid & 15;
    int r0 = rg * 4;
    float4 alo[4], ahi[4];
    #pragma unroll
    for (int rr = 0; rr < 4; ++rr) { alo[rr] = f4zero(); ahi[rr] = f4zero(); }
    for (int kci = 0; kci < 4; ++kci) {
        __syncthreads();
        #pragma unroll
        for (int i = 0; i < 4; ++i) {
            int idx = i * 256 + tid;
            int jj = idx >> 3, k4 = (idx & 7) * 4;
            float4 w = *reinterpret_cast<const float4*>(&B[(size_t)jj * 128 + kci * 32 + k4]);
            s_b[(k4 + 0) * 132 + jj] = w.x; s_b[(k4 + 1) * 132 + jj] = w.y;
            s_b[(k4 + 2) * 132 + jj] = w.z; s_b[(k4 + 3) * 132 + jj] = w.w;
        }
        __syncthreads();
        #pragma unroll
        for (int k4 = 0; k4 < 8; ++k4) {
            float4 a4[4];
            #pragma unroll
            for (int rr = 0; rr < 4; ++rr)
                a4[rr] = *reinterpret_cast<const float4*>(&s_a[(r0 + rr) * 132 + kci * 32 + k4 * 4]);
            #pragma unroll
            for (int jj = 0; jj < 4; ++jj) {
                float4 blo = *reinterpret_cast<const float4*>(&s_b[(k4 * 4 + jj) * 132 + cg * 4]);
                float4 bhi = *reinterpret_cast<const float4*>(&s_b[(k4 * 4 + jj) * 132 + 64 + cg * 4]);
                #pragma unroll
                for (int rr = 0; rr < 4; ++rr) {
                    float av = (jj == 0) ? a4[rr].x : (jj == 1) ? a4[rr].y : (jj == 2) ? a4[rr].z : a4[rr].w;
                    f4fma(alo[rr], av, blo);
                    f4fma(ahi[rr], av, bhi);
                }
            }
        }
    }
    float* dst = (nt == 0) ? qc : (nt == 1) ? kc : vc;
    float sc = (nt == 0) ? SCALE_ : 1.0f;
    float4 blo = *reinterpret_cast<const float4*>(&bi[cg * 4]);
    float4 bhi = *reinterpret_cast<const float4*>(&bi[64 + cg * 4]);
    #pragma unroll
    for (int rr = 0; rr < 4; ++rr) {
        float4 lo = alo[rr], hi = ahi[rr];
        lo.x = (lo.x + blo.x) * sc; lo.y = (lo.y + blo.y) * sc; lo.z = (lo.z + blo.z) * sc; lo.w = (lo.w + blo.w) * sc;
        hi.x = (hi.x + bhi.x) * sc; hi.y = (hi.y + bhi.y) * sc; hi.z = (hi.z + bhi.z) * sc; hi.w = (hi.w + bhi.w) * sc;
        size_t row = (size_t)nb * 64 + r0 + rr;
        *reinterpret_cast<float4*>(&dst[row * 128 + cg * 4]) = lo;
        *reinterpret_cast<float4*>(&dst[row * 128 + 64 + cg * 4]) = hi;
    }
}

// ---------------- temporal attention: block = (node-in-chunk, head), 64 threads ----------------

__global__ __launch_bounds__(64) void k_tattn(float* __restrict__ qc, const float* __restrict__ kc,
                                              const float* __restrict__ vc) {
    int nb = blockIdx.x, head = blockIdx.y;
    __shared__ float s_k[64 * 36];
    __shared__ float s_v[64 * 36];
    int t = threadIdx.x;
    #pragma unroll
    for (int i = 0; i < 8; ++i) {
        int idx = i * 64 + t;
        int row = idx >> 3, d4 = (idx & 7) * 4;
        *reinterpret_cast<float4*>(&s_k[row * 36 + d4]) =
            *reinterpret_cast<const float4*>(&kc[((size_t)nb * 64 + row) * 128 + head * DH_ + d4]);
        *reinterpret_cast<float4*>(&s_v[row * 36 + d4]) =
            *reinterpret_cast<const float4*>(&vc[((size_t)nb * 64 + row) * 128 + head * DH_ + d4]);
    }
    float4 q[8];
    {
        const float4* qr = reinterpret_cast<const float4*>(&qc[((size_t)nb * 64 + t) * 128 + head * DH_]);
        #pragma unroll
        for (int i = 0; i < 8; ++i) q[i] = qr[i];
    }
    __syncthreads();
    float m = -1e30f;
    for (int t2 = 0; t2 < 64; ++t2) {
        const float4* kr = reinterpret_cast<const float4*>(&s_k[t2 * 36]);
        float s0 = 0, s1 = 0, s2 = 0, s3 = 0;
        #pragma unroll
        for (int i = 0; i < 8; ++i) {
            float4 kk = kr[i];
            s0 += q[i].x * kk.x; s1 += q[i].y * kk.y; s2 += q[i].z * kk.z; s3 += q[i].w * kk.w;
        }
        m = fmaxf(m, (s0 + s1) + (s2 + s3));
    }
    float ssum = 0.0f;
    float4 o[8];
    #pragma unroll
    for (int i = 0; i < 8; ++i) o[i] = f4zero();
    for (int t2 = 0; t2 < 64; ++t2) {
        const float4* kr = reinterpret_cast<const float4*>(&s_k[t2 * 36]);
        float s0 = 0, s1 = 0, s2 = 0, s3 = 0;
        #pragma unroll
        for (int i = 0; i < 8; ++i) {
            float4 kk = kr[i];
            s0 += q[i].x * kk.x; s1 += q[i].y * kk.y; s2 += q[i].z * kk.z; s3 += q[i].w * kk.w;
        }
        float p = __expf((s0 + s1) + (s2 + s3) - m);
        ssum += p;
        const float4* vr = reinterpret_cast<const float4*>(&s_v[t2 * 36]);
        #pragma unroll
        for (int i = 0; i < 8; ++i) f4fma(o[i], p, vr[i]);
    }
    float inv = 1.0f / ssum;
    float4* orow = reinterpret_cast<float4*>(&qc[((size_t)nb * 64 + t) * 128 + head * DH_]);
    #pragma unroll
    for (int i = 0; i < 8; ++i) { float4 v = o[i]; f4scale(v, inv); orow[i] = v; }
}

// ---------------- temporal out-proj + residual + LN1 ----------------

__global__ __launch_bounds__(256) void k_toutln(const float* __restrict__ oc, float* __restrict__ hs,
                                                const float* __restrict__ t_out_w, const float* __restrict__ t_out_b,
                                                const float* __restrict__ ln_g, const float* __restrict__ ln_b,
                                                int li, int c0) {
    int nb = blockIdx.x;
    int node = c0 + nb;
    __shared__ float s_a[64 * 132];
    __shared__ float s_b[32 * 132];
    int tid = threadIdx.x;
    #pragma unroll
    for (int i = 0; i < 8; ++i) {
        int idx = i * 256 + tid;
        int r = idx >> 5, c4 = (idx & 31) * 4;
        *reinterpret_cast<float4*>(&s_a[r * 132 + c4]) =
            *reinterpret_cast<const float4*>(&oc[((size_t)nb * 64 + r) * 128 + c4]);
    }
    const float* B = t_out_w + (size_t)li * 128 * 128;
    const float* bo = t_out_b + (size_t)li * 128;
    int rg = tid >> 4, cg = tid & 15;
    int r0 = rg * 4;
    float4 alo[4], ahi[4];
    #pragma unroll
    for (int rr = 0; rr < 4; ++rr) { alo[rr] = f4zero(); ahi[rr] = f4zero(); }
    for (int kci = 0; kci < 4; ++kci) {
        __syncthreads();
        #pragma unroll
        for (int i = 0; i < 4; ++i) {
            int idx = i * 256 + tid;
            int jj = idx >> 3, k4 = (idx & 7) * 4;
            float4 w = *reinterpret_cast<const float4*>(&B[(size_t)jj * 128 + kci * 32 + k4]);
            s_b[(k4 + 0) * 132 + jj] = w.x; s_b[(k4 + 1) * 132 + jj] = w.y;
            s_b[(k4 + 2) * 132 + jj] = w.z; s_b[(k4 + 3) * 132 + jj] = w.w;
        }
        __syncthreads();
        #pragma unroll
        for (int k4 = 0; k4 < 8; ++k4) {
            float4 a4[4];
            #pragma unroll
            for (int rr = 0; rr < 4; ++rr)
                a4[rr] = *reinterpret_cast<const float4*>(&s_a[(r0 + rr) * 132 + kci * 32 + k4 * 4]);
            #pragma unroll
            for (int jj = 0; jj < 4; ++jj) {
                float4 blo = *reinterpret_cast<const float4*>(&s_b[(k4 * 4 + jj) * 132 + cg * 4]);
                float4 bhi = *reinterpret_cast<const float4*>(&s_b[(k4 * 4 + jj) * 132 + 64 + cg * 4]);
                #pragma unroll
                for (int rr = 0; rr < 4; ++rr) {
                    float av = (jj == 0) ? a4[rr].x : (jj == 1) ? a4[rr].y : (jj == 2) ? a4[rr].z : a4[rr].w;
                    f4fma(alo[rr], av, blo);
                    f4fma(ahi[rr], av, bhi);
                }
            }
        }
    }
    float4 bblo = *reinterpret_cast<const float4*>(&bo[cg * 4]);
    float4 bbhi = *reinterpret_cast<const float4*>(&bo[64 + cg * 4]);
    float4 glo = *reinterpret_cast<const float4*>(&ln_g[(size_t)li * 128 + cg * 4]);
    float4 ghi = *reinterpret_cast<const float4*>(&ln_g[(size_t)li * 128 + 64 + cg * 4]);
    float4 lblo = *reinterpret_cast<const float4*>(&ln_b[(size_t)li * 128 + cg * 4]);
    float4 lbhi = *reinterpret_cast<const float4*>(&ln_b[(size_t)li * 128 + 64 + cg * 4]);
    #pragma unroll
    for (int rr = 0; rr < 4; ++rr) {
        size_t row = (size_t)node * 64 + r0 + rr;
        float4 rlo = *reinterpret_cast<const float4*>(&hs[row * 128 + cg * 4]);
        float4 rhi = *reinterpret_cast<const float4*>(&hs[row * 128 + 64 + cg * 4]);
        float4 lo = alo[rr], hi = ahi[rr];
        lo.x += bblo.x + rlo.x; lo.y += bblo.y + rlo.y; lo.z += bblo.z + rlo.z; lo.w += bblo.w + rlo.w;
        hi.x += bbhi.x + rhi.x; hi.y += bbhi.y + rhi.y; hi.z += bbhi.z + rhi.z; hi.w += bbhi.w + rhi.w;
        float s = lo.x + lo.y + lo.z + lo.w + hi.x + hi.y + hi.z + hi.w;
        s += __shfl_xor(s, 1); s += __shfl_xor(s, 2); s += __shfl_xor(s, 4); s += __shfl_xor(s, 8);
        float mean = s * (1.0f / 128.0f);
        float4 dlo = make_float4(lo.x - mean, lo.y - mean, lo.z - mean, lo.w - mean);
        float4 dhi = make_float4(hi.x - mean, hi.y - mean, hi.z - mean, hi.w - mean);
        float vx = dlo.x * dlo.x + dlo.y * dlo.y + dlo.z * dlo.z + dlo.w * dlo.w +
                   dhi.x * dhi.x + dhi.y * dhi.y + dhi.z * dhi.z + dhi.w * dhi.w;
        vx += __shfl_xor(vx, 1); vx += __shfl_xor(vx, 2); vx += __shfl_xor(vx, 4); vx += __shfl_xor(vx, 8);
        float rstd = rsqrtf(vx * (1.0f / 128.0f) + 1e-5f);
        float4 olo = make_float4(dlo.x * rstd * glo.x + lblo.x, dlo.y * rstd * glo.y + lblo.y,
                                 dlo.z * rstd * glo.z + lblo.z, dlo.w * rstd * glo.w + lblo.w);
        float4 ohi = make_float4(dhi.x * rstd * ghi.x + lbhi.x, dhi.y * rstd * ghi.y + lbhi.y,
                                 dhi.z * rstd * ghi.z + lbhi.z, dhi.w * rstd * ghi.w + lbhi.w);
        *reinterpret_cast<float4*>(&hs[row * 128 + cg * 4]) = olo;
        *reinterpret_cast<float4*>(&hs[row * 128 + 64 + cg * 4]) = ohi;
    }
}

// ---------------- temporal fused FF (FF1+gelu+FF2) + residual + LN2 ----------------

__global__ __launch_bounds__(256) void k_tff(float* __restrict__ hs,
                                             const float* __restrict__ t_w1, const float* __restrict__ t_b1,
                                             const float* __restrict__ t_w2, const float* __restrict__ t_b2,
                                             const float* __restrict__ ln_g, const float* __restrict__ ln_b,
                                             int li) {
    int node = blockIdx.x;
    __shared__ float s_h[64 * 132];
    __shared__ float s_f[64 * 132];
    __shared__ float s_b[16 * 132];
    int tid = threadIdx.x;
    #pragma unroll
    for (int i = 0; i < 8; ++i) {
        int idx = i * 256 + tid;
        int r = idx >> 5, c4 = (idx & 31) * 4;
        *reinterpret_cast<float4*>(&s_h[r * 132 + c4]) =
            *reinterpret_cast<const float4*>(&hs[((size_t)node * 64 + r) * 128 + c4]);
    }
    __syncthreads();
    int rg = tid >> 4, cg = tid & 15;
    int r0 = rg * 4;
    const float* W1 = t_w1 + (size_t)li * FF_ * 128;
    const float* b1 = t_b1 + (size_t)li * FF_;
    const float* W2 = t_w2 + (size_t)li * 128 * FF_;
    const float* b2 = t_b2 + (size_t)li * 128;
    float4 c2lo[4], c2hi[4];
    #pragma unroll
    for (int rr = 0; rr < 4; ++rr) { c2lo[rr] = f4zero(); c2hi[rr] = f4zero(); }

    for (int nt = 0; nt < 4; ++nt) {
        float4 c1lo[4], c1hi[4];
        #pragma unroll
        for (int rr = 0; rr < 4; ++rr) { c1lo[rr] = f4zero(); c1hi[rr] = f4zero(); }
        for (int kci = 0; kci < 8; ++kci) {
            #pragma unroll
            for (int i = 0; i < 2; ++i) {
                int idx = i * 256 + tid;
                int jj = idx >> 2, k4 = (idx & 3) * 4;
                float4 w = *reinterpret_cast<const float4*>(&W1[(size_t)(nt * 128 + jj) * 128 + kci * 16 + k4]);
                s_b[(k4 + 0) * 132 + jj] = w.x; s_b[(k4 + 1) * 132 + jj] = w.y;
                s_b[(k4 + 2) * 132 + jj] = w.z; s_b[(k4 + 3) * 132 + jj] = w.w;
            }
            __syncthreads();
            #pragma unroll
            for (int k4 = 0; k4 < 4; ++k4) {
                float4 a4[4];
                #pragma unroll
                for (int rr = 0; rr < 4; ++rr)
                    a4[rr] = *reinterpret_cast<const float4*>(&s_h[(r0 + rr) * 132 + kci * 16 + k4 * 4]);
                #pragma unroll
                for (int jj = 0; jj < 4; ++jj) {
                    float4 blo = *reinterpret_cast<const float4*>(&s_b[(k4 * 4 + jj) * 132 + cg * 4]);
                    float4 bhi = *reinterpret_cast<const float4*>(&s_b[(k4 * 4 + jj) * 132 + 64 + cg * 4]);
                    #pragma unroll
                    for (int rr = 0; rr < 4; ++rr) {
                        float av = (jj == 0) ? a4[rr].x : (jj == 1) ? a4[rr].y : (jj == 2) ? a4[rr].z : a4[rr].w;
                        f4fma(c1lo[rr], av, blo);
                        f4fma(c1hi[rr], av, bhi);
                    }
                }
            }
            __syncthreads();
        }
        {
            float4 blo = *reinterpret_cast<const float4*>(&b1[nt * 128 + cg * 4]);
            float4 bhi = *reinterpret_cast<const float4*>(&b1[nt * 128 + 64 + cg * 4]);
            #pragma unroll
            for (int rr = 0; rr < 4; ++rr) {
                float4 lo = c1lo[rr], hi = c1hi[rr];
                lo.x = gelu_exact(lo.x + blo.x); lo.y = gelu_exact(lo.y + blo.y);
                lo.z = gelu_exact(lo.z + blo.z); lo.w = gelu_exact(lo.w + blo.w);
                hi.x = gelu_exact(hi.x + bhi.x); hi.y = gelu_exact(hi.y + bhi.y);
                hi.z = gelu_exact(hi.z + bhi.z); hi.w = gelu_exact(hi.w + bhi.w);
                *reinterpret_cast<float4*>(&s_f[(r0 + rr) * 132 + cg * 4]) = lo;
                *reinterpret_cast<float4*>(&s_f[(r0 + rr) * 132 + 64 + cg * 4]) = hi;
            }
        }
        __syncthreads();
        for (int kci = 0; kci < 8; ++kci) {
            #pragma unroll
            for (int i = 0; i < 2; ++i) {
                int idx = i * 256 + tid;
                int jj = idx >> 2, k4 = (idx & 3) * 4;
                float4 w = *reinterpret_cast<const float4*>(&W2[(size_t)jj * FF_ + nt * 128 + kci * 16 + k4]);
                s_b[(k4 + 0) * 132 + jj] = w.x; s_b[(k4 + 1) * 132 + jj] = w.y;
                s_b[(k4 + 2) * 132 + jj] = w.z; s_b[(k4 + 3) * 132 + jj] = w.w;
            }
            __syncthreads();
            #pragma unroll
            for (int k4 = 0; k4 < 4; ++k4) {
                float4 a4[4];
                #pragma unroll
                for (int rr = 0; rr < 4; ++rr)
                    a4[rr] = *reinterpret_cast<const float4*>(&s_f[(r0 + rr) * 132 + kci * 16 + k4 * 4]);
                #pragma unroll
                for (int jj = 0; jj < 4; ++jj) {
                    float4 blo = *reinterpret_cast<const float4*>(&s_b[(k4 * 4 + jj) * 132 + cg * 4]);
                    float4 bhi = *reinterpret_cast<const float4*>(&s_b[(k4 * 4 + jj) * 132 + 64 + cg * 4]);
                    #pragma unroll
                    for (int rr = 0; rr < 4; ++rr) {
                        float av = (jj == 0) ? a4[rr].x : (jj == 1) ? a4[rr].y : (jj == 2) ? a4[rr].z : a4[rr].w;
                        f4fma(c2lo[rr], av, blo);
                        f4fma(c2hi[rr], av, bhi);
                    }
                }
            }
            __syncthreads();
        }
    }
    float4 bblo = *reinterpret_cast<const float4*>(&b2[cg * 4]);
    float4 bbhi = *reinterpret_cast<const float4*>(&b2[64 + cg * 4]);
    float4 glo = *reinterpret_cast<const float4*>(&ln_g[(size_t)li * 128 + cg * 4]);
    float4 ghi = *reinterpret_cast<const float4*>(&ln_g[(size_t)li * 128 + 64 + cg * 4]);
    float4 lblo = *reinterpret_cast<const float4*>(&ln_b[(size_t)li * 128 + cg * 4]);
    float4 lbhi = *reinterpret_cast<const float4*>(&ln_b[(size_t)li * 128 + 64 + cg * 4]);
    #pragma unroll
    for (int rr = 0; rr < 4; ++rr) {
        size_t row = (size_t)node * 64 + r0 + rr;
        float4 rlo = *reinterpret_cast<const float4*>(&s_h[(r0 + rr) * 132 + cg * 4]);
        float4 rhi = *reinterpret_cast<const float4*>(&s_h[(r0 + rr) * 132 + 64 + cg * 4]);
        float4 lo = c2lo[rr], hi = c2hi[rr];
        lo.x += bblo.x + rlo.x; lo.y += bblo.y + rlo.y; lo.z += bblo.z + rlo.z; lo.w += bblo.w + rlo.w;
        hi.x += bbhi.x + rhi.x; hi.y += bbhi.y + rhi.y; hi.z += bbhi.z + rhi.z; hi.w += bbhi.w + rhi.w;
        float s = lo.x + lo.y + lo.z + lo.w + hi.x + hi.y + hi.z + hi.w;
        s += __shfl_xor(s, 1); s += __shfl_xor(s, 2); s += __shfl_xor(s, 4); s += __shfl_xor(s, 8);
        float mean = s * (1.0f / 128.0f);
        float4 dlo = make_float4(lo.x - mean, lo.y - mean, lo.z - mean, lo.w - mean);
        float4 dhi = make_float4(hi.x - mean, hi.y - mean, hi.z - mean, hi.w - mean);
        float vx = dlo.x * dlo.x + dlo.y * dlo.y + dlo.z * dlo.z + dlo.w * dlo.w +
                   dhi.x * dhi.x + dhi.y * dhi.y + dhi.z * dhi.z + dhi.w * dhi.w;
        vx += __shfl_xor(vx, 1); vx += __shfl_xor(vx, 2); vx += __shfl_xor(vx, 4); vx += __shfl_xor(vx, 8);
        float rstd = rsqrtf(vx * (1.0f / 128.0f) + 1e-5f);
        float4 olo = make_float4(dlo.x * rstd * glo.x + lblo.x, dlo.y * rstd * glo.y + lblo.y,
                                 dlo.z * rstd * glo.z + lblo.z, dlo.w * rstd * glo.w + lblo.w);
        float4 ohi = make_float4(dhi.x * rstd * ghi.x + lbhi.x, dhi.y * rstd * ghi.y + lbhi.y,
                                 dhi.z * rstd * ghi.z + lbhi.z, dhi.w * rstd * ghi.w + lbhi.w);
        *reinterpret_cast<float4*>(&hs[row * 128 + cg * 4]) = olo;
        *reinterpret_cast<float4*>(&hs[row * 128 + 64 + cg * 4]) = ohi;
    }
}

// ---------------- final LN -> out ----------------

__global__ __launch_bounds__(256) void k_fln(const float* __restrict__ hs, float* __restrict__ out,
                                             const float* __restrict__ g, const float* __restrict__ b) {
    int row = blockIdx.x * 4 + (threadIdx.x >> 6);
    int l = threadIdx.x & 63;
    float v0 = hs[(size_t)row * H_ + l];
    float v1 = hs[(size_t)row * H_ + 64 + l];
    float s = v0 + v1;
    #pragma unroll
    for (int off = 32; off; off >>= 1) s += __shfl_xor(s, off);
    float mean = s * (1.0f / H_);
    float d0 = v0 - mean, d1 = v1 - mean;
    float vs = d0 * d0 + d1 * d1;
    #pragma unroll
    for (int off = 32; off; off >>= 1) vs += __shfl_xor(vs, off);
    float rstd = rsqrtf(vs * (1.0f / H_) + 1e-5f);
    out[(size_t)row * H_ + l] = d0 * rstd * g[l] + b[l];
    out[(size_t)row * H_ + 64 + l] = d1 * rstd * g[64 + l] + b[64 + l];
}

// ---------------- launch ----------------

extern "C" void kernel_launch(void* const* d_in, const int* in_sizes, int n_in,
                              void* d_out, int out_size, void* d_ws, size_t ws_size,
                              hipStream_t stream) {
    const float* x          = (const float*)d_in[0];
    const int*   edge_index = (const int*)d_in[1];
    const int*   edge_type  = (const int*)d_in[2];
    const int*   node_type  = (const int*)d_in[3];
    const float* W_in    = (const float*)d_in[6];
    const float* b_in    = (const float*)d_in[7];
    const float* s_in_w  = (const float*)d_in[8];
    const float* s_in_b  = (const float*)d_in[9];
    const float* s_out_w = (const float*)d_in[10];
    const float* s_out_b = (const float*)d_in[11];
    const float* ln_s_g  = (const float*)d_in[12];
    const float* ln_s_b  = (const float*)d_in[13];
    const float* t_in_w  = (const float*)d_in[14];
    const float* t_in_b  = (const float*)d_in[15];
    const float* t_out_w = (const float*)d_in[16];
    const float* t_out_b = (const float*)d_in[17];
    const float* t_ln1_g = (const float*)d_in[18];
    const float* t_ln1_b = (const float*)d_in[19];
    const float* t_w1    = (const float*)d_in[20];
    const float* t_b1    = (const float*)d_in[21];
    const float* t_w2    = (const float*)d_in[22];
    const float* t_b2    = (const float*)d_in[23];
    const float* t_ln2_g = (const float*)d_in[24];
    const float* t_ln2_b = (const float*)d_in[25];
    const float* fin_g   = (const float*)d_in[26];
    const float* fin_b   = (const float*)d_in[27];
    float* out = (float*)d_out;

    // workspace layout (floats)
    float* h     = (float*)d_ws;                       // N*H = 8388608
    float* h_new = h + (size_t)N_ * H_;                // 8388608
    float* qkv   = h_new + (size_t)N_ * H_;            // E*384 = 11520000
    int* sorted  = (int*)(qkv + (size_t)E_ * 384);     // E
    int* gpos    = sorted + E_;                        // E
    int* gedge   = gpos + E_;                          // E
    int* cnt     = gedge + E_;                         // 64
    int* offs    = cnt + 64;                           // 64
    int* curs    = offs + 64;                          // 64
    int* nd64    = curs + 64;                          // 16
    int2* desc64 = (int2*)(nd64 + 16);                 // 544 int2

    // temporal chunk buffers (alias spatial regions, used after spatial completes)
    float* qc = qkv;                                   // CH*64*128 = 4194304
    float* kc = qkv + (size_t)CH_ * 64 * 128;          // 4194304
    float* vc = h_new;                                 // 4194304

    k_zero_cnt<<<1, 64, 0, stream>>>(cnt);
    k_hist<<<(E_ + 255) / 256, 256, 0, stream>>>(edge_index, edge_type, node_type, gedge, cnt);
    k_scan<<<1, 1, 0, stream>>>(cnt, offs, curs);
    k_scatter<<<(E_ + 255) / 256, 256, 0, stream>>>(gedge, curs, sorted, gpos);
    k_desc<<<1, 1, 0, stream>>>(offs, desc64, nd64);

    k_inproj<<<N_, 128, 0, stream>>>(x, node_type, W_in, b_in, h);

    k_zero<<<2048, 256, 0, stream>>>(h_new, N_ * H_);   // layer 0; later layers zeroed by k_lngelu
    for (int li = 0; li < L_; ++li) {
        k_sqkv_gemm<<<dim3(GATTN_GRID, 3), 256, 0, stream>>>(h, s_in_w, s_in_b, sorted, offs, edge_index,
                                                             desc64, nd64, qkv, li);
        k_gattn<<<GATTN_GRID, 512, 0, stream>>>(qkv, sorted, offs, edge_index, desc64, nd64,
                                                s_out_w, s_out_b, h_new, li);
        k_lngelu<<<N_, 64, 0, stream>>>(h_new, h, ln_s_g, ln_s_b, li);
    }

    // temporal: hs = h + PE (in place)
    k_peadd<<<2048, 256, 0, stream>>>(h);
    for (int li = 0; li < TL_; ++li) {
        for (int c = 0; c < NB_ / CH_; ++c) {
            int c0 = c * CH_;
            k_tqkv<<<dim3(CH_, 3), 256, 0, stream>>>(h, t_in_w, t_in_b, qc, kc, vc, li, c0);
            k_tattn<<<dim3(CH_, NH_), 64, 0, stream>>>(qc, kc, vc);
            k_toutln<<<CH_, 256, 0, stream>>>(qc, h, t_out_w, t_out_b, t_ln1_g, t_ln1_b, li, c0);
        }
        k_tff<<<NB_, 256, 0, stream>>>(h, t_w1, t_b1, t_w2, t_b2, t_ln2_g, t_ln2_b, li);
    }
    k_fln<<<N_ / 4, 256, 0, stream>>>(h, out, fin_g, fin_b);
}

// Round 10
// 2019.198 us; speedup vs baseline: 1.1899x; 1.1899x over previous
//
#include <hip/hip_runtime.h>
#include <hip/hip_bf16.h>
#include <hip/hip_fp16.h>
#include <math.h>

// Problem constants (fixed by reference)
#define N_   65536
#define F_   64
#define H_   128
#define E_   30000
#define NT_  5
#define ET_  10
#define NG_  50
#define L_   3
#define TL_  2
#define NH_  4
#define DH_  32
#define NB_  1024
#define TT_  64
#define FF_  512
#define CH_  512         // temporal node chunk
#define GATTN_GRID 544

#define SCALE_ 0.17677669529663687f   // 1/sqrt(32)

__device__ __forceinline__ float gelu_exact(float x) {
    return 0.5f * x * (1.0f + erff(x * 0.70710678118654752f));
}
__device__ __forceinline__ void f4fma(float4& a, float s, const float4& b) {
    a.x += s * b.x; a.y += s * b.y; a.z += s * b.z; a.w += s * b.w;
}
__device__ __forceinline__ void f4scale(float4& a, float s) {
    a.x *= s; a.y *= s; a.z *= s; a.w *= s;
}
__device__ __forceinline__ float4 f4zero() { return make_float4(0.f, 0.f, 0.f, 0.f); }

union F4H { float4 f; __half2 h[4]; };   // float4 = 16 B = 4 half2

// ---------------- grouping ----------------

__global__ void k_zero_cnt(int* cnt) {
    if (threadIdx.x < NG_) cnt[threadIdx.x] = 0;
}

__global__ void k_hist(const int* __restrict__ edge_index, const int* __restrict__ edge_type,
                       const int* __restrict__ node_type, int* __restrict__ gedge, int* __restrict__ cnt) {
    int e = blockIdx.x * blockDim.x + threadIdx.x;
    if (e >= E_) return;
    int dn = edge_index[E_ + e];
    int g = edge_type[e] * NT_ + node_type[dn];
    gedge[e] = g;
    atomicAdd(&cnt[g], 1);
}

__global__ void k_scan(const int* __restrict__ cnt, int* __restrict__ offs, int* __restrict__ curs) {
    if (threadIdx.x == 0 && blockIdx.x == 0) {
        int acc = 0;
        for (int g = 0; g < NG_; ++g) { offs[g] = acc; curs[g] = acc; acc += cnt[g]; }
        offs[NG_] = acc;
    }
}

__global__ void k_scatter(const int* __restrict__ gedge, int* __restrict__ curs,
                          int* __restrict__ sorted, int* __restrict__ gpos) {
    int e = blockIdx.x * blockDim.x + threadIdx.x;
    if (e >= E_) return;
    int g = gedge[e];
    int pos = atomicAdd(&curs[g], 1);
    sorted[pos] = e;
    gpos[pos] = g;
}

// descriptor lists: 64-edge tiles (qkv gemm + attention)
__global__ void k_desc(const int* __restrict__ offs, int2* __restrict__ desc64, int* __restrict__ nd64) {
    if (threadIdx.x || blockIdx.x) return;
    int n64 = 0;
    for (int g = 0; g < NG_; ++g) {
        int sz = offs[g + 1] - offs[g];
        for (int qs = 0; qs < sz; qs += 64) desc64[n64++] = make_int2(g, qs);
    }
    nd64[0] = n64;
}

// ---------------- input projection ----------------

__global__ void k_inproj(const float* __restrict__ x, const int* __restrict__ node_type,
                         const float* __restrict__ W_in, const float* __restrict__ b_in,
                         float* __restrict__ h) {
    int n = blockIdx.x;
    int j = threadIdx.x;  // 0..127
    __shared__ float sx[F_];
    if (j < F_) sx[j] = x[(size_t)n * F_ + j];
    __syncthreads();
    int nt = node_type[n];
    const float* W = W_in + (size_t)nt * F_ * H_;
    float acc = b_in[(size_t)nt * H_ + j];
    #pragma unroll 8
    for (int f = 0; f < F_; ++f) acc += sx[f] * W[(size_t)f * H_ + j];
    h[(size_t)n * H_ + j] = acc;
}

__global__ void k_zero(float* __restrict__ p, int n) {
    int i = blockIdx.x * blockDim.x + threadIdx.x;
    int stride = gridDim.x * blockDim.x;
    for (; i < n; i += stride) p[i] = 0.0f;
}

// ---------------- spatial qkv projection: tiled GEMM over 64-edge tiles ----------------
// grid = (544, 3); y: 0=q (dst rows), 1=k, 2=v (src rows)

__global__ __launch_bounds__(256) void k_sqkv_gemm(
    const float* __restrict__ h, const float* __restrict__ s_in_w, const float* __restrict__ s_in_b,
    const int* __restrict__ sorted, const int* __restrict__ offs, const int* __restrict__ edge_index,
    const int2* __restrict__ desc64, const int* __restrict__ nd64,
    float* __restrict__ qkv, int li) {
    int bx = blockIdx.x;
    if (bx >= nd64[0]) return;
    int2 dd = desc64[bx];
    int g = dd.x, qs = dd.y;
    int qbase = offs[g] + qs;
    int qcnt = min(64, offs[g + 1] - qbase);
    int et = g / NT_;
    int nt = blockIdx.y;
    __shared__ float s_a[64 * 132];
    __shared__ float s_b[32 * 132];
    int tid = threadIdx.x;
    // gather 64 input rows (dst for q, src for k/v)
    #pragma unroll
    for (int i = 0; i < 8; ++i) {
        int idx = i * 256 + tid;
        int r = idx >> 5, c4 = (idx & 31) * 4;
        int p = qbase + min(r, qcnt - 1);
        int e = sorted[p];
        int node = (nt == 0) ? edge_index[E_ + e] : edge_index[e];
        *reinterpret_cast<float4*>(&s_a[r * 132 + c4]) =
            *reinterpret_cast<const float4*>(&h[(size_t)node * H_ + c4]);
    }
    const float* B = s_in_w + ((size_t)(li * ET_ + et) * 3 * H_ + nt * H_) * H_;
    const float* bi = s_in_b + (size_t)(li * ET_ + et) * 3 * H_ + nt * H_;
    int rg = tid >> 4, cg = tid & 15;
    int r0 = rg * 4;
    float4 alo[4], ahi[4];
    #pragma unroll
    for (int rr = 0; rr < 4; ++rr) { alo[rr] = f4zero(); ahi[rr] = f4zero(); }
    for (int kci = 0; kci < 4; ++kci) {
        __syncthreads();
        #pragma unroll
        for (int i = 0; i < 4; ++i) {
            int idx = i * 256 + tid;
            int jj = idx >> 3, k4 = (idx & 7) * 4;
            float4 w = *reinterpret_cast<const float4*>(&B[(size_t)jj * H_ + kci * 32 + k4]);
            s_b[(k4 + 0) * 132 + jj] = w.x; s_b[(k4 + 1) * 132 + jj] = w.y;
            s_b[(k4 + 2) * 132 + jj] = w.z; s_b[(k4 + 3) * 132 + jj] = w.w;
        }
        __syncthreads();
        #pragma unroll
        for (int k4 = 0; k4 < 8; ++k4) {
            float4 a4[4];
            #pragma unroll
            for (int rr = 0; rr < 4; ++rr)
                a4[rr] = *reinterpret_cast<const float4*>(&s_a[(r0 + rr) * 132 + kci * 32 + k4 * 4]);
            #pragma unroll
            for (int jj = 0; jj < 4; ++jj) {
                float4 blo = *reinterpret_cast<const float4*>(&s_b[(k4 * 4 + jj) * 132 + cg * 4]);
                float4 bhi = *reinterpret_cast<const float4*>(&s_b[(k4 * 4 + jj) * 132 + 64 + cg * 4]);
                #pragma unroll
                for (int rr = 0; rr < 4; ++rr) {
                    float av = (jj == 0) ? a4[rr].x : (jj == 1) ? a4[rr].y : (jj == 2) ? a4[rr].z : a4[rr].w;
                    f4fma(alo[rr], av, blo);
                    f4fma(ahi[rr], av, bhi);
                }
            }
        }
    }
    float4 blo = *reinterpret_cast<const float4*>(&bi[cg * 4]);
    float4 bhi = *reinterpret_cast<const float4*>(&bi[64 + cg * 4]);
    #pragma unroll
    for (int rr = 0; rr < 4; ++rr) {
        int row = r0 + rr;
        if (row < qcnt) {
            float* op = qkv + (size_t)(qbase + row) * 384 + nt * H_;
            float4 lo = alo[rr], hi = ahi[rr];
            lo.x += blo.x; lo.y += blo.y; lo.z += blo.z; lo.w += blo.w;
            hi.x += bhi.x; hi.y += bhi.y; hi.z += bhi.z; hi.w += bhi.w;
            *reinterpret_cast<float4*>(op + cg * 4) = lo;
            *reinterpret_cast<float4*>(op + 64 + cg * 4) = hi;
        }
    }
}

// ---------------- grouped spatial attention + out-proj + scatter ----------------
// block = one (group, 64-query tile); 256 threads = 4 heads x 64 queries.
// K/V staged as fp16 in LDS; QK^T and PV via packed __hfma2. Softmax + out-proj fp32.

__global__ __launch_bounds__(256, 2) void k_gattn(
    const float* __restrict__ qkv, const int* __restrict__ sorted,
    const int* __restrict__ offs, const int* __restrict__ edge_index,
    const int2* __restrict__ desc, const int* __restrict__ ndesc,
    const float* __restrict__ s_out_w, const float* __restrict__ s_out_b,
    float* __restrict__ h_new, int li) {
    int bx = blockIdx.x;
    if (bx >= ndesc[0]) return;
    int2 dd = desc[bx];
    int g = dd.x, qs = dd.y;
    int start = offs[g], end = offs[g + 1];
    int qbase = start + qs;
    int qcnt = min(64, end - qbase);
    int et = g / NT_;

    __shared__ __half2 s_kh[32 * 64];   // k tile: [32 rows][64 half2] = 8 KB
    __shared__ __half2 s_vh[32 * 64];   // v tile: 8 KB
    __shared__ float  s_o[64 * 132];    // normalized attention output (33.8 KB)
    __shared__ int    s_dn[64];
    int tid = threadIdx.x;
    int head = tid >> 6, qi = tid & 63;   // wave = one head, 64 queries

    if (tid < 64) s_dn[tid] = edge_index[E_ + sorted[qbase + min(tid, qcnt - 1)]];

    int p0 = qbase + min(qi, qcnt - 1);
    __half2 q2[16];
    {
        const float4* qr = reinterpret_cast<const float4*>(&qkv[(size_t)p0 * 384 + head * DH_]);
        #pragma unroll
        for (int i = 0; i < 8; ++i) {
            float4 qf = qr[i];
            q2[2 * i]     = __floats2half2_rn(qf.x, qf.y);
            q2[2 * i + 1] = __floats2half2_rn(qf.z, qf.w);
        }
    }
    float m = -1e30f, ssum = 0.0f;
    __half2 o2[16];
    #pragma unroll
    for (int i = 0; i < 16; ++i) o2[i] = __floats2half2_rn(0.f, 0.f);

    int nkt = (end - start + 31) >> 5;
    for (int kt = 0; kt < nkt; ++kt) {
        int kb = start + kt * 32;
        int kcnt = min(32, end - kb);
        __syncthreads();
        // stage k,v tile as fp16: 32 rows x 256 floats; 8 float4 per thread
        #pragma unroll
        for (int i = 0; i < 8; ++i) {
            int idx = i * 256 + tid;
            int row = idx >> 6, c4 = idx & 63;
            if (row < kcnt) {
                float4 w = *reinterpret_cast<const float4*>(&qkv[(size_t)(kb + row) * 384 + 128 + c4 * 4]);
                __half2 h0 = __floats2half2_rn(w.x, w.y);
                __half2 h1 = __floats2half2_rn(w.z, w.w);
                int c = c4 * 4;
                if (c < 128) {
                    s_kh[row * 64 + (c >> 1)] = h0;
                    s_kh[row * 64 + (c >> 1) + 1] = h1;
                } else {
                    int cc = c - 128;
                    s_vh[row * 64 + (cc >> 1)] = h0;
                    s_vh[row * 64 + (cc >> 1) + 1] = h1;
                }
            }
        }
        __syncthreads();
        if (kcnt == 32) {
            // single pass: scores in statically-indexed registers
            float sc[32];
            float tmax = -1e30f;
            #pragma unroll
            for (int t2 = 0; t2 < 32; ++t2) {
                const float4* kr = reinterpret_cast<const float4*>(&s_kh[t2 * 64 + head * 16]);
                F4H k0, k1, k2, k3;
                k0.f = kr[0]; k1.f = kr[1]; k2.f = kr[2]; k3.f = kr[3];
                __half2 acc = __hmul2(q2[0], k0.h[0]);
                #pragma unroll
                for (int i = 1; i < 4; ++i) acc = __hfma2(q2[i], k0.h[i], acc);
                #pragma unroll
                for (int i = 0; i < 4; ++i) acc = __hfma2(q2[4 + i], k1.h[i], acc);
                #pragma unroll
                for (int i = 0; i < 4; ++i) acc = __hfma2(q2[8 + i], k2.h[i], acc);
                #pragma unroll
                for (int i = 0; i < 4; ++i) acc = __hfma2(q2[12 + i], k3.h[i], acc);
                float dot = (__low2float(acc) + __high2float(acc)) * SCALE_;
                sc[t2] = dot;
                tmax = fmaxf(tmax, dot);
            }
            float mn = fmaxf(m, tmax);
            float f = __expf(m - mn);
            ssum *= f;
            __half2 f2 = __float2half2_rn(f);
            #pragma unroll
            for (int i = 0; i < 16; ++i) o2[i] = __hmul2(o2[i], f2);
            #pragma unroll
            for (int t2 = 0; t2 < 32; ++t2) {
                float p = __expf(sc[t2] - mn);
                ssum += p;
                __half2 p2 = __float2half2_rn(p);
                const float4* vr = reinterpret_cast<const float4*>(&s_vh[t2 * 64 + head * 16]);
                F4H v0, v1, v2, v3;
                v0.f = vr[0]; v1.f = vr[1]; v2.f = vr[2]; v3.f = vr[3];
                #pragma unroll
                for (int i = 0; i < 4; ++i) o2[i]      = __hfma2(p2, v0.h[i], o2[i]);
                #pragma unroll
                for (int i = 0; i < 4; ++i) o2[4 + i]  = __hfma2(p2, v1.h[i], o2[4 + i]);
                #pragma unroll
                for (int i = 0; i < 4; ++i) o2[8 + i]  = __hfma2(p2, v2.h[i], o2[8 + i]);
                #pragma unroll
                for (int i = 0; i < 4; ++i) o2[12 + i] = __hfma2(p2, v3.h[i], o2[12 + i]);
            }
            m = mn;
        } else {
            // tail: two-pass recompute
            float tmax = -1e30f;
            for (int t2 = 0; t2 < kcnt; ++t2) {
                const float4* kr = reinterpret_cast<const float4*>(&s_kh[t2 * 64 + head * 16]);
                F4H k0, k1, k2, k3;
                k0.f = kr[0]; k1.f = kr[1]; k2.f = kr[2]; k3.f = kr[3];
                __half2 acc = __hmul2(q2[0], k0.h[0]);
                #pragma unroll
                for (int i = 1; i < 4; ++i) acc = __hfma2(q2[i], k0.h[i], acc);
                #pragma unroll
                for (int i = 0; i < 4; ++i) acc = __hfma2(q2[4 + i], k1.h[i], acc);
                #pragma unroll
                for (int i = 0; i < 4; ++i) acc = __hfma2(q2[8 + i], k2.h[i], acc);
                #pragma unroll
                for (int i = 0; i < 4; ++i) acc = __hfma2(q2[12 + i], k3.h[i], acc);
                tmax = fmaxf(tmax, (__low2float(acc) + __high2float(acc)) * SCALE_);
            }
            float mn = fmaxf(m, tmax);
            float f = __expf(m - mn);
            ssum *= f;
            __half2 f2 = __float2half2_rn(f);
            #pragma unroll
            for (int i = 0; i < 16; ++i) o2[i] = __hmul2(o2[i], f2);
            for (int t2 = 0; t2 < kcnt; ++t2) {
                const float4* kr = reinterpret_cast<const float4*>(&s_kh[t2 * 64 + head * 16]);
                F4H k0, k1, k2, k3;
                k0.f = kr[0]; k1.f = kr[1]; k2.f = kr[2]; k3.f = kr[3];
                __half2 acc = __hmul2(q2[0], k0.h[0]);
                #pragma unroll
                for (int i = 1; i < 4; ++i) acc = __hfma2(q2[i], k0.h[i], acc);
                #pragma unroll
                for (int i = 0; i < 4; ++i) acc = __hfma2(q2[4 + i], k1.h[i], acc);
                #pragma unroll
                for (int i = 0; i < 4; ++i) acc = __hfma2(q2[8 + i], k2.h[i], acc);
                #pragma unroll
                for (int i = 0; i < 4; ++i) acc = __hfma2(q2[12 + i], k3.h[i], acc);
                float p = __expf((__low2float(acc) + __high2float(acc)) * SCALE_ - mn);
                ssum += p;
                __half2 p2 = __float2half2_rn(p);
                const float4* vr = reinterpret_cast<const float4*>(&s_vh[t2 * 64 + head * 16]);
                F4H v0, v1, v2, v3;
                v0.f = vr[0]; v1.f = vr[1]; v2.f = vr[2]; v3.f = vr[3];
                #pragma unroll
                for (int i = 0; i < 4; ++i) o2[i]      = __hfma2(p2, v0.h[i], o2[i]);
                #pragma unroll
                for (int i = 0; i < 4; ++i) o2[4 + i]  = __hfma2(p2, v1.h[i], o2[4 + i]);
                #pragma unroll
                for (int i = 0; i < 4; ++i) o2[8 + i]  = __hfma2(p2, v2.h[i], o2[8 + i]);
                #pragma unroll
                for (int i = 0; i < 4; ++i) o2[12 + i] = __hfma2(p2, v3.h[i], o2[12 + i]);
            }
            m = mn;
        }
    }
    __syncthreads();
    // normalize (fp32) and publish to s_o
    if (qi < qcnt) {
        float inv = 1.0f / ssum;
        #pragma unroll
        for (int i = 0; i < 16; ++i) {
            float2 of = __half22float2(o2[i]);
            s_o[qi * 132 + head * DH_ + 2 * i]     = of.x * inv;
            s_o[qi * 132 + head * DH_ + 2 * i + 1] = of.y * inv;
        }
    }
    __syncthreads();
    // out-projection (fp32): thread = (col j, query-half); 32 queries per thread
    {
        int j = tid & 127, half = tid >> 7;
        const float* Wo = s_out_w + ((size_t)(li * ET_ + et) * H_ + j) * H_;
        float bo = s_out_b[(size_t)(li * ET_ + et) * H_ + j];
        float acc[32];
        #pragma unroll
        for (int qq = 0; qq < 32; ++qq) acc[qq] = bo;
        #pragma unroll 8
        for (int k4 = 0; k4 < 32; ++k4) {
            float4 w = *reinterpret_cast<const float4*>(&Wo[k4 * 4]);
            #pragma unroll
            for (int qq = 0; qq < 32; ++qq) {
                float4 ov = *reinterpret_cast<const float4*>(&s_o[(half * 32 + qq) * 132 + k4 * 4]);
                acc[qq] += w.x * ov.x + w.y * ov.y + w.z * ov.z + w.w * ov.w;
            }
        }
        #pragma unroll
        for (int qq = 0; qq < 32; ++qq) {
            int qrow = half * 32 + qq;
            if (qrow < qcnt) {
                atomicAdd(&h_new[(size_t)s_dn[qrow] * H_ + j], acc[qq]);
            }
        }
    }
}

// ---------------- LN + exact GELU + residual (spatial); re-zeroes h_new for next layer ----------------

__global__ void k_lngelu(float* __restrict__ h_new, float* __restrict__ h,
                         const float* __restrict__ ln_g, const float* __restrict__ ln_b, int li) {
    int n = blockIdx.x;
    int l = threadIdx.x;  // 0..63
    float v0 = h_new[(size_t)n * H_ + l];
    float v1 = h_new[(size_t)n * H_ + 64 + l];
    h_new[(size_t)n * H_ + l] = 0.0f;
    h_new[(size_t)n * H_ + 64 + l] = 0.0f;
    float s = v0 + v1;
    #pragma unroll
    for (int off = 32; off; off >>= 1) s += __shfl_xor(s, off);
    float mean = s * (1.0f / H_);
    float d0 = v0 - mean, d1 = v1 - mean;
    float vs = d0 * d0 + d1 * d1;
    #pragma unroll
    for (int off = 32; off; off >>= 1) vs += __shfl_xor(vs, off);
    float rstd = rsqrtf(vs * (1.0f / H_) + 1e-5f);
    const float* gg = ln_g + (size_t)li * H_;
    const float* bb = ln_b + (size_t)li * H_;
    float t0 = gelu_exact(d0 * rstd * gg[l] + bb[l]);
    float t1 = gelu_exact(d1 * rstd * gg[64 + l] + bb[64 + l]);
    size_t o = (size_t)n * H_;
    if (li == 0) { h[o + l] = t0; h[o + 64 + l] = t1; }
    else         { h[o + l] += t0; h[o + 64 + l] += t1; }
}

// ---------------- temporal: positional encoding add (in place on h) ----------------

__global__ void k_peadd(float* __restrict__ h) {
    int i = blockIdx.x * blockDim.x + threadIdx.x;
    int stride = gridDim.x * blockDim.x;
    for (; i < N_ * H_; i += stride) {
        int j = i & 127;
        int t = (i >> 7) & 63;
        float dv = __expf((float)(j & ~1) * (-0.0719557841560639f));
        float ang = (float)t * dv;
        float pe = (j & 1) ? cosf(ang) : sinf(ang);
        h[i] += pe;
    }
}

// ---------------- temporal qkv GEMM: block = (node-in-chunk, {q,k,v}) ----------------

__global__ __launch_bounds__(256) void k_tqkv(const float* __restrict__ hs,
                                              const float* __restrict__ t_in_w, const float* __restrict__ t_in_b,
                                              float* __restrict__ qc, float* __restrict__ kc, float* __restrict__ vc,
                                              int li, int c0) {
    int nb = blockIdx.x;        // node in chunk
    int nt = blockIdx.y;        // 0=q 1=k 2=v
    int node = c0 + nb;
    __shared__ float s_a[64 * 132];
    __shared__ float s_b[32 * 132];
    int tid = threadIdx.x;
    #pragma unroll
    for (int i = 0; i < 8; ++i) {
        int idx = i * 256 + tid;
        int r = idx >> 5, c4 = (idx & 31) * 4;
        *reinterpret_cast<float4*>(&s_a[r * 132 + c4]) =
            *reinterpret_cast<const float4*>(&hs[((size_t)node * 64 + r) * 128 + c4]);
    }
    const float* B = t_in_w + ((size_t)li * 384 + nt * 128) * 128;
    const float* bi = t_in_b + (size_t)li * 384 + nt * 128;
    int rg = tid >> 4, cg = tid & 15;
    int r0 = rg * 4;
    float4 alo[4], ahi[4];
    #pragma unroll
    for (int rr = 0; rr < 4; ++rr) { alo[rr] = f4zero(); ahi[rr] = f4zero(); }
    for (int kci = 0; kci < 4; ++kci) {
        __syncthreads();
        #pragma unroll
        for (int i = 0; i < 4; ++i) {
            int idx = i * 256 + tid;
            int jj = idx >> 3, k4 = (idx & 7) * 4;
            float4 w = *reinterpret_cast<const float4*>(&B[(size_t)jj * 128 + kci * 32 + k4]);
            s_b[(k4 + 0) * 132 + jj] = w.x; s_b[(k4 + 1) * 132 + jj] = w.y;
            s_b[(k4 + 2) * 132 + jj] = w.z; s_b[(k4 + 3) * 132 + jj] = w.w;
        }
        __syncthreads();
        #pragma unroll
        for (int k4 = 0; k4 < 8; ++k4) {
            float4 a4[4];
            #pragma unroll
            for (int rr = 0; rr < 4; ++rr)
                a4[rr] = *reinterpret_cast<const float4*>(&s_a[(r0 + rr) * 132 + kci * 32 + k4 * 4]);
            #pragma unroll
            for (int jj = 0; jj < 4; ++jj) {
                float4 blo = *reinterpret_cast<const float4*>(&s_b[(k4 * 4 + jj) * 132 + cg * 4]);
                float4 bhi = *reinterpret_cast<const float4*>(&s_b[(k4 * 4 + jj) * 132 + 64 + cg * 4]);
                #pragma unroll
                for (int rr = 0; rr < 4; ++rr) {
                    float av = (jj == 0) ? a4[rr].x : (jj == 1) ? a4[rr].y : (jj == 2) ? a4[rr].z : a4[rr].w;
                    f4fma(alo[rr], av, blo);
                    f4fma(ahi[rr], av, bhi);
                }
            }
        }
    }
    float* dst = (nt == 0) ? qc : (nt == 1) ? kc : vc;
    float sc = (nt == 0) ? SCALE_ : 1.0f;
    float4 blo = *reinterpret_cast<const float4*>(&bi[cg * 4]);
    float4 bhi = *reinterpret_cast<const float4*>(&bi[64 + cg * 4]);
    #pragma unroll
    for (int rr = 0; rr < 4; ++rr) {
        float4 lo = alo[rr], hi = ahi[rr];
        lo.x = (lo.x + blo.x) * sc; lo.y = (lo.y + blo.y) * sc; lo.z = (lo.z + blo.z) * sc; lo.w = (lo.w + blo.w) * sc;
        hi.x = (hi.x + bhi.x) * sc; hi.y = (hi.y + bhi.y) * sc; hi.z = (hi.z + bhi.z) * sc; hi.w = (hi.w + bhi.w) * sc;
        size_t row = (size_t)nb * 64 + r0 + rr;
        *reinterpret_cast<float4*>(&dst[row * 128 + cg * 4]) = lo;
        *reinterpret_cast<float4*>(&dst[row * 128 + 64 + cg * 4]) = hi;
    }
}

// ---------------- temporal attention: block = (node-in-chunk, head), 64 threads ----------------

__global__ __launch_bounds__(64) void k_tattn(float* __restrict__ qc, const float* __restrict__ kc,
                                              const float* __restrict__ vc) {
    int nb = blockIdx.x, head = blockIdx.y;
    __shared__ float s_k[64 * 36];
    __shared__ float s_v[64 * 36];
    int t = threadIdx.x;
    #pragma unroll
    for (int i = 0; i < 8; ++i) {
        int idx = i * 64 + t;
        int row = idx >> 3, d4 = (idx & 7) * 4;
        *reinterpret_cast<float4*>(&s_k[row * 36 + d4]) =
            *reinterpret_cast<const float4*>(&kc[((size_t)nb * 64 + row) * 128 + head * DH_ + d4]);
        *reinterpret_cast<float4*>(&s_v[row * 36 + d4]) =
            *reinterpret_cast<const float4*>(&vc[((size_t)nb * 64 + row) * 128 + head * DH_ + d4]);
    }
    float4 q[8];
    {
        const float4* qr = reinterpret_cast<const float4*>(&qc[((size_t)nb * 64 + t) * 128 + head * DH_]);
        #pragma unroll
        for (int i = 0; i < 8; ++i) q[i] = qr[i];
    }
    __syncthreads();
    float m = -1e30f;
    for (int t2 = 0; t2 < 64; ++t2) {
        const float4* kr = reinterpret_cast<const float4*>(&s_k[t2 * 36]);
        float s0 = 0, s1 = 0, s2 = 0, s3 = 0;
        #pragma unroll
        for (int i = 0; i < 8; ++i) {
            float4 kk = kr[i];
            s0 += q[i].x * kk.x; s1 += q[i].y * kk.y; s2 += q[i].z * kk.z; s3 += q[i].w * kk.w;
        }
        m = fmaxf(m, (s0 + s1) + (s2 + s3));
    }
    float ssum = 0.0f;
    float4 o[8];
    #pragma unroll
    for (int i = 0; i < 8; ++i) o[i] = f4zero();
    for (int t2 = 0; t2 < 64; ++t2) {
        const float4* kr = reinterpret_cast<const float4*>(&s_k[t2 * 36]);
        float s0 = 0, s1 = 0, s2 = 0, s3 = 0;
        #pragma unroll
        for (int i = 0; i < 8; ++i) {
            float4 kk = kr[i];
            s0 += q[i].x * kk.x; s1 += q[i].y * kk.y; s2 += q[i].z * kk.z; s3 += q[i].w * kk.w;
        }
        float p = __expf((s0 + s1) + (s2 + s3) - m);
        ssum += p;
        const float4* vr = reinterpret_cast<const float4*>(&s_v[t2 * 36]);
        #pragma unroll
        for (int i = 0; i < 8; ++i) f4fma(o[i], p, vr[i]);
    }
    float inv = 1.0f / ssum;
    float4* orow = reinterpret_cast<float4*>(&qc[((size_t)nb * 64 + t) * 128 + head * DH_]);
    #pragma unroll
    for (int i = 0; i < 8; ++i) { float4 v = o[i]; f4scale(v, inv); orow[i] = v; }
}

// ---------------- temporal out-proj + residual + LN1 ----------------

__global__ __launch_bounds__(256) void k_toutln(const float* __restrict__ oc, float* __restrict__ hs,
                                                const float* __restrict__ t_out_w, const float* __restrict__ t_out_b,
                                                const float* __restrict__ ln_g, const float* __restrict__ ln_b,
                                                int li, int c0) {
    int nb = blockIdx.x;
    int node = c0 + nb;
    __shared__ float s_a[64 * 132];
    __shared__ float s_b[32 * 132];
    int tid = threadIdx.x;
    #pragma unroll
    for (int i = 0; i < 8; ++i) {
        int idx = i * 256 + tid;
        int r = idx >> 5, c4 = (idx & 31) * 4;
        *reinterpret_cast<float4*>(&s_a[r * 132 + c4]) =
            *reinterpret_cast<const float4*>(&oc[((size_t)nb * 64 + r) * 128 + c4]);
    }
    const float* B = t_out_w + (size_t)li * 128 * 128;
    const float* bo = t_out_b + (size_t)li * 128;
    int rg = tid >> 4, cg = tid & 15;
    int r0 = rg * 4;
    float4 alo[4], ahi[4];
    #pragma unroll
    for (int rr = 0; rr < 4; ++rr) { alo[rr] = f4zero(); ahi[rr] = f4zero(); }
    for (int kci = 0; kci < 4; ++kci) {
        __syncthreads();
        #pragma unroll
        for (int i = 0; i < 4; ++i) {
            int idx = i * 256 + tid;
            int jj = idx >> 3, k4 = (idx & 7) * 4;
            float4 w = *reinterpret_cast<const float4*>(&B[(size_t)jj * 128 + kci * 32 + k4]);
            s_b[(k4 + 0) * 132 + jj] = w.x; s_b[(k4 + 1) * 132 + jj] = w.y;
            s_b[(k4 + 2) * 132 + jj] = w.z; s_b[(k4 + 3) * 132 + jj] = w.w;
        }
        __syncthreads();
        #pragma unroll
        for (int k4 = 0; k4 < 8; ++k4) {
            float4 a4[4];
            #pragma unroll
            for (int rr = 0; rr < 4; ++rr)
                a4[rr] = *reinterpret_cast<const float4*>(&s_a[(r0 + rr) * 132 + kci * 32 + k4 * 4]);
            #pragma unroll
            for (int jj = 0; jj < 4; ++jj) {
                float4 blo = *reinterpret_cast<const float4*>(&s_b[(k4 * 4 + jj) * 132 + cg * 4]);
                float4 bhi = *reinterpret_cast<const float4*>(&s_b[(k4 * 4 + jj) * 132 + 64 + cg * 4]);
                #pragma unroll
                for (int rr = 0; rr < 4; ++rr) {
                    float av = (jj == 0) ? a4[rr].x : (jj == 1) ? a4[rr].y : (jj == 2) ? a4[rr].z : a4[rr].w;
                    f4fma(alo[rr], av, blo);
                    f4fma(ahi[rr], av, bhi);
                }
            }
        }
    }
    float4 bblo = *reinterpret_cast<const float4*>(&bo[cg * 4]);
    float4 bbhi = *reinterpret_cast<const float4*>(&bo[64 + cg * 4]);
    float4 glo = *reinterpret_cast<const float4*>(&ln_g[(size_t)li * 128 + cg * 4]);
    float4 ghi = *reinterpret_cast<const float4*>(&ln_g[(size_t)li * 128 + 64 + cg * 4]);
    float4 lblo = *reinterpret_cast<const float4*>(&ln_b[(size_t)li * 128 + cg * 4]);
    float4 lbhi = *reinterpret_cast<const float4*>(&ln_b[(size_t)li * 128 + 64 + cg * 4]);
    #pragma unroll
    for (int rr = 0; rr < 4; ++rr) {
        size_t row = (size_t)node * 64 + r0 + rr;
        float4 rlo = *reinterpret_cast<const float4*>(&hs[row * 128 + cg * 4]);
        float4 rhi = *reinterpret_cast<const float4*>(&hs[row * 128 + 64 + cg * 4]);
        float4 lo = alo[rr], hi = ahi[rr];
        lo.x += bblo.x + rlo.x; lo.y += bblo.y + rlo.y; lo.z += bblo.z + rlo.z; lo.w += bblo.w + rlo.w;
        hi.x += bbhi.x + rhi.x; hi.y += bbhi.y + rhi.y; hi.z += bbhi.z + rhi.z; hi.w += bbhi.w + rhi.w;
        float s = lo.x + lo.y + lo.z + lo.w + hi.x + hi.y + hi.z + hi.w;
        s += __shfl_xor(s, 1); s += __shfl_xor(s, 2); s += __shfl_xor(s, 4); s += __shfl_xor(s, 8);
        float mean = s * (1.0f / 128.0f);
        float4 dlo = make_float4(lo.x - mean, lo.y - mean, lo.z - mean, lo.w - mean);
        float4 dhi = make_float4(hi.x - mean, hi.y - mean, hi.z - mean, hi.w - mean);
        float vx = dlo.x * dlo.x + dlo.y * dlo.y + dlo.z * dlo.z + dlo.w * dlo.w +
                   dhi.x * dhi.x + dhi.y * dhi.y + dhi.z * dhi.z + dhi.w * dhi.w;
        vx += __shfl_xor(vx, 1); vx += __shfl_xor(vx, 2); vx += __shfl_xor(vx, 4); vx += __shfl_xor(vx, 8);
        float rstd = rsqrtf(vx * (1.0f / 128.0f) + 1e-5f);
        float4 olo = make_float4(dlo.x * rstd * glo.x + lblo.x, dlo.y * rstd * glo.y + lblo.y,
                                 dlo.z * rstd * glo.z + lblo.z, dlo.w * rstd * glo.w + lblo.w);
        float4 ohi = make_float4(dhi.x * rstd * ghi.x + lbhi.x, dhi.y * rstd * ghi.y + lbhi.y,
                                 dhi.z * rstd * ghi.z + lbhi.z, dhi.w * rstd * ghi.w + lbhi.w);
        *reinterpret_cast<float4*>(&hs[row * 128 + cg * 4]) = olo;
        *reinterpret_cast<float4*>(&hs[row * 128 + 64 + cg * 4]) = ohi;
    }
}

// ---------------- temporal fused FF (FF1+gelu+FF2) + residual + LN2 ----------------

__global__ __launch_bounds__(256) void k_tff(float* __restrict__ hs,
                                             const float* __restrict__ t_w1, const float* __restrict__ t_b1,
                                             const float* __restrict__ t_w2, const float* __restrict__ t_b2,
                                             const float* __restrict__ ln_g, const float* __restrict__ ln_b,
                                             int li) {
    int node = blockIdx.x;
    __shared__ float s_h[64 * 132];
    __shared__ float s_f[64 * 132];
    __shared__ float s_b[16 * 132];
    int tid = threadIdx.x;
    #pragma unroll
    for (int i = 0; i < 8; ++i) {
        int idx = i * 256 + tid;
        int r = idx >> 5, c4 = (idx & 31) * 4;
        *reinterpret_cast<float4*>(&s_h[r * 132 + c4]) =
            *reinterpret_cast<const float4*>(&hs[((size_t)node * 64 + r) * 128 + c4]);
    }
    __syncthreads();
    int rg = tid >> 4, cg = tid & 15;
    int r0 = rg * 4;
    const float* W1 = t_w1 + (size_t)li * FF_ * 128;
    const float* b1 = t_b1 + (size_t)li * FF_;
    const float* W2 = t_w2 + (size_t)li * 128 * FF_;
    const float* b2 = t_b2 + (size_t)li * 128;
    float4 c2lo[4], c2hi[4];
    #pragma unroll
    for (int rr = 0; rr < 4; ++rr) { c2lo[rr] = f4zero(); c2hi[rr] = f4zero(); }

    for (int nt = 0; nt < 4; ++nt) {
        float4 c1lo[4], c1hi[4];
        #pragma unroll
        for (int rr = 0; rr < 4; ++rr) { c1lo[rr] = f4zero(); c1hi[rr] = f4zero(); }
        for (int kci = 0; kci < 8; ++kci) {
            #pragma unroll
            for (int i = 0; i < 2; ++i) {
                int idx = i * 256 + tid;
                int jj = idx >> 2, k4 = (idx & 3) * 4;
                float4 w = *reinterpret_cast<const float4*>(&W1[(size_t)(nt * 128 + jj) * 128 + kci * 16 + k4]);
                s_b[(k4 + 0) * 132 + jj] = w.x; s_b[(k4 + 1) * 132 + jj] = w.y;
                s_b[(k4 + 2) * 132 + jj] = w.z; s_b[(k4 + 3) * 132 + jj] = w.w;
            }
            __syncthreads();
            #pragma unroll
            for (int k4 = 0; k4 < 4; ++k4) {
                float4 a4[4];
                #pragma unroll
                for (int rr = 0; rr < 4; ++rr)
                    a4[rr] = *reinterpret_cast<const float4*>(&s_h[(r0 + rr) * 132 + kci * 16 + k4 * 4]);
                #pragma unroll
                for (int jj = 0; jj < 4; ++jj) {
                    float4 blo = *reinterpret_cast<const float4*>(&s_b[(k4 * 4 + jj) * 132 + cg * 4]);
                    float4 bhi = *reinterpret_cast<const float4*>(&s_b[(k4 * 4 + jj) * 132 + 64 + cg * 4]);
                    #pragma unroll
                    for (int rr = 0; rr < 4; ++rr) {
                        float av = (jj == 0) ? a4[rr].x : (jj == 1) ? a4[rr].y : (jj == 2) ? a4[rr].z : a4[rr].w;
                        f4fma(c1lo[rr], av, blo);
                        f4fma(c1hi[rr], av, bhi);
                    }
                }
            }
            __syncthreads();
        }
        {
            float4 blo = *reinterpret_cast<const float4*>(&b1[nt * 128 + cg * 4]);
            float4 bhi = *reinterpret_cast<const float4*>(&b1[nt * 128 + 64 + cg * 4]);
            #pragma unroll
            for (int rr = 0; rr < 4; ++rr) {
                float4 lo = c1lo[rr], hi = c1hi[rr];
                lo.x = gelu_exact(lo.x + blo.x); lo.y = gelu_exact(lo.y + blo.y);
                lo.z = gelu_exact(lo.z + blo.z); lo.w = gelu_exact(lo.w + blo.w);
                hi.x = gelu_exact(hi.x + bhi.x); hi.y = gelu_exact(hi.y + bhi.y);
                hi.z = gelu_exact(hi.z + bhi.z); hi.w = gelu_exact(hi.w + bhi.w);
                *reinterpret_cast<float4*>(&s_f[(r0 + rr) * 132 + cg * 4]) = lo;
                *reinterpret_cast<float4*>(&s_f[(r0 + rr) * 132 + 64 + cg * 4]) = hi;
            }
        }
        __syncthreads();
        for (int kci = 0; kci < 8; ++kci) {
            #pragma unroll
            for (int i = 0; i < 2; ++i) {
                int idx = i * 256 + tid;
                int jj = idx >> 2, k4 = (idx & 3) * 4;
                float4 w = *reinterpret_cast<const float4*>(&W2[(size_t)jj * FF_ + nt * 128 + kci * 16 + k4]);
                s_b[(k4 + 0) * 132 + jj] = w.x; s_b[(k4 + 1) * 132 + jj] = w.y;
                s_b[(k4 + 2) * 132 + jj] = w.z; s_b[(k4 + 3) * 132 + jj] = w.w;
            }
            __syncthreads();
            #pragma unroll
            for (int k4 = 0; k4 < 4; ++k4) {
                float4 a4[4];
                #pragma unroll
                for (int rr = 0; rr < 4; ++rr)
                    a4[rr] = *reinterpret_cast<const float4*>(&s_f[(r0 + rr) * 132 + kci * 16 + k4 * 4]);
                #pragma unroll
                for (int jj = 0; jj < 4; ++jj) {
                    float4 blo = *reinterpret_cast<const float4*>(&s_b[(k4 * 4 + jj) * 132 + cg * 4]);
                    float4 bhi = *reinterpret_cast<const float4*>(&s_b[(k4 * 4 + jj) * 132 + 64 + cg * 4]);
                    #pragma unroll
                    for (int rr = 0; rr < 4; ++rr) {
                        float av = (jj == 0) ? a4[rr].x : (jj == 1) ? a4[rr].y : (jj == 2) ? a4[rr].z : a4[rr].w;
                        f4fma(c2lo[rr], av, blo);
                        f4fma(c2hi[rr], av, bhi);
                    }
                }
            }
            __syncthreads();
        }
    }
    float4 bblo = *reinterpret_cast<const float4*>(&b2[cg * 4]);
    float4 bbhi = *reinterpret_cast<const float4*>(&b2[64 + cg * 4]);
    float4 glo = *reinterpret_cast<const float4*>(&ln_g[(size_t)li * 128 + cg * 4]);
    float4 ghi = *reinterpret_cast<const float4*>(&ln_g[(size_t)li * 128 + 64 + cg * 4]);
    float4 lblo = *reinterpret_cast<const float4*>(&ln_b[(size_t)li * 128 + cg * 4]);
    float4 lbhi = *reinterpret_cast<const float4*>(&ln_b[(size_t)li * 128 + 64 + cg * 4]);
    #pragma unroll
    for (int rr = 0; rr < 4; ++rr) {
        size_t row = (size_t)node * 64 + r0 + rr;
        float4 rlo = *reinterpret_cast<const float4*>(&s_h[(r0 + rr) * 132 + cg * 4]);
        float4 rhi = *reinterpret_cast<const float4*>(&s_h[(r0 + rr) * 132 + 64 + cg * 4]);
        float4 lo = c2lo[rr], hi = c2hi[rr];
        lo.x += bblo.x + rlo.x; lo.y += bblo.y + rlo.y; lo.z += bblo.z + rlo.z; lo.w += bblo.w + rlo.w;
        hi.x += bbhi.x + rhi.x; hi.y += bbhi.y + rhi.y; hi.z += bbhi.z + rhi.z; hi.w += bbhi.w + rhi.w;
        float s = lo.x + lo.y + lo.z + lo.w + hi.x + hi.y + hi.z + hi.w;
        s += __shfl_xor(s, 1); s += __shfl_xor(s, 2); s += __shfl_xor(s, 4); s += __shfl_xor(s, 8);
        float mean = s * (1.0f / 128.0f);
        float4 dlo = make_float4(lo.x - mean, lo.y - mean, lo.z - mean, lo.w - mean);
        float4 dhi = make_float4(hi.x - mean, hi.y - mean, hi.z - mean, hi.w - mean);
        float vx = dlo.x * dlo.x + dlo.y * dlo.y + dlo.z * dlo.z + dlo.w * dlo.w +
                   dhi.x * dhi.x + dhi.y * dhi.y + dhi.z * dhi.z + dhi.w * dhi.w;
        vx += __shfl_xor(vx, 1); vx += __shfl_xor(vx, 2); vx += __shfl_xor(vx, 4); vx += __shfl_xor(vx, 8);
        float rstd = rsqrtf(vx * (1.0f / 128.0f) + 1e-5f);
        float4 olo = make_float4(dlo.x * rstd * glo.x + lblo.x, dlo.y * rstd * glo.y + lblo.y,
                                 dlo.z * rstd * glo.z + lblo.z, dlo.w * rstd * glo.w + lblo.w);
        float4 ohi = make_float4(dhi.x * rstd * ghi.x + lbhi.x, dhi.y * rstd * ghi.y + lbhi.y,
                                 dhi.z * rstd * ghi.z + lbhi.z, dhi.w * rstd * ghi.w + lbhi.w);
        *reinterpret_cast<float4*>(&hs[row * 128 + cg * 4]) = olo;
        *reinterpret_cast<float4*>(&hs[row * 128 + 64 + cg * 4]) = ohi;
    }
}

// ---------------- final LN -> out ----------------

__global__ __launch_bounds__(256) void k_fln(const float* __restrict__ hs, float* __restrict__ out,
                                             const float* __restrict__ g, const float* __restrict__ b) {
    int row = blockIdx.x * 4 + (threadIdx.x >> 6);
    int l = threadIdx.x & 63;
    float v0 = hs[(size_t)row * H_ + l];
    float v1 = hs[(size_t)row * H_ + 64 + l];
    float s = v0 + v1;
    #pragma unroll
    for (int off = 32; off; off >>= 1) s += __shfl_xor(s, off);
    float mean = s * (1.0f / H_);
    float d0 = v0 - mean, d1 = v1 - mean;
    float vs = d0 * d0 + d1 * d1;
    #pragma unroll
    for (int off = 32; off; off >>= 1) vs += __shfl_xor(vs, off);
    float rstd = rsqrtf(vs * (1.0f / H_) + 1e-5f);
    out[(size_t)row * H_ + l] = d0 * rstd * g[l] + b[l];
    out[(size_t)row * H_ + 64 + l] = d1 * rstd * g[64 + l] + b[64 + l];
}

// ---------------- launch ----------------

extern "C" void kernel_launch(void* const* d_in, const int* in_sizes, int n_in,
                              void* d_out, int out_size, void* d_ws, size_t ws_size,
                              hipStream_t stream) {
    const float* x          = (const float*)d_in[0];
    const int*   edge_index = (const int*)d_in[1];
    const int*   edge_type  = (const int*)d_in[2];
    const int*   node_type  = (const int*)d_in[3];
    const float* W_in    = (const float*)d_in[6];
    const float* b_in    = (const float*)d_in[7];
    const float* s_in_w  = (const float*)d_in[8];
    const float* s_in_b  = (const float*)d_in[9];
    const float* s_out_w = (const float*)d_in[10];
    const float* s_out_b = (const float*)d_in[11];
    const float* ln_s_g  = (const float*)d_in[12];
    const float* ln_s_b  = (const float*)d_in[13];
    const float* t_in_w  = (const float*)d_in[14];
    const float* t_in_b  = (const float*)d_in[15];
    const float* t_out_w = (const float*)d_in[16];
    const float* t_out_b = (const float*)d_in[17];
    const float* t_ln1_g = (const float*)d_in[18];
    const float* t_ln1_b = (const float*)d_in[19];
    const float* t_w1    = (const float*)d_in[20];
    const float* t_b1    = (const float*)d_in[21];
    const float* t_w2    = (const float*)d_in[22];
    const float* t_b2    = (const float*)d_in[23];
    const float* t_ln2_g = (const float*)d_in[24];
    const float* t_ln2_b = (const float*)d_in[25];
    const float* fin_g   = (const float*)d_in[26];
    const float* fin_b   = (const float*)d_in[27];
    float* out = (float*)d_out;

    // workspace layout (floats)
    float* h     = (float*)d_ws;                       // N*H = 8388608
    float* h_new = h + (size_t)N_ * H_;                // 8388608
    float* qkv   = h_new + (size_t)N_ * H_;            // E*384 = 11520000
    int* sorted  = (int*)(qkv + (size_t)E_ * 384);     // E
    int* gpos    = sorted + E_;                        // E
    int* gedge   = gpos + E_;                          // E
    int* cnt     = gedge + E_;                         // 64
    int* offs    = cnt + 64;                           // 64
    int* curs    = offs + 64;                          // 64
    int* nd64    = curs + 64;                          // 16
    int2* desc64 = (int2*)(nd64 + 16);                 // 544 int2

    // temporal chunk buffers (alias spatial regions, used after spatial completes)
    float* qc = qkv;                                   // CH*64*128 = 4194304
    float* kc = qkv + (size_t)CH_ * 64 * 128;          // 4194304
    float* vc = h_new;                                 // 4194304

    k_zero_cnt<<<1, 64, 0, stream>>>(cnt);
    k_hist<<<(E_ + 255) / 256, 256, 0, stream>>>(edge_index, edge_type, node_type, gedge, cnt);
    k_scan<<<1, 1, 0, stream>>>(cnt, offs, curs);
    k_scatter<<<(E_ + 255) / 256, 256, 0, stream>>>(gedge, curs, sorted, gpos);
    k_desc<<<1, 1, 0, stream>>>(offs, desc64, nd64);

    k_inproj<<<N_, 128, 0, stream>>>(x, node_type, W_in, b_in, h);

    k_zero<<<2048, 256, 0, stream>>>(h_new, N_ * H_);   // layer 0; later layers zeroed by k_lngelu
    for (int li = 0; li < L_; ++li) {
        k_sqkv_gemm<<<dim3(GATTN_GRID, 3), 256, 0, stream>>>(h, s_in_w, s_in_b, sorted, offs, edge_index,
                                                             desc64, nd64, qkv, li);
        k_gattn<<<GATTN_GRID, 256, 0, stream>>>(qkv, sorted, offs, edge_index, desc64, nd64,
                                                s_out_w, s_out_b, h_new, li);
        k_lngelu<<<N_, 64, 0, stream>>>(h_new, h, ln_s_g, ln_s_b, li);
    }

    // temporal: hs = h + PE (in place)
    k_peadd<<<2048, 256, 0, stream>>>(h);
    for (int li = 0; li < TL_; ++li) {
        for (int c = 0; c < NB_ / CH_; ++c) {
            int c0 = c * CH_;
            k_tqkv<<<dim3(CH_, 3), 256, 0, stream>>>(h, t_in_w, t_in_b, qc, kc, vc, li, c0);
            k_tattn<<<dim3(CH_, NH_), 64, 0, stream>>>(qc, kc, vc);
            k_toutln<<<CH_, 256, 0, stream>>>(qc, h, t_out_w, t_out_b, t_ln1_g, t_ln1_b, li, c0);
        }
        k_tff<<<NB_, 256, 0, stream>>>(h, t_w1, t_b1, t_w2, t_b2, t_ln2_g, t_ln2_b, li);
    }
    k_fln<<<N_ / 4, 256, 0, stream>>>(h, out, fin_g, fin_b);
}

// Round 11
// 1825.476 us; speedup vs baseline: 1.3161x; 1.1061x over previous
//
#include <hip/hip_runtime.h>
#include <hip/hip_bf16.h>
#include <hip/hip_fp16.h>
#include <math.h>

// Problem constants (fixed by reference)
#define N_   65536
#define F_   64
#define H_   128
#define E_   30000
#define NT_  5
#define ET_  10
#define NG_  50
#define L_   3
#define TL_  2
#define NH_  4
#define DH_  32
#define NB_  1024
#define TT_  64
#define FF_  512
#define CH_  512         // temporal node chunk
#define GATTN_GRID 544

#define SCALE_ 0.17677669529663687f   // 1/sqrt(32)

typedef _Float16 hh2 __attribute__((ext_vector_type(2)));

__device__ __forceinline__ float gelu_exact(float x) {
    return 0.5f * x * (1.0f + erff(x * 0.70710678118654752f));
}
__device__ __forceinline__ void f4fma(float4& a, float s, const float4& b) {
    a.x += s * b.x; a.y += s * b.y; a.z += s * b.z; a.w += s * b.w;
}
__device__ __forceinline__ void f4scale(float4& a, float s) {
    a.x *= s; a.y *= s; a.z *= s; a.w *= s;
}
__device__ __forceinline__ float4 f4zero() { return make_float4(0.f, 0.f, 0.f, 0.f); }
__device__ __forceinline__ hh2 f2h2(float a, float b) {
    hh2 r; r[0] = (_Float16)a; r[1] = (_Float16)b; return r;
}
#define FDOT2(a, b, c) __builtin_amdgcn_fdot2((a), (b), (c), false)

union F4H { float4 f; __half2 h[4]; };   // fp16-attn helper (float4 = 4 half2)
union U4H2 { float4 f; hh2 h[4]; };      // read 4 hh2 as one b128

// ---------------- grouping ----------------

__global__ void k_zero_cnt(int* cnt) {
    if (threadIdx.x < NG_) cnt[threadIdx.x] = 0;
}

__global__ void k_hist(const int* __restrict__ edge_index, const int* __restrict__ edge_type,
                       const int* __restrict__ node_type, int* __restrict__ gedge, int* __restrict__ cnt) {
    int e = blockIdx.x * blockDim.x + threadIdx.x;
    if (e >= E_) return;
    int dn = edge_index[E_ + e];
    int g = edge_type[e] * NT_ + node_type[dn];
    gedge[e] = g;
    atomicAdd(&cnt[g], 1);
}

__global__ void k_scan(const int* __restrict__ cnt, int* __restrict__ offs, int* __restrict__ curs) {
    if (threadIdx.x == 0 && blockIdx.x == 0) {
        int acc = 0;
        for (int g = 0; g < NG_; ++g) { offs[g] = acc; curs[g] = acc; acc += cnt[g]; }
        offs[NG_] = acc;
    }
}

__global__ void k_scatter(const int* __restrict__ gedge, int* __restrict__ curs,
                          int* __restrict__ sorted, int* __restrict__ gpos) {
    int e = blockIdx.x * blockDim.x + threadIdx.x;
    if (e >= E_) return;
    int g = gedge[e];
    int pos = atomicAdd(&curs[g], 1);
    sorted[pos] = e;
    gpos[pos] = g;
}

__global__ void k_desc(const int* __restrict__ offs, int2* __restrict__ desc64, int* __restrict__ nd64) {
    if (threadIdx.x || blockIdx.x) return;
    int n64 = 0;
    for (int g = 0; g < NG_; ++g) {
        int sz = offs[g + 1] - offs[g];
        for (int qs = 0; qs < sz; qs += 64) desc64[n64++] = make_int2(g, qs);
    }
    nd64[0] = n64;
}

// ---------------- input projection ----------------

__global__ void k_inproj(const float* __restrict__ x, const int* __restrict__ node_type,
                         const float* __restrict__ W_in, const float* __restrict__ b_in,
                         float* __restrict__ h) {
    int n = blockIdx.x;
    int j = threadIdx.x;  // 0..127
    __shared__ float sx[F_];
    if (j < F_) sx[j] = x[(size_t)n * F_ + j];
    __syncthreads();
    int nt = node_type[n];
    const float* W = W_in + (size_t)nt * F_ * H_;
    float acc = b_in[(size_t)nt * H_ + j];
    #pragma unroll 8
    for (int f = 0; f < F_; ++f) acc += sx[f] * W[(size_t)f * H_ + j];
    h[(size_t)n * H_ + j] = acc;
}

__global__ void k_zero(float* __restrict__ p, int n) {
    int i = blockIdx.x * blockDim.x + threadIdx.x;
    int stride = gridDim.x * blockDim.x;
    for (; i < n; i += stride) p[i] = 0.0f;
}

// ---------------- spatial qkv projection: fp16/fdot2 tiled GEMM over 64-edge tiles ----------------
// grid = (544, 3); y: 0=q (dst rows), 1=k, 2=v (src rows)

__global__ __launch_bounds__(256) void k_sqkv_gemm(
    const float* __restrict__ h, const float* __restrict__ s_in_w, const float* __restrict__ s_in_b,
    const int* __restrict__ sorted, const int* __restrict__ offs, const int* __restrict__ edge_index,
    const int2* __restrict__ desc64, const int* __restrict__ nd64,
    float* __restrict__ qkv, int li) {
    int bx = blockIdx.x;
    if (bx >= nd64[0]) return;
    int2 dd = desc64[bx];
    int g = dd.x, qs = dd.y;
    int qbase = offs[g] + qs;
    int qcnt = min(64, offs[g + 1] - qbase);
    int et = g / NT_;
    int nt = blockIdx.y;
    __shared__ hh2 s_ah[64 * 67];    // A fp16: [64 rows][64 h2 + pad]
    __shared__ hh2 s_bh[16 * 132];   // B fp16 transposed: [k2][col]
    int tid = threadIdx.x;
    // gather 64 input rows (dst for q, src for k/v), convert to fp16
    #pragma unroll
    for (int i = 0; i < 8; ++i) {
        int idx = i * 256 + tid;
        int r = idx >> 5, c4i = idx & 31;
        int p = qbase + min(r, qcnt - 1);
        int e = sorted[p];
        int node = (nt == 0) ? edge_index[E_ + e] : edge_index[e];
        float4 v = *reinterpret_cast<const float4*>(&h[(size_t)node * H_ + c4i * 4]);
        s_ah[r * 67 + c4i * 2]     = f2h2(v.x, v.y);
        s_ah[r * 67 + c4i * 2 + 1] = f2h2(v.z, v.w);
    }
    const float* B = s_in_w + ((size_t)(li * ET_ + et) * 3 * H_ + nt * H_) * H_;
    const float* bi = s_in_b + (size_t)(li * ET_ + et) * 3 * H_ + nt * H_;
    int rg = tid >> 4, cg = tid & 15;
    int r0 = rg * 4;
    float4 alo[4], ahi[4];
    #pragma unroll
    for (int rr = 0; rr < 4; ++rr) { alo[rr] = f4zero(); ahi[rr] = f4zero(); }
    for (int kci = 0; kci < 4; ++kci) {
        __syncthreads();
        #pragma unroll
        for (int i = 0; i < 4; ++i) {
            int idx = i * 256 + tid;
            int jj = idx >> 3, k4 = (idx & 7) * 4;
            float4 w = *reinterpret_cast<const float4*>(&B[(size_t)jj * H_ + kci * 32 + k4]);
            int k2 = k4 >> 1;
            s_bh[k2 * 132 + jj]       = f2h2(w.x, w.y);
            s_bh[(k2 + 1) * 132 + jj] = f2h2(w.z, w.w);
        }
        __syncthreads();
        #pragma unroll
        for (int k2 = 0; k2 < 16; ++k2) {
            hh2 a2[4];
            #pragma unroll
            for (int rr = 0; rr < 4; ++rr) a2[rr] = s_ah[(r0 + rr) * 67 + kci * 16 + k2];
            U4H2 bl, bh_;
            bl.f  = *reinterpret_cast<const float4*>(&s_bh[k2 * 132 + cg * 4]);
            bh_.f = *reinterpret_cast<const float4*>(&s_bh[k2 * 132 + 64 + cg * 4]);
            #pragma unroll
            for (int rr = 0; rr < 4; ++rr) {
                alo[rr].x = FDOT2(a2[rr], bl.h[0], alo[rr].x);
                alo[rr].y = FDOT2(a2[rr], bl.h[1], alo[rr].y);
                alo[rr].z = FDOT2(a2[rr], bl.h[2], alo[rr].z);
                alo[rr].w = FDOT2(a2[rr], bl.h[3], alo[rr].w);
                ahi[rr].x = FDOT2(a2[rr], bh_.h[0], ahi[rr].x);
                ahi[rr].y = FDOT2(a2[rr], bh_.h[1], ahi[rr].y);
                ahi[rr].z = FDOT2(a2[rr], bh_.h[2], ahi[rr].z);
                ahi[rr].w = FDOT2(a2[rr], bh_.h[3], ahi[rr].w);
            }
        }
    }
    float4 blo = *reinterpret_cast<const float4*>(&bi[cg * 4]);
    float4 bhi = *reinterpret_cast<const float4*>(&bi[64 + cg * 4]);
    #pragma unroll
    for (int rr = 0; rr < 4; ++rr) {
        int row = r0 + rr;
        if (row < qcnt) {
            float* op = qkv + (size_t)(qbase + row) * 384 + nt * H_;
            float4 lo = alo[rr], hi = ahi[rr];
            lo.x += blo.x; lo.y += blo.y; lo.z += blo.z; lo.w += blo.w;
            hi.x += bhi.x; hi.y += bhi.y; hi.z += bhi.z; hi.w += bhi.w;
            *reinterpret_cast<float4*>(op + cg * 4) = lo;
            *reinterpret_cast<float4*>(op + 64 + cg * 4) = hi;
        }
    }
}

// ---------------- grouped spatial attention + out-proj + scatter (fp16 hfma2, unchanged) ----------------

__global__ __launch_bounds__(256, 2) void k_gattn(
    const float* __restrict__ qkv, const int* __restrict__ sorted,
    const int* __restrict__ offs, const int* __restrict__ edge_index,
    const int2* __restrict__ desc, const int* __restrict__ ndesc,
    const float* __restrict__ s_out_w, const float* __restrict__ s_out_b,
    float* __restrict__ h_new, int li) {
    int bx = blockIdx.x;
    if (bx >= ndesc[0]) return;
    int2 dd = desc[bx];
    int g = dd.x, qs = dd.y;
    int start = offs[g], end = offs[g + 1];
    int qbase = start + qs;
    int qcnt = min(64, end - qbase);
    int et = g / NT_;

    __shared__ __half2 s_kh[32 * 64];
    __shared__ __half2 s_vh[32 * 64];
    __shared__ float  s_o[64 * 132];
    __shared__ int    s_dn[64];
    int tid = threadIdx.x;
    int head = tid >> 6, qi = tid & 63;

    if (tid < 64) s_dn[tid] = edge_index[E_ + sorted[qbase + min(tid, qcnt - 1)]];

    int p0 = qbase + min(qi, qcnt - 1);
    __half2 q2[16];
    {
        const float4* qr = reinterpret_cast<const float4*>(&qkv[(size_t)p0 * 384 + head * DH_]);
        #pragma unroll
        for (int i = 0; i < 8; ++i) {
            float4 qf = qr[i];
            q2[2 * i]     = __floats2half2_rn(qf.x, qf.y);
            q2[2 * i + 1] = __floats2half2_rn(qf.z, qf.w);
        }
    }
    float m = -1e30f, ssum = 0.0f;
    __half2 o2[16];
    #pragma unroll
    for (int i = 0; i < 16; ++i) o2[i] = __floats2half2_rn(0.f, 0.f);

    int nkt = (end - start + 31) >> 5;
    for (int kt = 0; kt < nkt; ++kt) {
        int kb = start + kt * 32;
        int kcnt = min(32, end - kb);
        __syncthreads();
        #pragma unroll
        for (int i = 0; i < 8; ++i) {
            int idx = i * 256 + tid;
            int row = idx >> 6, c4 = idx & 63;
            if (row < kcnt) {
                float4 w = *reinterpret_cast<const float4*>(&qkv[(size_t)(kb + row) * 384 + 128 + c4 * 4]);
                __half2 h0 = __floats2half2_rn(w.x, w.y);
                __half2 h1 = __floats2half2_rn(w.z, w.w);
                int c = c4 * 4;
                if (c < 128) {
                    s_kh[row * 64 + (c >> 1)] = h0;
                    s_kh[row * 64 + (c >> 1) + 1] = h1;
                } else {
                    int cc = c - 128;
                    s_vh[row * 64 + (cc >> 1)] = h0;
                    s_vh[row * 64 + (cc >> 1) + 1] = h1;
                }
            }
        }
        __syncthreads();
        if (kcnt == 32) {
            float sc[32];
            float tmax = -1e30f;
            #pragma unroll
            for (int t2 = 0; t2 < 32; ++t2) {
                const float4* kr = reinterpret_cast<const float4*>(&s_kh[t2 * 64 + head * 16]);
                F4H k0, k1, k2, k3;
                k0.f = kr[0]; k1.f = kr[1]; k2.f = kr[2]; k3.f = kr[3];
                __half2 acc = __hmul2(q2[0], k0.h[0]);
                #pragma unroll
                for (int i = 1; i < 4; ++i) acc = __hfma2(q2[i], k0.h[i], acc);
                #pragma unroll
                for (int i = 0; i < 4; ++i) acc = __hfma2(q2[4 + i], k1.h[i], acc);
                #pragma unroll
                for (int i = 0; i < 4; ++i) acc = __hfma2(q2[8 + i], k2.h[i], acc);
                #pragma unroll
                for (int i = 0; i < 4; ++i) acc = __hfma2(q2[12 + i], k3.h[i], acc);
                float dot = (__low2float(acc) + __high2float(acc)) * SCALE_;
                sc[t2] = dot;
                tmax = fmaxf(tmax, dot);
            }
            float mn = fmaxf(m, tmax);
            float f = __expf(m - mn);
            ssum *= f;
            __half2 f2 = __float2half2_rn(f);
            #pragma unroll
            for (int i = 0; i < 16; ++i) o2[i] = __hmul2(o2[i], f2);
            #pragma unroll
            for (int t2 = 0; t2 < 32; ++t2) {
                float p = __expf(sc[t2] - mn);
                ssum += p;
                __half2 p2 = __float2half2_rn(p);
                const float4* vr = reinterpret_cast<const float4*>(&s_vh[t2 * 64 + head * 16]);
                F4H v0, v1, v2, v3;
                v0.f = vr[0]; v1.f = vr[1]; v2.f = vr[2]; v3.f = vr[3];
                #pragma unroll
                for (int i = 0; i < 4; ++i) o2[i]      = __hfma2(p2, v0.h[i], o2[i]);
                #pragma unroll
                for (int i = 0; i < 4; ++i) o2[4 + i]  = __hfma2(p2, v1.h[i], o2[4 + i]);
                #pragma unroll
                for (int i = 0; i < 4; ++i) o2[8 + i]  = __hfma2(p2, v2.h[i], o2[8 + i]);
                #pragma unroll
                for (int i = 0; i < 4; ++i) o2[12 + i] = __hfma2(p2, v3.h[i], o2[12 + i]);
            }
            m = mn;
        } else {
            float tmax = -1e30f;
            for (int t2 = 0; t2 < kcnt; ++t2) {
                const float4* kr = reinterpret_cast<const float4*>(&s_kh[t2 * 64 + head * 16]);
                F4H k0, k1, k2, k3;
                k0.f = kr[0]; k1.f = kr[1]; k2.f = kr[2]; k3.f = kr[3];
                __half2 acc = __hmul2(q2[0], k0.h[0]);
                #pragma unroll
                for (int i = 1; i < 4; ++i) acc = __hfma2(q2[i], k0.h[i], acc);
                #pragma unroll
                for (int i = 0; i < 4; ++i) acc = __hfma2(q2[4 + i], k1.h[i], acc);
                #pragma unroll
                for (int i = 0; i < 4; ++i) acc = __hfma2(q2[8 + i], k2.h[i], acc);
                #pragma unroll
                for (int i = 0; i < 4; ++i) acc = __hfma2(q2[12 + i], k3.h[i], acc);
                tmax = fmaxf(tmax, (__low2float(acc) + __high2float(acc)) * SCALE_);
            }
            float mn = fmaxf(m, tmax);
            float f = __expf(m - mn);
            ssum *= f;
            __half2 f2 = __float2half2_rn(f);
            #pragma unroll
            for (int i = 0; i < 16; ++i) o2[i] = __hmul2(o2[i], f2);
            for (int t2 = 0; t2 < kcnt; ++t2) {
                const float4* kr = reinterpret_cast<const float4*>(&s_kh[t2 * 64 + head * 16]);
                F4H k0, k1, k2, k3;
                k0.f = kr[0]; k1.f = kr[1]; k2.f = kr[2]; k3.f = kr[3];
                __half2 acc = __hmul2(q2[0], k0.h[0]);
                #pragma unroll
                for (int i = 1; i < 4; ++i) acc = __hfma2(q2[i], k0.h[i], acc);
                #pragma unroll
                for (int i = 0; i < 4; ++i) acc = __hfma2(q2[4 + i], k1.h[i], acc);
                #pragma unroll
                for (int i = 0; i < 4; ++i) acc = __hfma2(q2[8 + i], k2.h[i], acc);
                #pragma unroll
                for (int i = 0; i < 4; ++i) acc = __hfma2(q2[12 + i], k3.h[i], acc);
                float p = __expf((__low2float(acc) + __high2float(acc)) * SCALE_ - mn);
                ssum += p;
                __half2 p2 = __float2half2_rn(p);
                const float4* vr = reinterpret_cast<const float4*>(&s_vh[t2 * 64 + head * 16]);
                F4H v0, v1, v2, v3;
                v0.f = vr[0]; v1.f = vr[1]; v2.f = vr[2]; v3.f = vr[3];
                #pragma unroll
                for (int i = 0; i < 4; ++i) o2[i]      = __hfma2(p2, v0.h[i], o2[i]);
                #pragma unroll
                for (int i = 0; i < 4; ++i) o2[4 + i]  = __hfma2(p2, v1.h[i], o2[4 + i]);
                #pragma unroll
                for (int i = 0; i < 4; ++i) o2[8 + i]  = __hfma2(p2, v2.h[i], o2[8 + i]);
                #pragma unroll
                for (int i = 0; i < 4; ++i) o2[12 + i] = __hfma2(p2, v3.h[i], o2[12 + i]);
            }
            m = mn;
        }
    }
    __syncthreads();
    if (qi < qcnt) {
        float inv = 1.0f / ssum;
        #pragma unroll
        for (int i = 0; i < 16; ++i) {
            float2 of = __half22float2(o2[i]);
            s_o[qi * 132 + head * DH_ + 2 * i]     = of.x * inv;
            s_o[qi * 132 + head * DH_ + 2 * i + 1] = of.y * inv;
        }
    }
    __syncthreads();
    {
        int j = tid & 127, half = tid >> 7;
        const float* Wo = s_out_w + ((size_t)(li * ET_ + et) * H_ + j) * H_;
        float bo = s_out_b[(size_t)(li * ET_ + et) * H_ + j];
        float acc[32];
        #pragma unroll
        for (int qq = 0; qq < 32; ++qq) acc[qq] = bo;
        #pragma unroll 8
        for (int k4 = 0; k4 < 32; ++k4) {
            float4 w = *reinterpret_cast<const float4*>(&Wo[k4 * 4]);
            #pragma unroll
            for (int qq = 0; qq < 32; ++qq) {
                float4 ov = *reinterpret_cast<const float4*>(&s_o[(half * 32 + qq) * 132 + k4 * 4]);
                acc[qq] += w.x * ov.x + w.y * ov.y + w.z * ov.z + w.w * ov.w;
            }
        }
        #pragma unroll
        for (int qq = 0; qq < 32; ++qq) {
            int qrow = half * 32 + qq;
            if (qrow < qcnt) {
                atomicAdd(&h_new[(size_t)s_dn[qrow] * H_ + j], acc[qq]);
            }
        }
    }
}

// ---------------- LN + exact GELU + residual (spatial); re-zeroes h_new ----------------

__global__ void k_lngelu(float* __restrict__ h_new, float* __restrict__ h,
                         const float* __restrict__ ln_g, const float* __restrict__ ln_b, int li) {
    int n = blockIdx.x;
    int l = threadIdx.x;  // 0..63
    float v0 = h_new[(size_t)n * H_ + l];
    float v1 = h_new[(size_t)n * H_ + 64 + l];
    h_new[(size_t)n * H_ + l] = 0.0f;
    h_new[(size_t)n * H_ + 64 + l] = 0.0f;
    float s = v0 + v1;
    #pragma unroll
    for (int off = 32; off; off >>= 1) s += __shfl_xor(s, off);
    float mean = s * (1.0f / H_);
    float d0 = v0 - mean, d1 = v1 - mean;
    float vs = d0 * d0 + d1 * d1;
    #pragma unroll
    for (int off = 32; off; off >>= 1) vs += __shfl_xor(vs, off);
    float rstd = rsqrtf(vs * (1.0f / H_) + 1e-5f);
    const float* gg = ln_g + (size_t)li * H_;
    const float* bb = ln_b + (size_t)li * H_;
    float t0 = gelu_exact(d0 * rstd * gg[l] + bb[l]);
    float t1 = gelu_exact(d1 * rstd * gg[64 + l] + bb[64 + l]);
    size_t o = (size_t)n * H_;
    if (li == 0) { h[o + l] = t0; h[o + 64 + l] = t1; }
    else         { h[o + l] += t0; h[o + 64 + l] += t1; }
}

// ---------------- temporal: positional encoding add ----------------

__global__ void k_peadd(float* __restrict__ h) {
    int i = blockIdx.x * blockDim.x + threadIdx.x;
    int stride = gridDim.x * blockDim.x;
    for (; i < N_ * H_; i += stride) {
        int j = i & 127;
        int t = (i >> 7) & 63;
        float dv = __expf((float)(j & ~1) * (-0.0719557841560639f));
        float ang = (float)t * dv;
        float pe = (j & 1) ? cosf(ang) : sinf(ang);
        h[i] += pe;
    }
}

// ---------------- temporal qkv GEMM (fp16/fdot2): block = (node-in-chunk, {q,k,v}) ----------------

__global__ __launch_bounds__(256) void k_tqkv(const float* __restrict__ hs,
                                              const float* __restrict__ t_in_w, const float* __restrict__ t_in_b,
                                              float* __restrict__ qc, float* __restrict__ kc, float* __restrict__ vc,
                                              int li, int c0) {
    int nb = blockIdx.x;
    int nt = blockIdx.y;
    int node = c0 + nb;
    __shared__ hh2 s_ah[64 * 67];
    __shared__ hh2 s_bh[16 * 132];
    int tid = threadIdx.x;
    #pragma unroll
    for (int i = 0; i < 8; ++i) {
        int idx = i * 256 + tid;
        int r = idx >> 5, c4i = idx & 31;
        float4 v = *reinterpret_cast<const float4*>(&hs[((size_t)node * 64 + r) * 128 + c4i * 4]);
        s_ah[r * 67 + c4i * 2]     = f2h2(v.x, v.y);
        s_ah[r * 67 + c4i * 2 + 1] = f2h2(v.z, v.w);
    }
    const float* B = t_in_w + ((size_t)li * 384 + nt * 128) * 128;
    const float* bi = t_in_b + (size_t)li * 384 + nt * 128;
    int rg = tid >> 4, cg = tid & 15;
    int r0 = rg * 4;
    float4 alo[4], ahi[4];
    #pragma unroll
    for (int rr = 0; rr < 4; ++rr) { alo[rr] = f4zero(); ahi[rr] = f4zero(); }
    for (int kci = 0; kci < 4; ++kci) {
        __syncthreads();
        #pragma unroll
        for (int i = 0; i < 4; ++i) {
            int idx = i * 256 + tid;
            int jj = idx >> 3, k4 = (idx & 7) * 4;
            float4 w = *reinterpret_cast<const float4*>(&B[(size_t)jj * 128 + kci * 32 + k4]);
            int k2 = k4 >> 1;
            s_bh[k2 * 132 + jj]       = f2h2(w.x, w.y);
            s_bh[(k2 + 1) * 132 + jj] = f2h2(w.z, w.w);
        }
        __syncthreads();
        #pragma unroll
        for (int k2 = 0; k2 < 16; ++k2) {
            hh2 a2[4];
            #pragma unroll
            for (int rr = 0; rr < 4; ++rr) a2[rr] = s_ah[(r0 + rr) * 67 + kci * 16 + k2];
            U4H2 bl, bh_;
            bl.f  = *reinterpret_cast<const float4*>(&s_bh[k2 * 132 + cg * 4]);
            bh_.f = *reinterpret_cast<const float4*>(&s_bh[k2 * 132 + 64 + cg * 4]);
            #pragma unroll
            for (int rr = 0; rr < 4; ++rr) {
                alo[rr].x = FDOT2(a2[rr], bl.h[0], alo[rr].x);
                alo[rr].y = FDOT2(a2[rr], bl.h[1], alo[rr].y);
                alo[rr].z = FDOT2(a2[rr], bl.h[2], alo[rr].z);
                alo[rr].w = FDOT2(a2[rr], bl.h[3], alo[rr].w);
                ahi[rr].x = FDOT2(a2[rr], bh_.h[0], ahi[rr].x);
                ahi[rr].y = FDOT2(a2[rr], bh_.h[1], ahi[rr].y);
                ahi[rr].z = FDOT2(a2[rr], bh_.h[2], ahi[rr].z);
                ahi[rr].w = FDOT2(a2[rr], bh_.h[3], ahi[rr].w);
            }
        }
    }
    float* dst = (nt == 0) ? qc : (nt == 1) ? kc : vc;
    float sc = (nt == 0) ? SCALE_ : 1.0f;
    float4 blo = *reinterpret_cast<const float4*>(&bi[cg * 4]);
    float4 bhi = *reinterpret_cast<const float4*>(&bi[64 + cg * 4]);
    #pragma unroll
    for (int rr = 0; rr < 4; ++rr) {
        float4 lo = alo[rr], hi = ahi[rr];
        lo.x = (lo.x + blo.x) * sc; lo.y = (lo.y + blo.y) * sc; lo.z = (lo.z + blo.z) * sc; lo.w = (lo.w + blo.w) * sc;
        hi.x = (hi.x + bhi.x) * sc; hi.y = (hi.y + bhi.y) * sc; hi.z = (hi.z + bhi.z) * sc; hi.w = (hi.w + bhi.w) * sc;
        size_t row = (size_t)nb * 64 + r0 + rr;
        *reinterpret_cast<float4*>(&dst[row * 128 + cg * 4]) = lo;
        *reinterpret_cast<float4*>(&dst[row * 128 + 64 + cg * 4]) = hi;
    }
}

// ---------------- temporal attention (fp32, unchanged) ----------------

__global__ __launch_bounds__(64) void k_tattn(float* __restrict__ qc, const float* __restrict__ kc,
                                              const float* __restrict__ vc) {
    int nb = blockIdx.x, head = blockIdx.y;
    __shared__ float s_k[64 * 36];
    __shared__ float s_v[64 * 36];
    int t = threadIdx.x;
    #pragma unroll
    for (int i = 0; i < 8; ++i) {
        int idx = i * 64 + t;
        int row = idx >> 3, d4 = (idx & 7) * 4;
        *reinterpret_cast<float4*>(&s_k[row * 36 + d4]) =
            *reinterpret_cast<const float4*>(&kc[((size_t)nb * 64 + row) * 128 + head * DH_ + d4]);
        *reinterpret_cast<float4*>(&s_v[row * 36 + d4]) =
            *reinterpret_cast<const float4*>(&vc[((size_t)nb * 64 + row) * 128 + head * DH_ + d4]);
    }
    float4 q[8];
    {
        const float4* qr = reinterpret_cast<const float4*>(&qc[((size_t)nb * 64 + t) * 128 + head * DH_]);
        #pragma unroll
        for (int i = 0; i < 8; ++i) q[i] = qr[i];
    }
    __syncthreads();
    float m = -1e30f;
    for (int t2 = 0; t2 < 64; ++t2) {
        const float4* kr = reinterpret_cast<const float4*>(&s_k[t2 * 36]);
        float s0 = 0, s1 = 0, s2 = 0, s3 = 0;
        #pragma unroll
        for (int i = 0; i < 8; ++i) {
            float4 kk = kr[i];
            s0 += q[i].x * kk.x; s1 += q[i].y * kk.y; s2 += q[i].z * kk.z; s3 += q[i].w * kk.w;
        }
        m = fmaxf(m, (s0 + s1) + (s2 + s3));
    }
    float ssum = 0.0f;
    float4 o[8];
    #pragma unroll
    for (int i = 0; i < 8; ++i) o[i] = f4zero();
    for (int t2 = 0; t2 < 64; ++t2) {
        const float4* kr = reinterpret_cast<const float4*>(&s_k[t2 * 36]);
        float s0 = 0, s1 = 0, s2 = 0, s3 = 0;
        #pragma unroll
        for (int i = 0; i < 8; ++i) {
            float4 kk = kr[i];
            s0 += q[i].x * kk.x; s1 += q[i].y * kk.y; s2 += q[i].z * kk.z; s3 += q[i].w * kk.w;
        }
        float p = __expf((s0 + s1) + (s2 + s3) - m);
        ssum += p;
        const float4* vr = reinterpret_cast<const float4*>(&s_v[t2 * 36]);
        #pragma unroll
        for (int i = 0; i < 8; ++i) f4fma(o[i], p, vr[i]);
    }
    float inv = 1.0f / ssum;
    float4* orow = reinterpret_cast<float4*>(&qc[((size_t)nb * 64 + t) * 128 + head * DH_]);
    #pragma unroll
    for (int i = 0; i < 8; ++i) { float4 v = o[i]; f4scale(v, inv); orow[i] = v; }
}

// ---------------- temporal out-proj (fp16/fdot2) + residual + LN1 ----------------

__global__ __launch_bounds__(256) void k_toutln(const float* __restrict__ oc, float* __restrict__ hs,
                                                const float* __restrict__ t_out_w, const float* __restrict__ t_out_b,
                                                const float* __restrict__ ln_g, const float* __restrict__ ln_b,
                                                int li, int c0) {
    int nb = blockIdx.x;
    int node = c0 + nb;
    __shared__ hh2 s_ah[64 * 67];
    __shared__ hh2 s_bh[16 * 132];
    int tid = threadIdx.x;
    #pragma unroll
    for (int i = 0; i < 8; ++i) {
        int idx = i * 256 + tid;
        int r = idx >> 5, c4i = idx & 31;
        float4 v = *reinterpret_cast<const float4*>(&oc[((size_t)nb * 64 + r) * 128 + c4i * 4]);
        s_ah[r * 67 + c4i * 2]     = f2h2(v.x, v.y);
        s_ah[r * 67 + c4i * 2 + 1] = f2h2(v.z, v.w);
    }
    const float* B = t_out_w + (size_t)li * 128 * 128;
    const float* bo = t_out_b + (size_t)li * 128;
    int rg = tid >> 4, cg = tid & 15;
    int r0 = rg * 4;
    float4 alo[4], ahi[4];
    #pragma unroll
    for (int rr = 0; rr < 4; ++rr) { alo[rr] = f4zero(); ahi[rr] = f4zero(); }
    for (int kci = 0; kci < 4; ++kci) {
        __syncthreads();
        #pragma unroll
        for (int i = 0; i < 4; ++i) {
            int idx = i * 256 + tid;
            int jj = idx >> 3, k4 = (idx & 7) * 4;
            float4 w = *reinterpret_cast<const float4*>(&B[(size_t)jj * 128 + kci * 32 + k4]);
            int k2 = k4 >> 1;
            s_bh[k2 * 132 + jj]       = f2h2(w.x, w.y);
            s_bh[(k2 + 1) * 132 + jj] = f2h2(w.z, w.w);
        }
        __syncthreads();
        #pragma unroll
        for (int k2 = 0; k2 < 16; ++k2) {
            hh2 a2[4];
            #pragma unroll
            for (int rr = 0; rr < 4; ++rr) a2[rr] = s_ah[(r0 + rr) * 67 + kci * 16 + k2];
            U4H2 bl, bh_;
            bl.f  = *reinterpret_cast<const float4*>(&s_bh[k2 * 132 + cg * 4]);
            bh_.f = *reinterpret_cast<const float4*>(&s_bh[k2 * 132 + 64 + cg * 4]);
            #pragma unroll
            for (int rr = 0; rr < 4; ++rr) {
                alo[rr].x = FDOT2(a2[rr], bl.h[0], alo[rr].x);
                alo[rr].y = FDOT2(a2[rr], bl.h[1], alo[rr].y);
                alo[rr].z = FDOT2(a2[rr], bl.h[2], alo[rr].z);
                alo[rr].w = FDOT2(a2[rr], bl.h[3], alo[rr].w);
                ahi[rr].x = FDOT2(a2[rr], bh_.h[0], ahi[rr].x);
                ahi[rr].y = FDOT2(a2[rr], bh_.h[1], ahi[rr].y);
                ahi[rr].z = FDOT2(a2[rr], bh_.h[2], ahi[rr].z);
                ahi[rr].w = FDOT2(a2[rr], bh_.h[3], ahi[rr].w);
            }
        }
    }
    float4 bblo = *reinterpret_cast<const float4*>(&bo[cg * 4]);
    float4 bbhi = *reinterpret_cast<const float4*>(&bo[64 + cg * 4]);
    float4 glo = *reinterpret_cast<const float4*>(&ln_g[(size_t)li * 128 + cg * 4]);
    float4 ghi = *reinterpret_cast<const float4*>(&ln_g[(size_t)li * 128 + 64 + cg * 4]);
    float4 lblo = *reinterpret_cast<const float4*>(&ln_b[(size_t)li * 128 + cg * 4]);
    float4 lbhi = *reinterpret_cast<const float4*>(&ln_b[(size_t)li * 128 + 64 + cg * 4]);
    #pragma unroll
    for (int rr = 0; rr < 4; ++rr) {
        size_t row = (size_t)node * 64 + r0 + rr;
        float4 rlo = *reinterpret_cast<const float4*>(&hs[row * 128 + cg * 4]);
        float4 rhi = *reinterpret_cast<const float4*>(&hs[row * 128 + 64 + cg * 4]);
        float4 lo = alo[rr], hi = ahi[rr];
        lo.x += bblo.x + rlo.x; lo.y += bblo.y + rlo.y; lo.z += bblo.z + rlo.z; lo.w += bblo.w + rlo.w;
        hi.x += bbhi.x + rhi.x; hi.y += bbhi.y + rhi.y; hi.z += bbhi.z + rhi.z; hi.w += bbhi.w + rhi.w;
        float s = lo.x + lo.y + lo.z + lo.w + hi.x + hi.y + hi.z + hi.w;
        s += __shfl_xor(s, 1); s += __shfl_xor(s, 2); s += __shfl_xor(s, 4); s += __shfl_xor(s, 8);
        float mean = s * (1.0f / 128.0f);
        float4 dlo = make_float4(lo.x - mean, lo.y - mean, lo.z - mean, lo.w - mean);
        float4 dhi = make_float4(hi.x - mean, hi.y - mean, hi.z - mean, hi.w - mean);
        float vx = dlo.x * dlo.x + dlo.y * dlo.y + dlo.z * dlo.z + dlo.w * dlo.w +
                   dhi.x * dhi.x + dhi.y * dhi.y + dhi.z * dhi.z + dhi.w * dhi.w;
        vx += __shfl_xor(vx, 1); vx += __shfl_xor(vx, 2); vx += __shfl_xor(vx, 4); vx += __shfl_xor(vx, 8);
        float rstd = rsqrtf(vx * (1.0f / 128.0f) + 1e-5f);
        float4 olo = make_float4(dlo.x * rstd * glo.x + lblo.x, dlo.y * rstd * glo.y + lblo.y,
                                 dlo.z * rstd * glo.z + lblo.z, dlo.w * rstd * glo.w + lblo.w);
        float4 ohi = make_float4(dhi.x * rstd * ghi.x + lbhi.x, dhi.y * rstd * ghi.y + lbhi.y,
                                 dhi.z * rstd * ghi.z + lbhi.z, dhi.w * rstd * ghi.w + lbhi.w);
        *reinterpret_cast<float4*>(&hs[row * 128 + cg * 4]) = olo;
        *reinterpret_cast<float4*>(&hs[row * 128 + 64 + cg * 4]) = ohi;
    }
}

// ---------------- temporal fused FF (fp16/fdot2) + residual + LN2 ----------------

__global__ __launch_bounds__(256) void k_tff(float* __restrict__ hs,
                                             const float* __restrict__ t_w1, const float* __restrict__ t_b1,
                                             const float* __restrict__ t_w2, const float* __restrict__ t_b2,
                                             const float* __restrict__ ln_g, const float* __restrict__ ln_b,
                                             int li) {
    int node = blockIdx.x;
    __shared__ hh2 s_hh[64 * 67];    // hs fp16 (input + residual source)
    __shared__ hh2 s_fh[64 * 67];    // gelu(f1) fp16
    __shared__ hh2 s_bh[16 * 132];   // weight tile
    int tid = threadIdx.x;
    #pragma unroll
    for (int i = 0; i < 8; ++i) {
        int idx = i * 256 + tid;
        int r = idx >> 5, c4i = idx & 31;
        float4 v = *reinterpret_cast<const float4*>(&hs[((size_t)node * 64 + r) * 128 + c4i * 4]);
        s_hh[r * 67 + c4i * 2]     = f2h2(v.x, v.y);
        s_hh[r * 67 + c4i * 2 + 1] = f2h2(v.z, v.w);
    }
    int rg = tid >> 4, cg = tid & 15;
    int r0 = rg * 4;
    const float* W1 = t_w1 + (size_t)li * FF_ * 128;
    const float* b1 = t_b1 + (size_t)li * FF_;
    const float* W2 = t_w2 + (size_t)li * 128 * FF_;
    const float* b2 = t_b2 + (size_t)li * 128;
    float4 c2lo[4], c2hi[4];
    #pragma unroll
    for (int rr = 0; rr < 4; ++rr) { c2lo[rr] = f4zero(); c2hi[rr] = f4zero(); }

    for (int nt = 0; nt < 4; ++nt) {
        // GEMM1: c1 = s_hh @ W1[nt]^T  (K=128)
        float4 c1lo[4], c1hi[4];
        #pragma unroll
        for (int rr = 0; rr < 4; ++rr) { c1lo[rr] = f4zero(); c1hi[rr] = f4zero(); }
        for (int kci = 0; kci < 4; ++kci) {
            __syncthreads();
            #pragma unroll
            for (int i = 0; i < 4; ++i) {
                int idx = i * 256 + tid;
                int jj = idx >> 3, k4 = (idx & 7) * 4;
                float4 w = *reinterpret_cast<const float4*>(&W1[(size_t)(nt * 128 + jj) * 128 + kci * 32 + k4]);
                int k2 = k4 >> 1;
                s_bh[k2 * 132 + jj]       = f2h2(w.x, w.y);
                s_bh[(k2 + 1) * 132 + jj] = f2h2(w.z, w.w);
            }
            __syncthreads();
            #pragma unroll
            for (int k2 = 0; k2 < 16; ++k2) {
                hh2 a2[4];
                #pragma unroll
                for (int rr = 0; rr < 4; ++rr) a2[rr] = s_hh[(r0 + rr) * 67 + kci * 16 + k2];
                U4H2 bl, bh_;
                bl.f  = *reinterpret_cast<const float4*>(&s_bh[k2 * 132 + cg * 4]);
                bh_.f = *reinterpret_cast<const float4*>(&s_bh[k2 * 132 + 64 + cg * 4]);
                #pragma unroll
                for (int rr = 0; rr < 4; ++rr) {
                    c1lo[rr].x = FDOT2(a2[rr], bl.h[0], c1lo[rr].x);
                    c1lo[rr].y = FDOT2(a2[rr], bl.h[1], c1lo[rr].y);
                    c1lo[rr].z = FDOT2(a2[rr], bl.h[2], c1lo[rr].z);
                    c1lo[rr].w = FDOT2(a2[rr], bl.h[3], c1lo[rr].w);
                    c1hi[rr].x = FDOT2(a2[rr], bh_.h[0], c1hi[rr].x);
                    c1hi[rr].y = FDOT2(a2[rr], bh_.h[1], c1hi[rr].y);
                    c1hi[rr].z = FDOT2(a2[rr], bh_.h[2], c1hi[rr].z);
                    c1hi[rr].w = FDOT2(a2[rr], bh_.h[3], c1hi[rr].w);
                }
            }
        }
        // bias + gelu (fp32) -> s_fh (fp16)
        __syncthreads();   // prior GEMM2 reads of s_fh complete (nt>0)
        {
            float4 blo = *reinterpret_cast<const float4*>(&b1[nt * 128 + cg * 4]);
            float4 bhi = *reinterpret_cast<const float4*>(&b1[nt * 128 + 64 + cg * 4]);
            #pragma unroll
            for (int rr = 0; rr < 4; ++rr) {
                float gx = gelu_exact(c1lo[rr].x + blo.x), gy = gelu_exact(c1lo[rr].y + blo.y);
                float gz = gelu_exact(c1lo[rr].z + blo.z), gw = gelu_exact(c1lo[rr].w + blo.w);
                s_fh[(r0 + rr) * 67 + cg * 2]     = f2h2(gx, gy);
                s_fh[(r0 + rr) * 67 + cg * 2 + 1] = f2h2(gz, gw);
                float hx = gelu_exact(c1hi[rr].x + bhi.x), hy = gelu_exact(c1hi[rr].y + bhi.y);
                float hz = gelu_exact(c1hi[rr].z + bhi.z), hw = gelu_exact(c1hi[rr].w + bhi.w);
                s_fh[(r0 + rr) * 67 + 32 + cg * 2]     = f2h2(hx, hy);
                s_fh[(r0 + rr) * 67 + 32 + cg * 2 + 1] = f2h2(hz, hw);
            }
        }
        // GEMM2: c2 += s_fh @ W2[:, nt*128..]^T  (K=128)
        for (int kci = 0; kci < 4; ++kci) {
            __syncthreads();
            #pragma unroll
            for (int i = 0; i < 4; ++i) {
                int idx = i * 256 + tid;
                int jj = idx >> 3, k4 = (idx & 7) * 4;
                float4 w = *reinterpret_cast<const float4*>(&W2[(size_t)jj * FF_ + nt * 128 + kci * 32 + k4]);
                int k2 = k4 >> 1;
                s_bh[k2 * 132 + jj]       = f2h2(w.x, w.y);
                s_bh[(k2 + 1) * 132 + jj] = f2h2(w.z, w.w);
            }
            __syncthreads();
            #pragma unroll
            for (int k2 = 0; k2 < 16; ++k2) {
                hh2 a2[4];
                #pragma unroll
                for (int rr = 0; rr < 4; ++rr) a2[rr] = s_fh[(r0 + rr) * 67 + kci * 16 + k2];
                U4H2 bl, bh_;
                bl.f  = *reinterpret_cast<const float4*>(&s_bh[k2 * 132 + cg * 4]);
                bh_.f = *reinterpret_cast<const float4*>(&s_bh[k2 * 132 + 64 + cg * 4]);
                #pragma unroll
                for (int rr = 0; rr < 4; ++rr) {
                    c2lo[rr].x = FDOT2(a2[rr], bl.h[0], c2lo[rr].x);
                    c2lo[rr].y = FDOT2(a2[rr], bl.h[1], c2lo[rr].y);
                    c2lo[rr].z = FDOT2(a2[rr], bl.h[2], c2lo[rr].z);
                    c2lo[rr].w = FDOT2(a2[rr], bl.h[3], c2lo[rr].w);
                    c2hi[rr].x = FDOT2(a2[rr], bh_.h[0], c2hi[rr].x);
                    c2hi[rr].y = FDOT2(a2[rr], bh_.h[1], c2hi[rr].y);
                    c2hi[rr].z = FDOT2(a2[rr], bh_.h[2], c2hi[rr].z);
                    c2hi[rr].w = FDOT2(a2[rr], bh_.h[3], c2hi[rr].w);
                }
            }
        }
    }
    // epilogue: bias + residual (from s_hh) + LN2 -> hs
    float4 bblo = *reinterpret_cast<const float4*>(&b2[cg * 4]);
    float4 bbhi = *reinterpret_cast<const float4*>(&b2[64 + cg * 4]);
    float4 glo = *reinterpret_cast<const float4*>(&ln_g[(size_t)li * 128 + cg * 4]);
    float4 ghi = *reinterpret_cast<const float4*>(&ln_g[(size_t)li * 128 + 64 + cg * 4]);
    float4 lblo = *reinterpret_cast<const float4*>(&ln_b[(size_t)li * 128 + cg * 4]);
    float4 lbhi = *reinterpret_cast<const float4*>(&ln_b[(size_t)li * 128 + 64 + cg * 4]);
    #pragma unroll
    for (int rr = 0; rr < 4; ++rr) {
        size_t row = (size_t)node * 64 + r0 + rr;
        hh2 ra = s_hh[(r0 + rr) * 67 + cg * 2];
        hh2 rb = s_hh[(r0 + rr) * 67 + cg * 2 + 1];
        hh2 rc = s_hh[(r0 + rr) * 67 + 32 + cg * 2];
        hh2 rd = s_hh[(r0 + rr) * 67 + 32 + cg * 2 + 1];
        float4 lo = c2lo[rr], hi = c2hi[rr];
        lo.x += bblo.x + (float)ra[0]; lo.y += bblo.y + (float)ra[1];
        lo.z += bblo.z + (float)rb[0]; lo.w += bblo.w + (float)rb[1];
        hi.x += bbhi.x + (float)rc[0]; hi.y += bbhi.y + (float)rc[1];
        hi.z += bbhi.z + (float)rd[0]; hi.w += bbhi.w + (float)rd[1];
        float s = lo.x + lo.y + lo.z + lo.w + hi.x + hi.y + hi.z + hi.w;
        s += __shfl_xor(s, 1); s += __shfl_xor(s, 2); s += __shfl_xor(s, 4); s += __shfl_xor(s, 8);
        float mean = s * (1.0f / 128.0f);
        float4 dlo = make_float4(lo.x - mean, lo.y - mean, lo.z - mean, lo.w - mean);
        float4 dhi = make_float4(hi.x - mean, hi.y - mean, hi.z - mean, hi.w - mean);
        float vx = dlo.x * dlo.x + dlo.y * dlo.y + dlo.z * dlo.z + dlo.w * dlo.w +
                   dhi.x * dhi.x + dhi.y * dhi.y + dhi.z * dhi.z + dhi.w * dhi.w;
        vx += __shfl_xor(vx, 1); vx += __shfl_xor(vx, 2); vx += __shfl_xor(vx, 4); vx += __shfl_xor(vx, 8);
        float rstd = rsqrtf(vx * (1.0f / 128.0f) + 1e-5f);
        float4 olo = make_float4(dlo.x * rstd * glo.x + lblo.x, dlo.y * rstd * glo.y + lblo.y,
                                 dlo.z * rstd * glo.z + lblo.z, dlo.w * rstd * glo.w + lblo.w);
        float4 ohi = make_float4(dhi.x * rstd * ghi.x + lbhi.x, dhi.y * rstd * ghi.y + lbhi.y,
                                 dhi.z * rstd * ghi.z + lbhi.z, dhi.w * rstd * ghi.w + lbhi.w);
        *reinterpret_cast<float4*>(&hs[row * 128 + cg * 4]) = olo;
        *reinterpret_cast<float4*>(&hs[row * 128 + 64 + cg * 4]) = ohi;
    }
}

// ---------------- final LN -> out ----------------

__global__ __launch_bounds__(256) void k_fln(const float* __restrict__ hs, float* __restrict__ out,
                                             const float* __restrict__ g, const float* __restrict__ b) {
    int row = blockIdx.x * 4 + (threadIdx.x >> 6);
    int l = threadIdx.x & 63;
    float v0 = hs[(size_t)row * H_ + l];
    float v1 = hs[(size_t)row * H_ + 64 + l];
    float s = v0 + v1;
    #pragma unroll
    for (int off = 32; off; off >>= 1) s += __shfl_xor(s, off);
    float mean = s * (1.0f / H_);
    float d0 = v0 - mean, d1 = v1 - mean;
    float vs = d0 * d0 + d1 * d1;
    #pragma unroll
    for (int off = 32; off; off >>= 1) vs += __shfl_xor(vs, off);
    float rstd = rsqrtf(vs * (1.0f / H_) + 1e-5f);
    out[(size_t)row * H_ + l] = d0 * rstd * g[l] + b[l];
    out[(size_t)row * H_ + 64 + l] = d1 * rstd * g[64 + l] + b[64 + l];
}

// ---------------- launch ----------------

extern "C" void kernel_launch(void* const* d_in, const int* in_sizes, int n_in,
                              void* d_out, int out_size, void* d_ws, size_t ws_size,
                              hipStream_t stream) {
    const float* x          = (const float*)d_in[0];
    const int*   edge_index = (const int*)d_in[1];
    const int*   edge_type  = (const int*)d_in[2];
    const int*   node_type  = (const int*)d_in[3];
    const float* W_in    = (const float*)d_in[6];
    const float* b_in    = (const float*)d_in[7];
    const float* s_in_w  = (const float*)d_in[8];
    const float* s_in_b  = (const float*)d_in[9];
    const float* s_out_w = (const float*)d_in[10];
    const float* s_out_b = (const float*)d_in[11];
    const float* ln_s_g  = (const float*)d_in[12];
    const float* ln_s_b  = (const float*)d_in[13];
    const float* t_in_w  = (const float*)d_in[14];
    const float* t_in_b  = (const float*)d_in[15];
    const float* t_out_w = (const float*)d_in[16];
    const float* t_out_b = (const float*)d_in[17];
    const float* t_ln1_g = (const float*)d_in[18];
    const float* t_ln1_b = (const float*)d_in[19];
    const float* t_w1    = (const float*)d_in[20];
    const float* t_b1    = (const float*)d_in[21];
    const float* t_w2    = (const float*)d_in[22];
    const float* t_b2    = (const float*)d_in[23];
    const float* t_ln2_g = (const float*)d_in[24];
    const float* t_ln2_b = (const float*)d_in[25];
    const float* fin_g   = (const float*)d_in[26];
    const float* fin_b   = (const float*)d_in[27];
    float* out = (float*)d_out;

    // workspace layout (floats)
    float* h     = (float*)d_ws;                       // N*H = 8388608
    float* h_new = h + (size_t)N_ * H_;                // 8388608
    float* qkv   = h_new + (size_t)N_ * H_;            // E*384 = 11520000
    int* sorted  = (int*)(qkv + (size_t)E_ * 384);     // E
    int* gpos    = sorted + E_;                        // E
    int* gedge   = gpos + E_;                          // E
    int* cnt     = gedge + E_;                         // 64
    int* offs    = cnt + 64;                           // 64
    int* curs    = offs + 64;                          // 64
    int* nd64    = curs + 64;                          // 16
    int2* desc64 = (int2*)(nd64 + 16);                 // 544 int2

    // temporal chunk buffers (alias spatial regions, used after spatial completes)
    float* qc = qkv;                                   // CH*64*128 = 4194304
    float* kc = qkv + (size_t)CH_ * 64 * 128;          // 4194304
    float* vc = h_new;                                 // 4194304

    k_zero_cnt<<<1, 64, 0, stream>>>(cnt);
    k_hist<<<(E_ + 255) / 256, 256, 0, stream>>>(edge_index, edge_type, node_type, gedge, cnt);
    k_scan<<<1, 1, 0, stream>>>(cnt, offs, curs);
    k_scatter<<<(E_ + 255) / 256, 256, 0, stream>>>(gedge, curs, sorted, gpos);
    k_desc<<<1, 1, 0, stream>>>(offs, desc64, nd64);

    k_inproj<<<N_, 128, 0, stream>>>(x, node_type, W_in, b_in, h);

    k_zero<<<2048, 256, 0, stream>>>(h_new, N_ * H_);   // layer 0; later layers zeroed by k_lngelu
    for (int li = 0; li < L_; ++li) {
        k_sqkv_gemm<<<dim3(GATTN_GRID, 3), 256, 0, stream>>>(h, s_in_w, s_in_b, sorted, offs, edge_index,
                                                             desc64, nd64, qkv, li);
        k_gattn<<<GATTN_GRID, 256, 0, stream>>>(qkv, sorted, offs, edge_index, desc64, nd64,
                                                s_out_w, s_out_b, h_new, li);
        k_lngelu<<<N_, 64, 0, stream>>>(h_new, h, ln_s_g, ln_s_b, li);
    }

    // temporal: hs = h + PE (in place)
    k_peadd<<<2048, 256, 0, stream>>>(h);
    for (int li = 0; li < TL_; ++li) {
        for (int c = 0; c < NB_ / CH_; ++c) {
            int c0 = c * CH_;
            k_tqkv<<<dim3(CH_, 3), 256, 0, stream>>>(h, t_in_w, t_in_b, qc, kc, vc, li, c0);
            k_tattn<<<dim3(CH_, NH_), 64, 0, stream>>>(qc, kc, vc);
            k_toutln<<<CH_, 256, 0, stream>>>(qc, h, t_out_w, t_out_b, t_ln1_g, t_ln1_b, li, c0);
        }
        k_tff<<<NB_, 256, 0, stream>>>(h, t_w1, t_b1, t_w2, t_b2, t_ln2_g, t_ln2_b, li);
    }
    k_fln<<<N_ / 4, 256, 0, stream>>>(h, out, fin_g, fin_b);
}

// Round 12
// 1733.393 us; speedup vs baseline: 1.3861x; 1.0531x over previous
//
#include <hip/hip_runtime.h>
#include <hip/hip_bf16.h>
#include <hip/hip_fp16.h>
#include <math.h>

// Problem constants (fixed by reference)
#define N_   65536
#define F_   64
#define H_   128
#define E_   30000
#define NT_  5
#define ET_  10
#define NG_  50
#define L_   3
#define TL_  2
#define NH_  4
#define DH_  32
#define NB_  1024
#define TT_  64
#define FF_  512
#define CH_  512         // temporal node chunk
#define GATTN_GRID 544

#define SCALE_ 0.17677669529663687f   // 1/sqrt(32)

typedef _Float16 hh2 __attribute__((ext_vector_type(2)));

__device__ __forceinline__ float gelu_exact(float x) {
    return 0.5f * x * (1.0f + erff(x * 0.70710678118654752f));
}
__device__ __forceinline__ void f4fma(float4& a, float s, const float4& b) {
    a.x += s * b.x; a.y += s * b.y; a.z += s * b.z; a.w += s * b.w;
}
__device__ __forceinline__ void f4scale(float4& a, float s) {
    a.x *= s; a.y *= s; a.z *= s; a.w *= s;
}
__device__ __forceinline__ float4 f4zero() { return make_float4(0.f, 0.f, 0.f, 0.f); }
__device__ __forceinline__ hh2 f2h2(float a, float b) {
    hh2 r; r[0] = (_Float16)a; r[1] = (_Float16)b; return r;
}
#define FDOT2(a, b, c) __builtin_amdgcn_fdot2((a), (b), (c), false)

union F4H { float4 f; __half2 h[4]; };   // float4 = 4 half2
union U4H2 { float4 f; hh2 h[4]; };
union PK2 { float2 f2; __half2 h[2]; };  // 8-byte fp16 store helper

// ---------------- grouping ----------------

__global__ void k_zero_cnt(int* cnt) {
    if (threadIdx.x < NG_) cnt[threadIdx.x] = 0;
}

__global__ void k_hist(const int* __restrict__ edge_index, const int* __restrict__ edge_type,
                       const int* __restrict__ node_type, int* __restrict__ gedge, int* __restrict__ cnt) {
    int e = blockIdx.x * blockDim.x + threadIdx.x;
    if (e >= E_) return;
    int dn = edge_index[E_ + e];
    int g = edge_type[e] * NT_ + node_type[dn];
    gedge[e] = g;
    atomicAdd(&cnt[g], 1);
}

__global__ void k_scan(const int* __restrict__ cnt, int* __restrict__ offs, int* __restrict__ curs) {
    if (threadIdx.x == 0 && blockIdx.x == 0) {
        int acc = 0;
        for (int g = 0; g < NG_; ++g) { offs[g] = acc; curs[g] = acc; acc += cnt[g]; }
        offs[NG_] = acc;
    }
}

__global__ void k_scatter(const int* __restrict__ gedge, int* __restrict__ curs,
                          int* __restrict__ sorted, int* __restrict__ gpos) {
    int e = blockIdx.x * blockDim.x + threadIdx.x;
    if (e >= E_) return;
    int g = gedge[e];
    int pos = atomicAdd(&curs[g], 1);
    sorted[pos] = e;
    gpos[pos] = g;
}

__global__ void k_desc(const int* __restrict__ offs, int2* __restrict__ desc64, int* __restrict__ nd64) {
    if (threadIdx.x || blockIdx.x) return;
    int n64 = 0;
    for (int g = 0; g < NG_; ++g) {
        int sz = offs[g + 1] - offs[g];
        for (int qs = 0; qs < sz; qs += 64) desc64[n64++] = make_int2(g, qs);
    }
    nd64[0] = n64;
}

// ---------------- input projection ----------------

__global__ void k_inproj(const float* __restrict__ x, const int* __restrict__ node_type,
                         const float* __restrict__ W_in, const float* __restrict__ b_in,
                         float* __restrict__ h) {
    int n = blockIdx.x;
    int j = threadIdx.x;  // 0..127
    __shared__ float sx[F_];
    if (j < F_) sx[j] = x[(size_t)n * F_ + j];
    __syncthreads();
    int nt = node_type[n];
    const float* W = W_in + (size_t)nt * F_ * H_;
    float acc = b_in[(size_t)nt * H_ + j];
    #pragma unroll 8
    for (int f = 0; f < F_; ++f) acc += sx[f] * W[(size_t)f * H_ + j];
    h[(size_t)n * H_ + j] = acc;
}

__global__ void k_zero(float* __restrict__ p, int n) {
    int i = blockIdx.x * blockDim.x + threadIdx.x;
    int stride = gridDim.x * blockDim.x;
    for (; i < n; i += stride) p[i] = 0.0f;
}

// ---------------- spatial qkv projection: fp16/fdot2 tiled GEMM over 64-edge tiles ----------------
// grid = (544, 3); y: 0=q (dst rows) -> qh fp16, 1=k, 2=v (src rows) -> kvh fp16

__global__ __launch_bounds__(256) void k_sqkv_gemm(
    const float* __restrict__ h, const float* __restrict__ s_in_w, const float* __restrict__ s_in_b,
    const int* __restrict__ sorted, const int* __restrict__ offs, const int* __restrict__ edge_index,
    const int2* __restrict__ desc64, const int* __restrict__ nd64,
    __half* __restrict__ qh, __half* __restrict__ kvh, int li) {
    int bx = blockIdx.x;
    if (bx >= nd64[0]) return;
    int2 dd = desc64[bx];
    int g = dd.x, qs = dd.y;
    int qbase = offs[g] + qs;
    int qcnt = min(64, offs[g + 1] - qbase);
    int et = g / NT_;
    int nt = blockIdx.y;
    __shared__ hh2 s_ah[64 * 67];
    __shared__ hh2 s_bh[16 * 132];
    int tid = threadIdx.x;
    #pragma unroll
    for (int i = 0; i < 8; ++i) {
        int idx = i * 256 + tid;
        int r = idx >> 5, c4i = idx & 31;
        int p = qbase + min(r, qcnt - 1);
        int e = sorted[p];
        int node = (nt == 0) ? edge_index[E_ + e] : edge_index[e];
        float4 v = *reinterpret_cast<const float4*>(&h[(size_t)node * H_ + c4i * 4]);
        s_ah[r * 67 + c4i * 2]     = f2h2(v.x, v.y);
        s_ah[r * 67 + c4i * 2 + 1] = f2h2(v.z, v.w);
    }
    const float* B = s_in_w + ((size_t)(li * ET_ + et) * 3 * H_ + nt * H_) * H_;
    const float* bi = s_in_b + (size_t)(li * ET_ + et) * 3 * H_ + nt * H_;
    int rg = tid >> 4, cg = tid & 15;
    int r0 = rg * 4;
    float4 alo[4], ahi[4];
    #pragma unroll
    for (int rr = 0; rr < 4; ++rr) { alo[rr] = f4zero(); ahi[rr] = f4zero(); }
    for (int kci = 0; kci < 4; ++kci) {
        __syncthreads();
        #pragma unroll
        for (int i = 0; i < 4; ++i) {
            int idx = i * 256 + tid;
            int jj = idx >> 3, k4 = (idx & 7) * 4;
            float4 w = *reinterpret_cast<const float4*>(&B[(size_t)jj * H_ + kci * 32 + k4]);
            int k2 = k4 >> 1;
            s_bh[k2 * 132 + jj]       = f2h2(w.x, w.y);
            s_bh[(k2 + 1) * 132 + jj] = f2h2(w.z, w.w);
        }
        __syncthreads();
        #pragma unroll
        for (int k2 = 0; k2 < 16; ++k2) {
            hh2 a2[4];
            #pragma unroll
            for (int rr = 0; rr < 4; ++rr) a2[rr] = s_ah[(r0 + rr) * 67 + kci * 16 + k2];
            U4H2 bl, bh_;
            bl.f  = *reinterpret_cast<const float4*>(&s_bh[k2 * 132 + cg * 4]);
            bh_.f = *reinterpret_cast<const float4*>(&s_bh[k2 * 132 + 64 + cg * 4]);
            #pragma unroll
            for (int rr = 0; rr < 4; ++rr) {
                alo[rr].x = FDOT2(a2[rr], bl.h[0], alo[rr].x);
                alo[rr].y = FDOT2(a2[rr], bl.h[1], alo[rr].y);
                alo[rr].z = FDOT2(a2[rr], bl.h[2], alo[rr].z);
                alo[rr].w = FDOT2(a2[rr], bl.h[3], alo[rr].w);
                ahi[rr].x = FDOT2(a2[rr], bh_.h[0], ahi[rr].x);
                ahi[rr].y = FDOT2(a2[rr], bh_.h[1], ahi[rr].y);
                ahi[rr].z = FDOT2(a2[rr], bh_.h[2], ahi[rr].z);
                ahi[rr].w = FDOT2(a2[rr], bh_.h[3], ahi[rr].w);
            }
        }
    }
    float4 blo = *reinterpret_cast<const float4*>(&bi[cg * 4]);
    float4 bhi = *reinterpret_cast<const float4*>(&bi[64 + cg * 4]);
    #pragma unroll
    for (int rr = 0; rr < 4; ++rr) {
        int row = r0 + rr;
        if (row < qcnt) {
            float4 lo = alo[rr], hi = ahi[rr];
            lo.x += blo.x; lo.y += blo.y; lo.z += blo.z; lo.w += blo.w;
            hi.x += bhi.x; hi.y += bhi.y; hi.z += bhi.z; hi.w += bhi.w;
            __half* base = (nt == 0) ? (qh + (size_t)(qbase + row) * 128)
                                     : (kvh + (size_t)(qbase + row) * 256 + (nt - 1) * 128);
            PK2 p0, p1;
            p0.h[0] = __floats2half2_rn(lo.x, lo.y);
            p0.h[1] = __floats2half2_rn(lo.z, lo.w);
            p1.h[0] = __floats2half2_rn(hi.x, hi.y);
            p1.h[1] = __floats2half2_rn(hi.z, hi.w);
            *reinterpret_cast<float2*>(base + cg * 4)      = p0.f2;
            *reinterpret_cast<float2*>(base + 64 + cg * 4) = p1.f2;
        }
    }
}

// ---------------- grouped spatial attention + out-proj + scatter ----------------
// K/V/Q fp16 in global; stage with raw copies; QK^T via 4 independent hfma2 chains.

__global__ __launch_bounds__(256, 2) void k_gattn(
    const __half* __restrict__ qh, const __half* __restrict__ kvh, const int* __restrict__ sorted,
    const int* __restrict__ offs, const int* __restrict__ edge_index,
    const int2* __restrict__ desc, const int* __restrict__ ndesc,
    const float* __restrict__ s_out_w, const float* __restrict__ s_out_b,
    float* __restrict__ h_new, int li) {
    int bx = blockIdx.x;
    if (bx >= ndesc[0]) return;
    int2 dd = desc[bx];
    int g = dd.x, qs = dd.y;
    int start = offs[g], end = offs[g + 1];
    int qbase = start + qs;
    int qcnt = min(64, end - qbase);
    int et = g / NT_;

    __shared__ __half2 s_kh[32 * 64];
    __shared__ __half2 s_vh[32 * 64];
    __shared__ float  s_o[64 * 132];
    __shared__ int    s_dn[64];
    int tid = threadIdx.x;
    int head = tid >> 6, qi = tid & 63;

    if (tid < 64) s_dn[tid] = edge_index[E_ + sorted[qbase + min(tid, qcnt - 1)]];

    int p0 = qbase + min(qi, qcnt - 1);
    __half2 q2[16];
    {
        const float4* qr = reinterpret_cast<const float4*>(qh + (size_t)p0 * 128 + head * DH_);
        F4H t0, t1, t2, t3;
        t0.f = qr[0]; t1.f = qr[1]; t2.f = qr[2]; t3.f = qr[3];
        #pragma unroll
        for (int i = 0; i < 4; ++i) {
            q2[i] = t0.h[i]; q2[4 + i] = t1.h[i]; q2[8 + i] = t2.h[i]; q2[12 + i] = t3.h[i];
        }
    }
    float m = -1e30f, ssum = 0.0f;
    __half2 o2[16];
    #pragma unroll
    for (int i = 0; i < 16; ++i) o2[i] = __floats2half2_rn(0.f, 0.f);

    int nkt = (end - start + 31) >> 5;
    for (int kt = 0; kt < nkt; ++kt) {
        int kb = start + kt * 32;
        int kcnt = min(32, end - kb);
        __syncthreads();
        // stage k,v tile: 32 rows x 512 B (fp16), raw 16B copies, no conversion
        #pragma unroll
        for (int i = 0; i < 4; ++i) {
            int idx = i * 256 + tid;
            int row = idx >> 5, seg = idx & 31;
            if (row < kcnt) {
                float4 w = *reinterpret_cast<const float4*>(kvh + (size_t)(kb + row) * 256 + seg * 8);
                __half2* dp = (seg < 16) ? &s_kh[row * 64 + seg * 4] : &s_vh[row * 64 + (seg - 16) * 4];
                *reinterpret_cast<float4*>(dp) = w;
            }
        }
        __syncthreads();
        if (kcnt == 32) {
            float sc[32];
            float tmax = -1e30f;
            #pragma unroll
            for (int t2 = 0; t2 < 32; ++t2) {
                const float4* kr = reinterpret_cast<const float4*>(&s_kh[t2 * 64 + head * 16]);
                F4H k0, k1, k2, k3;
                k0.f = kr[0]; k1.f = kr[1]; k2.f = kr[2]; k3.f = kr[3];
                __half2 a0 = __hmul2(q2[0], k0.h[0]), a1 = __hmul2(q2[1], k0.h[1]),
                        a2 = __hmul2(q2[2], k0.h[2]), a3 = __hmul2(q2[3], k0.h[3]);
                a0 = __hfma2(q2[4], k1.h[0], a0); a1 = __hfma2(q2[5], k1.h[1], a1);
                a2 = __hfma2(q2[6], k1.h[2], a2); a3 = __hfma2(q2[7], k1.h[3], a3);
                a0 = __hfma2(q2[8], k2.h[0], a0); a1 = __hfma2(q2[9], k2.h[1], a1);
                a2 = __hfma2(q2[10], k2.h[2], a2); a3 = __hfma2(q2[11], k2.h[3], a3);
                a0 = __hfma2(q2[12], k3.h[0], a0); a1 = __hfma2(q2[13], k3.h[1], a1);
                a2 = __hfma2(q2[14], k3.h[2], a2); a3 = __hfma2(q2[15], k3.h[3], a3);
                __half2 sh = __hadd2(__hadd2(a0, a1), __hadd2(a2, a3));
                float dot = (__low2float(sh) + __high2float(sh)) * SCALE_;
                sc[t2] = dot;
                tmax = fmaxf(tmax, dot);
            }
            float mn = fmaxf(m, tmax);
            float f = __expf(m - mn);
            ssum *= f;
            __half2 f2 = __float2half2_rn(f);
            #pragma unroll
            for (int i = 0; i < 16; ++i) o2[i] = __hmul2(o2[i], f2);
            #pragma unroll
            for (int t2 = 0; t2 < 32; ++t2) {
                float p = __expf(sc[t2] - mn);
                ssum += p;
                __half2 p2 = __float2half2_rn(p);
                const float4* vr = reinterpret_cast<const float4*>(&s_vh[t2 * 64 + head * 16]);
                F4H v0, v1, v2, v3;
                v0.f = vr[0]; v1.f = vr[1]; v2.f = vr[2]; v3.f = vr[3];
                #pragma unroll
                for (int i = 0; i < 4; ++i) o2[i]      = __hfma2(p2, v0.h[i], o2[i]);
                #pragma unroll
                for (int i = 0; i < 4; ++i) o2[4 + i]  = __hfma2(p2, v1.h[i], o2[4 + i]);
                #pragma unroll
                for (int i = 0; i < 4; ++i) o2[8 + i]  = __hfma2(p2, v2.h[i], o2[8 + i]);
                #pragma unroll
                for (int i = 0; i < 4; ++i) o2[12 + i] = __hfma2(p2, v3.h[i], o2[12 + i]);
            }
            m = mn;
        } else {
            float tmax = -1e30f;
            for (int t2 = 0; t2 < kcnt; ++t2) {
                const float4* kr = reinterpret_cast<const float4*>(&s_kh[t2 * 64 + head * 16]);
                F4H k0, k1, k2, k3;
                k0.f = kr[0]; k1.f = kr[1]; k2.f = kr[2]; k3.f = kr[3];
                __half2 a0 = __hmul2(q2[0], k0.h[0]), a1 = __hmul2(q2[1], k0.h[1]),
                        a2 = __hmul2(q2[2], k0.h[2]), a3 = __hmul2(q2[3], k0.h[3]);
                a0 = __hfma2(q2[4], k1.h[0], a0); a1 = __hfma2(q2[5], k1.h[1], a1);
                a2 = __hfma2(q2[6], k1.h[2], a2); a3 = __hfma2(q2[7], k1.h[3], a3);
                a0 = __hfma2(q2[8], k2.h[0], a0); a1 = __hfma2(q2[9], k2.h[1], a1);
                a2 = __hfma2(q2[10], k2.h[2], a2); a3 = __hfma2(q2[11], k2.h[3], a3);
                a0 = __hfma2(q2[12], k3.h[0], a0); a1 = __hfma2(q2[13], k3.h[1], a1);
                a2 = __hfma2(q2[14], k3.h[2], a2); a3 = __hfma2(q2[15], k3.h[3], a3);
                __half2 sh = __hadd2(__hadd2(a0, a1), __hadd2(a2, a3));
                tmax = fmaxf(tmax, (__low2float(sh) + __high2float(sh)) * SCALE_);
            }
            float mn = fmaxf(m, tmax);
            float f = __expf(m - mn);
            ssum *= f;
            __half2 f2 = __float2half2_rn(f);
            #pragma unroll
            for (int i = 0; i < 16; ++i) o2[i] = __hmul2(o2[i], f2);
            for (int t2 = 0; t2 < kcnt; ++t2) {
                const float4* kr = reinterpret_cast<const float4*>(&s_kh[t2 * 64 + head * 16]);
                F4H k0, k1, k2, k3;
                k0.f = kr[0]; k1.f = kr[1]; k2.f = kr[2]; k3.f = kr[3];
                __half2 a0 = __hmul2(q2[0], k0.h[0]), a1 = __hmul2(q2[1], k0.h[1]),
                        a2 = __hmul2(q2[2], k0.h[2]), a3 = __hmul2(q2[3], k0.h[3]);
                a0 = __hfma2(q2[4], k1.h[0], a0); a1 = __hfma2(q2[5], k1.h[1], a1);
                a2 = __hfma2(q2[6], k1.h[2], a2); a3 = __hfma2(q2[7], k1.h[3], a3);
                a0 = __hfma2(q2[8], k2.h[0], a0); a1 = __hfma2(q2[9], k2.h[1], a1);
                a2 = __hfma2(q2[10], k2.h[2], a2); a3 = __hfma2(q2[11], k2.h[3], a3);
                a0 = __hfma2(q2[12], k3.h[0], a0); a1 = __hfma2(q2[13], k3.h[1], a1);
                a2 = __hfma2(q2[14], k3.h[2], a2); a3 = __hfma2(q2[15], k3.h[3], a3);
                __half2 sh = __hadd2(__hadd2(a0, a1), __hadd2(a2, a3));
                float p = __expf((__low2float(sh) + __high2float(sh)) * SCALE_ - mn);
                ssum += p;
                __half2 p2 = __float2half2_rn(p);
                const float4* vr = reinterpret_cast<const float4*>(&s_vh[t2 * 64 + head * 16]);
                F4H v0, v1, v2, v3;
                v0.f = vr[0]; v1.f = vr[1]; v2.f = vr[2]; v3.f = vr[3];
                #pragma unroll
                for (int i = 0; i < 4; ++i) o2[i]      = __hfma2(p2, v0.h[i], o2[i]);
                #pragma unroll
                for (int i = 0; i < 4; ++i) o2[4 + i]  = __hfma2(p2, v1.h[i], o2[4 + i]);
                #pragma unroll
                for (int i = 0; i < 4; ++i) o2[8 + i]  = __hfma2(p2, v2.h[i], o2[8 + i]);
                #pragma unroll
                for (int i = 0; i < 4; ++i) o2[12 + i] = __hfma2(p2, v3.h[i], o2[12 + i]);
            }
            m = mn;
        }
    }
    __syncthreads();
    if (qi < qcnt) {
        float inv = 1.0f / ssum;
        #pragma unroll
        for (int i = 0; i < 16; ++i) {
            float2 of = __half22float2(o2[i]);
            s_o[qi * 132 + head * DH_ + 2 * i]     = of.x * inv;
            s_o[qi * 132 + head * DH_ + 2 * i + 1] = of.y * inv;
        }
    }
    __syncthreads();
    {
        int j = tid & 127, half = tid >> 7;
        const float* Wo = s_out_w + ((size_t)(li * ET_ + et) * H_ + j) * H_;
        float bo = s_out_b[(size_t)(li * ET_ + et) * H_ + j];
        float acc[32];
        #pragma unroll
        for (int qq = 0; qq < 32; ++qq) acc[qq] = bo;
        #pragma unroll 8
        for (int k4 = 0; k4 < 32; ++k4) {
            float4 w = *reinterpret_cast<const float4*>(&Wo[k4 * 4]);
            #pragma unroll
            for (int qq = 0; qq < 32; ++qq) {
                float4 ov = *reinterpret_cast<const float4*>(&s_o[(half * 32 + qq) * 132 + k4 * 4]);
                acc[qq] += w.x * ov.x + w.y * ov.y + w.z * ov.z + w.w * ov.w;
            }
        }
        #pragma unroll
        for (int qq = 0; qq < 32; ++qq) {
            int qrow = half * 32 + qq;
            if (qrow < qcnt) {
                atomicAdd(&h_new[(size_t)s_dn[qrow] * H_ + j], acc[qq]);
            }
        }
    }
}

// ---------------- LN + exact GELU + residual (spatial); 4 nodes/block; re-zeroes h_new ----------------

__global__ __launch_bounds__(256) void k_lngelu(float* __restrict__ h_new, float* __restrict__ h,
                                                const float* __restrict__ ln_g, const float* __restrict__ ln_b, int li) {
    int n = blockIdx.x * 4 + (threadIdx.x >> 6);
    int l = threadIdx.x & 63;
    float v0 = h_new[(size_t)n * H_ + l];
    float v1 = h_new[(size_t)n * H_ + 64 + l];
    h_new[(size_t)n * H_ + l] = 0.0f;
    h_new[(size_t)n * H_ + 64 + l] = 0.0f;
    float s = v0 + v1;
    #pragma unroll
    for (int off = 32; off; off >>= 1) s += __shfl_xor(s, off);
    float mean = s * (1.0f / H_);
    float d0 = v0 - mean, d1 = v1 - mean;
    float vs = d0 * d0 + d1 * d1;
    #pragma unroll
    for (int off = 32; off; off >>= 1) vs += __shfl_xor(vs, off);
    float rstd = rsqrtf(vs * (1.0f / H_) + 1e-5f);
    const float* gg = ln_g + (size_t)li * H_;
    const float* bb = ln_b + (size_t)li * H_;
    float t0 = gelu_exact(d0 * rstd * gg[l] + bb[l]);
    float t1 = gelu_exact(d1 * rstd * gg[64 + l] + bb[64 + l]);
    size_t o = (size_t)n * H_;
    if (li == 0) { h[o + l] = t0; h[o + 64 + l] = t1; }
    else         { h[o + l] += t0; h[o + 64 + l] += t1; }
}

// ---------------- temporal: positional encoding add ----------------

__global__ void k_peadd(float* __restrict__ h) {
    int i = blockIdx.x * blockDim.x + threadIdx.x;
    int stride = gridDim.x * blockDim.x;
    for (; i < N_ * H_; i += stride) {
        int j = i & 127;
        int t = (i >> 7) & 63;
        float dv = __expf((float)(j & ~1) * (-0.0719557841560639f));
        float ang = (float)t * dv;
        float pe = (j & 1) ? cosf(ang) : sinf(ang);
        h[i] += pe;
    }
}

// ---------------- temporal qkv GEMM (fp16/fdot2) ----------------

__global__ __launch_bounds__(256) void k_tqkv(const float* __restrict__ hs,
                                              const float* __restrict__ t_in_w, const float* __restrict__ t_in_b,
                                              float* __restrict__ qc, float* __restrict__ kc, float* __restrict__ vc,
                                              int li, int c0) {
    int nb = blockIdx.x;
    int nt = blockIdx.y;
    int node = c0 + nb;
    __shared__ hh2 s_ah[64 * 67];
    __shared__ hh2 s_bh[16 * 132];
    int tid = threadIdx.x;
    #pragma unroll
    for (int i = 0; i < 8; ++i) {
        int idx = i * 256 + tid;
        int r = idx >> 5, c4i = idx & 31;
        float4 v = *reinterpret_cast<const float4*>(&hs[((size_t)node * 64 + r) * 128 + c4i * 4]);
        s_ah[r * 67 + c4i * 2]     = f2h2(v.x, v.y);
        s_ah[r * 67 + c4i * 2 + 1] = f2h2(v.z, v.w);
    }
    const float* B = t_in_w + ((size_t)li * 384 + nt * 128) * 128;
    const float* bi = t_in_b + (size_t)li * 384 + nt * 128;
    int rg = tid >> 4, cg = tid & 15;
    int r0 = rg * 4;
    float4 alo[4], ahi[4];
    #pragma unroll
    for (int rr = 0; rr < 4; ++rr) { alo[rr] = f4zero(); ahi[rr] = f4zero(); }
    for (int kci = 0; kci < 4; ++kci) {
        __syncthreads();
        #pragma unroll
        for (int i = 0; i < 4; ++i) {
            int idx = i * 256 + tid;
            int jj = idx >> 3, k4 = (idx & 7) * 4;
            float4 w = *reinterpret_cast<const float4*>(&B[(size_t)jj * 128 + kci * 32 + k4]);
            int k2 = k4 >> 1;
            s_bh[k2 * 132 + jj]       = f2h2(w.x, w.y);
            s_bh[(k2 + 1) * 132 + jj] = f2h2(w.z, w.w);
        }
        __syncthreads();
        #pragma unroll
        for (int k2 = 0; k2 < 16; ++k2) {
            hh2 a2[4];
            #pragma unroll
            for (int rr = 0; rr < 4; ++rr) a2[rr] = s_ah[(r0 + rr) * 67 + kci * 16 + k2];
            U4H2 bl, bh_;
            bl.f  = *reinterpret_cast<const float4*>(&s_bh[k2 * 132 + cg * 4]);
            bh_.f = *reinterpret_cast<const float4*>(&s_bh[k2 * 132 + 64 + cg * 4]);
            #pragma unroll
            for (int rr = 0; rr < 4; ++rr) {
                alo[rr].x = FDOT2(a2[rr], bl.h[0], alo[rr].x);
                alo[rr].y = FDOT2(a2[rr], bl.h[1], alo[rr].y);
                alo[rr].z = FDOT2(a2[rr], bl.h[2], alo[rr].z);
                alo[rr].w = FDOT2(a2[rr], bl.h[3], alo[rr].w);
                ahi[rr].x = FDOT2(a2[rr], bh_.h[0], ahi[rr].x);
                ahi[rr].y = FDOT2(a2[rr], bh_.h[1], ahi[rr].y);
                ahi[rr].z = FDOT2(a2[rr], bh_.h[2], ahi[rr].z);
                ahi[rr].w = FDOT2(a2[rr], bh_.h[3], ahi[rr].w);
            }
        }
    }
    float* dst = (nt == 0) ? qc : (nt == 1) ? kc : vc;
    float sc = (nt == 0) ? SCALE_ : 1.0f;
    float4 blo = *reinterpret_cast<const float4*>(&bi[cg * 4]);
    float4 bhi = *reinterpret_cast<const float4*>(&bi[64 + cg * 4]);
    #pragma unroll
    for (int rr = 0; rr < 4; ++rr) {
        float4 lo = alo[rr], hi = ahi[rr];
        lo.x = (lo.x + blo.x) * sc; lo.y = (lo.y + blo.y) * sc; lo.z = (lo.z + blo.z) * sc; lo.w = (lo.w + blo.w) * sc;
        hi.x = (hi.x + bhi.x) * sc; hi.y = (hi.y + bhi.y) * sc; hi.z = (hi.z + bhi.z) * sc; hi.w = (hi.w + bhi.w) * sc;
        size_t row = (size_t)nb * 64 + r0 + rr;
        *reinterpret_cast<float4*>(&dst[row * 128 + cg * 4]) = lo;
        *reinterpret_cast<float4*>(&dst[row * 128 + 64 + cg * 4]) = hi;
    }
}

// ---------------- temporal attention (fp32) ----------------

__global__ __launch_bounds__(64) void k_tattn(float* __restrict__ qc, const float* __restrict__ kc,
                                              const float* __restrict__ vc) {
    int nb = blockIdx.x, head = blockIdx.y;
    __shared__ float s_k[64 * 36];
    __shared__ float s_v[64 * 36];
    int t = threadIdx.x;
    #pragma unroll
    for (int i = 0; i < 8; ++i) {
        int idx = i * 64 + t;
        int row = idx >> 3, d4 = (idx & 7) * 4;
        *reinterpret_cast<float4*>(&s_k[row * 36 + d4]) =
            *reinterpret_cast<const float4*>(&kc[((size_t)nb * 64 + row) * 128 + head * DH_ + d4]);
        *reinterpret_cast<float4*>(&s_v[row * 36 + d4]) =
            *reinterpret_cast<const float4*>(&vc[((size_t)nb * 64 + row) * 128 + head * DH_ + d4]);
    }
    float4 q[8];
    {
        const float4* qr = reinterpret_cast<const float4*>(&qc[((size_t)nb * 64 + t) * 128 + head * DH_]);
        #pragma unroll
        for (int i = 0; i < 8; ++i) q[i] = qr[i];
    }
    __syncthreads();
    float m = -1e30f;
    for (int t2 = 0; t2 < 64; ++t2) {
        const float4* kr = reinterpret_cast<const float4*>(&s_k[t2 * 36]);
        float s0 = 0, s1 = 0, s2 = 0, s3 = 0;
        #pragma unroll
        for (int i = 0; i < 8; ++i) {
            float4 kk = kr[i];
            s0 += q[i].x * kk.x; s1 += q[i].y * kk.y; s2 += q[i].z * kk.z; s3 += q[i].w * kk.w;
        }
        m = fmaxf(m, (s0 + s1) + (s2 + s3));
    }
    float ssum = 0.0f;
    float4 o[8];
    #pragma unroll
    for (int i = 0; i < 8; ++i) o[i] = f4zero();
    for (int t2 = 0; t2 < 64; ++t2) {
        const float4* kr = reinterpret_cast<const float4*>(&s_k[t2 * 36]);
        float s0 = 0, s1 = 0, s2 = 0, s3 = 0;
        #pragma unroll
        for (int i = 0; i < 8; ++i) {
            float4 kk = kr[i];
            s0 += q[i].x * kk.x; s1 += q[i].y * kk.y; s2 += q[i].z * kk.z; s3 += q[i].w * kk.w;
        }
        float p = __expf((s0 + s1) + (s2 + s3) - m);
        ssum += p;
        const float4* vr = reinterpret_cast<const float4*>(&s_v[t2 * 36]);
        #pragma unroll
        for (int i = 0; i < 8; ++i) f4fma(o[i], p, vr[i]);
    }
    float inv = 1.0f / ssum;
    float4* orow = reinterpret_cast<float4*>(&qc[((size_t)nb * 64 + t) * 128 + head * DH_]);
    #pragma unroll
    for (int i = 0; i < 8; ++i) { float4 v = o[i]; f4scale(v, inv); orow[i] = v; }
}

// ---------------- temporal out-proj (fp16/fdot2) + residual + LN1 ----------------

__global__ __launch_bounds__(256) void k_toutln(const float* __restrict__ oc, float* __restrict__ hs,
                                                const float* __restrict__ t_out_w, const float* __restrict__ t_out_b,
                                                const float* __restrict__ ln_g, const float* __restrict__ ln_b,
                                                int li, int c0) {
    int nb = blockIdx.x;
    int node = c0 + nb;
    __shared__ hh2 s_ah[64 * 67];
    __shared__ hh2 s_bh[16 * 132];
    int tid = threadIdx.x;
    #pragma unroll
    for (int i = 0; i < 8; ++i) {
        int idx = i * 256 + tid;
        int r = idx >> 5, c4i = idx & 31;
        float4 v = *reinterpret_cast<const float4*>(&oc[((size_t)nb * 64 + r) * 128 + c4i * 4]);
        s_ah[r * 67 + c4i * 2]     = f2h2(v.x, v.y);
        s_ah[r * 67 + c4i * 2 + 1] = f2h2(v.z, v.w);
    }
    const float* B = t_out_w + (size_t)li * 128 * 128;
    const float* bo = t_out_b + (size_t)li * 128;
    int rg = tid >> 4, cg = tid & 15;
    int r0 = rg * 4;
    float4 alo[4], ahi[4];
    #pragma unroll
    for (int rr = 0; rr < 4; ++rr) { alo[rr] = f4zero(); ahi[rr] = f4zero(); }
    for (int kci = 0; kci < 4; ++kci) {
        __syncthreads();
        #pragma unroll
        for (int i = 0; i < 4; ++i) {
            int idx = i * 256 + tid;
            int jj = idx >> 3, k4 = (idx & 7) * 4;
            float4 w = *reinterpret_cast<const float4*>(&B[(size_t)jj * 128 + kci * 32 + k4]);
            int k2 = k4 >> 1;
            s_bh[k2 * 132 + jj]       = f2h2(w.x, w.y);
            s_bh[(k2 + 1) * 132 + jj] = f2h2(w.z, w.w);
        }
        __syncthreads();
        #pragma unroll
        for (int k2 = 0; k2 < 16; ++k2) {
            hh2 a2[4];
            #pragma unroll
            for (int rr = 0; rr < 4; ++rr) a2[rr] = s_ah[(r0 + rr) * 67 + kci * 16 + k2];
            U4H2 bl, bh_;
            bl.f  = *reinterpret_cast<const float4*>(&s_bh[k2 * 132 + cg * 4]);
            bh_.f = *reinterpret_cast<const float4*>(&s_bh[k2 * 132 + 64 + cg * 4]);
            #pragma unroll
            for (int rr = 0; rr < 4; ++rr) {
                alo[rr].x = FDOT2(a2[rr], bl.h[0], alo[rr].x);
                alo[rr].y = FDOT2(a2[rr], bl.h[1], alo[rr].y);
                alo[rr].z = FDOT2(a2[rr], bl.h[2], alo[rr].z);
                alo[rr].w = FDOT2(a2[rr], bl.h[3], alo[rr].w);
                ahi[rr].x = FDOT2(a2[rr], bh_.h[0], ahi[rr].x);
                ahi[rr].y = FDOT2(a2[rr], bh_.h[1], ahi[rr].y);
                ahi[rr].z = FDOT2(a2[rr], bh_.h[2], ahi[rr].z);
                ahi[rr].w = FDOT2(a2[rr], bh_.h[3], ahi[rr].w);
            }
        }
    }
    float4 bblo = *reinterpret_cast<const float4*>(&bo[cg * 4]);
    float4 bbhi = *reinterpret_cast<const float4*>(&bo[64 + cg * 4]);
    float4 glo = *reinterpret_cast<const float4*>(&ln_g[(size_t)li * 128 + cg * 4]);
    float4 ghi = *reinterpret_cast<const float4*>(&ln_g[(size_t)li * 128 + 64 + cg * 4]);
    float4 lblo = *reinterpret_cast<const float4*>(&ln_b[(size_t)li * 128 + cg * 4]);
    float4 lbhi = *reinterpret_cast<const float4*>(&ln_b[(size_t)li * 128 + 64 + cg * 4]);
    #pragma unroll
    for (int rr = 0; rr < 4; ++rr) {
        size_t row = (size_t)node * 64 + r0 + rr;
        float4 rlo = *reinterpret_cast<const float4*>(&hs[row * 128 + cg * 4]);
        float4 rhi = *reinterpret_cast<const float4*>(&hs[row * 128 + 64 + cg * 4]);
        float4 lo = alo[rr], hi = ahi[rr];
        lo.x += bblo.x + rlo.x; lo.y += bblo.y + rlo.y; lo.z += bblo.z + rlo.z; lo.w += bblo.w + rlo.w;
        hi.x += bbhi.x + rhi.x; hi.y += bbhi.y + rhi.y; hi.z += bbhi.z + rhi.z; hi.w += bbhi.w + rhi.w;
        float s = lo.x + lo.y + lo.z + lo.w + hi.x + hi.y + hi.z + hi.w;
        s += __shfl_xor(s, 1); s += __shfl_xor(s, 2); s += __shfl_xor(s, 4); s += __shfl_xor(s, 8);
        float mean = s * (1.0f / 128.0f);
        float4 dlo = make_float4(lo.x - mean, lo.y - mean, lo.z - mean, lo.w - mean);
        float4 dhi = make_float4(hi.x - mean, hi.y - mean, hi.z - mean, hi.w - mean);
        float vx = dlo.x * dlo.x + dlo.y * dlo.y + dlo.z * dlo.z + dlo.w * dlo.w +
                   dhi.x * dhi.x + dhi.y * dhi.y + dhi.z * dhi.z + dhi.w * dhi.w;
        vx += __shfl_xor(vx, 1); vx += __shfl_xor(vx, 2); vx += __shfl_xor(vx, 4); vx += __shfl_xor(vx, 8);
        float rstd = rsqrtf(vx * (1.0f / 128.0f) + 1e-5f);
        float4 olo = make_float4(dlo.x * rstd * glo.x + lblo.x, dlo.y * rstd * glo.y + lblo.y,
                                 dlo.z * rstd * glo.z + lblo.z, dlo.w * rstd * glo.w + lblo.w);
        float4 ohi = make_float4(dhi.x * rstd * ghi.x + lbhi.x, dhi.y * rstd * ghi.y + lbhi.y,
                                 dhi.z * rstd * ghi.z + lbhi.z, dhi.w * rstd * ghi.w + lbhi.w);
        *reinterpret_cast<float4*>(&hs[row * 128 + cg * 4]) = olo;
        *reinterpret_cast<float4*>(&hs[row * 128 + 64 + cg * 4]) = ohi;
    }
}

// ---------------- temporal fused FF (fp16/fdot2) + residual + LN2 ----------------

__global__ __launch_bounds__(256) void k_tff(float* __restrict__ hs,
                                             const float* __restrict__ t_w1, const float* __restrict__ t_b1,
                                             const float* __restrict__ t_w2, const float* __restrict__ t_b2,
                                             const float* __restrict__ ln_g, const float* __restrict__ ln_b,
                                             int li) {
    int node = blockIdx.x;
    __shared__ hh2 s_hh[64 * 67];
    __shared__ hh2 s_fh[64 * 67];
    __shared__ hh2 s_bh[16 * 132];
    int tid = threadIdx.x;
    #pragma unroll
    for (int i = 0; i < 8; ++i) {
        int idx = i * 256 + tid;
        int r = idx >> 5, c4i = idx & 31;
        float4 v = *reinterpret_cast<const float4*>(&hs[((size_t)node * 64 + r) * 128 + c4i * 4]);
        s_hh[r * 67 + c4i * 2]     = f2h2(v.x, v.y);
        s_hh[r * 67 + c4i * 2 + 1] = f2h2(v.z, v.w);
    }
    int rg = tid >> 4, cg = tid & 15;
    int r0 = rg * 4;
    const float* W1 = t_w1 + (size_t)li * FF_ * 128;
    const float* b1 = t_b1 + (size_t)li * FF_;
    const float* W2 = t_w2 + (size_t)li * 128 * FF_;
    const float* b2 = t_b2 + (size_t)li * 128;
    float4 c2lo[4], c2hi[4];
    #pragma unroll
    for (int rr = 0; rr < 4; ++rr) { c2lo[rr] = f4zero(); c2hi[rr] = f4zero(); }

    for (int nt = 0; nt < 4; ++nt) {
        float4 c1lo[4], c1hi[4];
        #pragma unroll
        for (int rr = 0; rr < 4; ++rr) { c1lo[rr] = f4zero(); c1hi[rr] = f4zero(); }
        for (int kci = 0; kci < 4; ++kci) {
            __syncthreads();
            #pragma unroll
            for (int i = 0; i < 4; ++i) {
                int idx = i * 256 + tid;
                int jj = idx >> 3, k4 = (idx & 7) * 4;
                float4 w = *reinterpret_cast<const float4*>(&W1[(size_t)(nt * 128 + jj) * 128 + kci * 32 + k4]);
                int k2 = k4 >> 1;
                s_bh[k2 * 132 + jj]       = f2h2(w.x, w.y);
                s_bh[(k2 + 1) * 132 + jj] = f2h2(w.z, w.w);
            }
            __syncthreads();
            #pragma unroll
            for (int k2 = 0; k2 < 16; ++k2) {
                hh2 a2[4];
                #pragma unroll
                for (int rr = 0; rr < 4; ++rr) a2[rr] = s_hh[(r0 + rr) * 67 + kci * 16 + k2];
                U4H2 bl, bh_;
                bl.f  = *reinterpret_cast<const float4*>(&s_bh[k2 * 132 + cg * 4]);
                bh_.f = *reinterpret_cast<const float4*>(&s_bh[k2 * 132 + 64 + cg * 4]);
                #pragma unroll
                for (int rr = 0; rr < 4; ++rr) {
                    c1lo[rr].x = FDOT2(a2[rr], bl.h[0], c1lo[rr].x);
                    c1lo[rr].y = FDOT2(a2[rr], bl.h[1], c1lo[rr].y);
                    c1lo[rr].z = FDOT2(a2[rr], bl.h[2], c1lo[rr].z);
                    c1lo[rr].w = FDOT2(a2[rr], bl.h[3], c1lo[rr].w);
                    c1hi[rr].x = FDOT2(a2[rr], bh_.h[0], c1hi[rr].x);
                    c1hi[rr].y = FDOT2(a2[rr], bh_.h[1], c1hi[rr].y);
                    c1hi[rr].z = FDOT2(a2[rr], bh_.h[2], c1hi[rr].z);
                    c1hi[rr].w = FDOT2(a2[rr], bh_.h[3], c1hi[rr].w);
                }
            }
        }
        __syncthreads();
        {
            float4 blo = *reinterpret_cast<const float4*>(&b1[nt * 128 + cg * 4]);
            float4 bhi = *reinterpret_cast<const float4*>(&b1[nt * 128 + 64 + cg * 4]);
            #pragma unroll
            for (int rr = 0; rr < 4; ++rr) {
                float gx = gelu_exact(c1lo[rr].x + blo.x), gy = gelu_exact(c1lo[rr].y + blo.y);
                float gz = gelu_exact(c1lo[rr].z + blo.z), gw = gelu_exact(c1lo[rr].w + blo.w);
                s_fh[(r0 + rr) * 67 + cg * 2]     = f2h2(gx, gy);
                s_fh[(r0 + rr) * 67 + cg * 2 + 1] = f2h2(gz, gw);
                float hx = gelu_exact(c1hi[rr].x + bhi.x), hy = gelu_exact(c1hi[rr].y + bhi.y);
                float hz = gelu_exact(c1hi[rr].z + bhi.z), hw = gelu_exact(c1hi[rr].w + bhi.w);
                s_fh[(r0 + rr) * 67 + 32 + cg * 2]     = f2h2(hx, hy);
                s_fh[(r0 + rr) * 67 + 32 + cg * 2 + 1] = f2h2(hz, hw);
            }
        }
        for (int kci = 0; kci < 4; ++kci) {
            __syncthreads();
            #pragma unroll
            for (int i = 0; i < 4; ++i) {
                int idx = i * 256 + tid;
                int jj = idx >> 3, k4 = (idx & 7) * 4;
                float4 w = *reinterpret_cast<const float4*>(&W2[(size_t)jj * FF_ + nt * 128 + kci * 32 + k4]);
                int k2 = k4 >> 1;
                s_bh[k2 * 132 + jj]       = f2h2(w.x, w.y);
                s_bh[(k2 + 1) * 132 + jj] = f2h2(w.z, w.w);
            }
            __syncthreads();
            #pragma unroll
            for (int k2 = 0; k2 < 16; ++k2) {
                hh2 a2[4];
                #pragma unroll
                for (int rr = 0; rr < 4; ++rr) a2[rr] = s_fh[(r0 + rr) * 67 + kci * 16 + k2];
                U4H2 bl, bh_;
                bl.f  = *reinterpret_cast<const float4*>(&s_bh[k2 * 132 + cg * 4]);
                bh_.f = *reinterpret_cast<const float4*>(&s_bh[k2 * 132 + 64 + cg * 4]);
                #pragma unroll
                for (int rr = 0; rr < 4; ++rr) {
                    c2lo[rr].x = FDOT2(a2[rr], bl.h[0], c2lo[rr].x);
                    c2lo[rr].y = FDOT2(a2[rr], bl.h[1], c2lo[rr].y);
                    c2lo[rr].z = FDOT2(a2[rr], bl.h[2], c2lo[rr].z);
                    c2lo[rr].w = FDOT2(a2[rr], bl.h[3], c2lo[rr].w);
                    c2hi[rr].x = FDOT2(a2[rr], bh_.h[0], c2hi[rr].x);
                    c2hi[rr].y = FDOT2(a2[rr], bh_.h[1], c2hi[rr].y);
                    c2hi[rr].z = FDOT2(a2[rr], bh_.h[2], c2hi[rr].z);
                    c2hi[rr].w = FDOT2(a2[rr], bh_.h[3], c2hi[rr].w);
                }
            }
        }
    }
    float4 bblo = *reinterpret_cast<const float4*>(&b2[cg * 4]);
    float4 bbhi = *reinterpret_cast<const float4*>(&b2[64 + cg * 4]);
    float4 glo = *reinterpret_cast<const float4*>(&ln_g[(size_t)li * 128 + cg * 4]);
    float4 ghi = *reinterpret_cast<const float4*>(&ln_g[(size_t)li * 128 + 64 + cg * 4]);
    float4 lblo = *reinterpret_cast<const float4*>(&ln_b[(size_t)li * 128 + cg * 4]);
    float4 lbhi = *reinterpret_cast<const float4*>(&ln_b[(size_t)li * 128 + 64 + cg * 4]);
    #pragma unroll
    for (int rr = 0; rr < 4; ++rr) {
        size_t row = (size_t)node * 64 + r0 + rr;
        hh2 ra = s_hh[(r0 + rr) * 67 + cg * 2];
        hh2 rb = s_hh[(r0 + rr) * 67 + cg * 2 + 1];
        hh2 rc = s_hh[(r0 + rr) * 67 + 32 + cg * 2];
        hh2 rd = s_hh[(r0 + rr) * 67 + 32 + cg * 2 + 1];
        float4 lo = c2lo[rr], hi = c2hi[rr];
        lo.x += bblo.x + (float)ra[0]; lo.y += bblo.y + (float)ra[1];
        lo.z += bblo.z + (float)rb[0]; lo.w += bblo.w + (float)rb[1];
        hi.x += bbhi.x + (float)rc[0]; hi.y += bbhi.y + (float)rc[1];
        hi.z += bbhi.z + (float)rd[0]; hi.w += bbhi.w + (float)rd[1];
        float s = lo.x + lo.y + lo.z + lo.w + hi.x + hi.y + hi.z + hi.w;
        s += __shfl_xor(s, 1); s += __shfl_xor(s, 2); s += __shfl_xor(s, 4); s += __shfl_xor(s, 8);
        float mean = s * (1.0f / 128.0f);
        float4 dlo = make_float4(lo.x - mean, lo.y - mean, lo.z - mean, lo.w - mean);
        float4 dhi = make_float4(hi.x - mean, hi.y - mean, hi.z - mean, hi.w - mean);
        float vx = dlo.x * dlo.x + dlo.y * dlo.y + dlo.z * dlo.z + dlo.w * dlo.w +
                   dhi.x * dhi.x + dhi.y * dhi.y + dhi.z * dhi.z + dhi.w * dhi.w;
        vx += __shfl_xor(vx, 1); vx += __shfl_xor(vx, 2); vx += __shfl_xor(vx, 4); vx += __shfl_xor(vx, 8);
        float rstd = rsqrtf(vx * (1.0f / 128.0f) + 1e-5f);
        float4 olo = make_float4(dlo.x * rstd * glo.x + lblo.x, dlo.y * rstd * glo.y + lblo.y,
                                 dlo.z * rstd * glo.z + lblo.z, dlo.w * rstd * glo.w + lblo.w);
        float4 ohi = make_float4(dhi.x * rstd * ghi.x + lbhi.x, dhi.y * rstd * ghi.y + lbhi.y,
                                 dhi.z * rstd * ghi.z + lbhi.z, dhi.w * rstd * ghi.w + lbhi.w);
        *reinterpret_cast<float4*>(&hs[row * 128 + cg * 4]) = olo;
        *reinterpret_cast<float4*>(&hs[row * 128 + 64 + cg * 4]) = ohi;
    }
}

// ---------------- final LN -> out ----------------

__global__ __launch_bounds__(256) void k_fln(const float* __restrict__ hs, float* __restrict__ out,
                                             const float* __restrict__ g, const float* __restrict__ b) {
    int row = blockIdx.x * 4 + (threadIdx.x >> 6);
    int l = threadIdx.x & 63;
    float v0 = hs[(size_t)row * H_ + l];
    float v1 = hs[(size_t)row * H_ + 64 + l];
    float s = v0 + v1;
    #pragma unroll
    for (int off = 32; off; off >>= 1) s += __shfl_xor(s, off);
    float mean = s * (1.0f / H_);
    float d0 = v0 - mean, d1 = v1 - mean;
    float vs = d0 * d0 + d1 * d1;
    #pragma unroll
    for (int off = 32; off; off >>= 1) vs += __shfl_xor(vs, off);
    float rstd = rsqrtf(vs * (1.0f / H_) + 1e-5f);
    out[(size_t)row * H_ + l] = d0 * rstd * g[l] + b[l];
    out[(size_t)row * H_ + 64 + l] = d1 * rstd * g[64 + l] + b[64 + l];
}

// ---------------- launch ----------------

extern "C" void kernel_launch(void* const* d_in, const int* in_sizes, int n_in,
                              void* d_out, int out_size, void* d_ws, size_t ws_size,
                              hipStream_t stream) {
    const float* x          = (const float*)d_in[0];
    const int*   edge_index = (const int*)d_in[1];
    const int*   edge_type  = (const int*)d_in[2];
    const int*   node_type  = (const int*)d_in[3];
    const float* W_in    = (const float*)d_in[6];
    const float* b_in    = (const float*)d_in[7];
    const float* s_in_w  = (const float*)d_in[8];
    const float* s_in_b  = (const float*)d_in[9];
    const float* s_out_w = (const float*)d_in[10];
    const float* s_out_b = (const float*)d_in[11];
    const float* ln_s_g  = (const float*)d_in[12];
    const float* ln_s_b  = (const float*)d_in[13];
    const float* t_in_w  = (const float*)d_in[14];
    const float* t_in_b  = (const float*)d_in[15];
    const float* t_out_w = (const float*)d_in[16];
    const float* t_out_b = (const float*)d_in[17];
    const float* t_ln1_g = (const float*)d_in[18];
    const float* t_ln1_b = (const float*)d_in[19];
    const float* t_w1    = (const float*)d_in[20];
    const float* t_b1    = (const float*)d_in[21];
    const float* t_w2    = (const float*)d_in[22];
    const float* t_b2    = (const float*)d_in[23];
    const float* t_ln2_g = (const float*)d_in[24];
    const float* t_ln2_b = (const float*)d_in[25];
    const float* fin_g   = (const float*)d_in[26];
    const float* fin_b   = (const float*)d_in[27];
    float* out = (float*)d_out;

    // workspace layout (floats)
    float* h     = (float*)d_ws;                       // N*H = 8388608
    float* h_new = h + (size_t)N_ * H_;                // 8388608
    float* spat  = h_new + (size_t)N_ * H_;            // 11520000 float region
    __half* qh   = (__half*)spat;                      // E*128 halves
    __half* kvh  = (__half*)spat + (size_t)E_ * 128;   // E*256 halves
    int* sorted  = (int*)(spat + (size_t)E_ * 384);    // E
    int* gpos    = sorted + E_;                        // E
    int* gedge   = gpos + E_;                          // E
    int* cnt     = gedge + E_;                         // 64
    int* offs    = cnt + 64;                           // 64
    int* curs    = offs + 64;                          // 64
    int* nd64    = curs + 64;                          // 16
    int2* desc64 = (int2*)(nd64 + 16);                 // 544 int2

    // temporal chunk buffers (alias spat region + h_new, used after spatial completes)
    float* qc = spat;                                  // CH*64*128 = 4194304
    float* kc = spat + (size_t)CH_ * 64 * 128;         // 4194304
    float* vc = h_new;                                 // 4194304

    k_zero_cnt<<<1, 64, 0, stream>>>(cnt);
    k_hist<<<(E_ + 255) / 256, 256, 0, stream>>>(edge_index, edge_type, node_type, gedge, cnt);
    k_scan<<<1, 1, 0, stream>>>(cnt, offs, curs);
    k_scatter<<<(E_ + 255) / 256, 256, 0, stream>>>(gedge, curs, sorted, gpos);
    k_desc<<<1, 1, 0, stream>>>(offs, desc64, nd64);

    k_inproj<<<N_, 128, 0, stream>>>(x, node_type, W_in, b_in, h);

    k_zero<<<2048, 256, 0, stream>>>(h_new, N_ * H_);   // layer 0; later layers zeroed by k_lngelu
    for (int li = 0; li < L_; ++li) {
        k_sqkv_gemm<<<dim3(GATTN_GRID, 3), 256, 0, stream>>>(h, s_in_w, s_in_b, sorted, offs, edge_index,
                                                             desc64, nd64, qh, kvh, li);
        k_gattn<<<GATTN_GRID, 256, 0, stream>>>(qh, kvh, sorted, offs, edge_index, desc64, nd64,
                                                s_out_w, s_out_b, h_new, li);
        k_lngelu<<<N_ / 4, 256, 0, stream>>>(h_new, h, ln_s_g, ln_s_b, li);
    }

    // temporal: hs = h + PE (in place)
    k_peadd<<<2048, 256, 0, stream>>>(h);
    for (int li = 0; li < TL_; ++li) {
        for (int c = 0; c < NB_ / CH_; ++c) {
            int c0 = c * CH_;
            k_tqkv<<<dim3(CH_, 3), 256, 0, stream>>>(h, t_in_w, t_in_b, qc, kc, vc, li, c0);
            k_tattn<<<dim3(CH_, NH_), 64, 0, stream>>>(qc, kc, vc);
            k_toutln<<<CH_, 256, 0, stream>>>(qc, h, t_out_w, t_out_b, t_ln1_g, t_ln1_b, li, c0);
        }
        k_tff<<<NB_, 256, 0, stream>>>(h, t_w1, t_b1, t_w2, t_b2, t_ln2_g, t_ln2_b, li);
    }
    k_fln<<<N_ / 4, 256, 0, stream>>>(h, out, fin_g, fin_b);
}

// Round 13
// 1506.397 us; speedup vs baseline: 1.5949x; 1.1507x over previous
//
#include <hip/hip_runtime.h>
#include <hip/hip_bf16.h>
#include <hip/hip_fp16.h>
#include <math.h>

// Problem constants (fixed by reference)
#define N_   65536
#define F_   64
#define H_   128
#define E_   30000
#define NT_  5
#define ET_  10
#define NG_  50
#define L_   3
#define TL_  2
#define NH_  4
#define DH_  32
#define NB_  1024
#define TT_  64
#define FF_  512
#define CH_  512         // temporal node chunk
#define GATTN_GRID 544

#define SCALE_ 0.17677669529663687f   // 1/sqrt(32)

typedef _Float16 hh2 __attribute__((ext_vector_type(2)));
typedef _Float16 f16x8 __attribute__((ext_vector_type(8)));
typedef float f32x4 __attribute__((ext_vector_type(4)));

__device__ __forceinline__ float gelu_exact(float x) {
    return 0.5f * x * (1.0f + erff(x * 0.70710678118654752f));
}
__device__ __forceinline__ void f4fma(float4& a, float s, const float4& b) {
    a.x += s * b.x; a.y += s * b.y; a.z += s * b.z; a.w += s * b.w;
}
__device__ __forceinline__ void f4scale(float4& a, float s) {
    a.x *= s; a.y *= s; a.z *= s; a.w *= s;
}
__device__ __forceinline__ float4 f4zero() { return make_float4(0.f, 0.f, 0.f, 0.f); }
__device__ __forceinline__ hh2 f2h2(float a, float b) {
    hh2 r; r[0] = (_Float16)a; r[1] = (_Float16)b; return r;
}
#define FDOT2(a, b, c) __builtin_amdgcn_fdot2((a), (b), (c), false)

union F4H { float4 f; __half2 h[4]; };   // float4 = 4 half2
union U4H2 { float4 f; hh2 h[4]; };
union PK2 { float2 f2; __half2 h[2]; };  // 8-byte fp16 store helper
union U4V8 { float4 f; f16x8 v; };       // 16B LDS read as 8 fp16 (MFMA fragment)

// ---------------- grouping ----------------

__global__ void k_zero_cnt(int* cnt) {
    if (threadIdx.x < NG_) cnt[threadIdx.x] = 0;
}

__global__ void k_hist(const int* __restrict__ edge_index, const int* __restrict__ edge_type,
                       const int* __restrict__ node_type, int* __restrict__ gedge, int* __restrict__ cnt) {
    int e = blockIdx.x * blockDim.x + threadIdx.x;
    if (e >= E_) return;
    int dn = edge_index[E_ + e];
    int g = edge_type[e] * NT_ + node_type[dn];
    gedge[e] = g;
    atomicAdd(&cnt[g], 1);
}

__global__ void k_scan(const int* __restrict__ cnt, int* __restrict__ offs, int* __restrict__ curs) {
    if (threadIdx.x == 0 && blockIdx.x == 0) {
        int acc = 0;
        for (int g = 0; g < NG_; ++g) { offs[g] = acc; curs[g] = acc; acc += cnt[g]; }
        offs[NG_] = acc;
    }
}

__global__ void k_scatter(const int* __restrict__ gedge, int* __restrict__ curs,
                          int* __restrict__ sorted, int* __restrict__ gpos) {
    int e = blockIdx.x * blockDim.x + threadIdx.x;
    if (e >= E_) return;
    int g = gedge[e];
    int pos = atomicAdd(&curs[g], 1);
    sorted[pos] = e;
    gpos[pos] = g;
}

__global__ void k_desc(const int* __restrict__ offs, int2* __restrict__ desc64, int* __restrict__ nd64) {
    if (threadIdx.x || blockIdx.x) return;
    int n64 = 0;
    for (int g = 0; g < NG_; ++g) {
        int sz = offs[g + 1] - offs[g];
        for (int qs = 0; qs < sz; qs += 64) desc64[n64++] = make_int2(g, qs);
    }
    nd64[0] = n64;
}

// ---------------- input projection ----------------

__global__ void k_inproj(const float* __restrict__ x, const int* __restrict__ node_type,
                         const float* __restrict__ W_in, const float* __restrict__ b_in,
                         float* __restrict__ h) {
    int n = blockIdx.x;
    int j = threadIdx.x;  // 0..127
    __shared__ float sx[F_];
    if (j < F_) sx[j] = x[(size_t)n * F_ + j];
    __syncthreads();
    int nt = node_type[n];
    const float* W = W_in + (size_t)nt * F_ * H_;
    float acc = b_in[(size_t)nt * H_ + j];
    #pragma unroll 8
    for (int f = 0; f < F_; ++f) acc += sx[f] * W[(size_t)f * H_ + j];
    h[(size_t)n * H_ + j] = acc;
}

__global__ void k_zero(float* __restrict__ p, int n) {
    int i = blockIdx.x * blockDim.x + threadIdx.x;
    int stride = gridDim.x * blockDim.x;
    for (; i < n; i += stride) p[i] = 0.0f;
}

// ---------------- spatial qkv projection: fp16/fdot2 tiled GEMM over 64-edge tiles ----------------

__global__ __launch_bounds__(256) void k_sqkv_gemm(
    const float* __restrict__ h, const float* __restrict__ s_in_w, const float* __restrict__ s_in_b,
    const int* __restrict__ sorted, const int* __restrict__ offs, const int* __restrict__ edge_index,
    const int2* __restrict__ desc64, const int* __restrict__ nd64,
    __half* __restrict__ qh, __half* __restrict__ kvh, int li) {
    int bx = blockIdx.x;
    if (bx >= nd64[0]) return;
    int2 dd = desc64[bx];
    int g = dd.x, qs = dd.y;
    int qbase = offs[g] + qs;
    int qcnt = min(64, offs[g + 1] - qbase);
    int et = g / NT_;
    int nt = blockIdx.y;
    __shared__ hh2 s_ah[64 * 67];
    __shared__ hh2 s_bh[16 * 132];
    int tid = threadIdx.x;
    #pragma unroll
    for (int i = 0; i < 8; ++i) {
        int idx = i * 256 + tid;
        int r = idx >> 5, c4i = idx & 31;
        int p = qbase + min(r, qcnt - 1);
        int e = sorted[p];
        int node = (nt == 0) ? edge_index[E_ + e] : edge_index[e];
        float4 v = *reinterpret_cast<const float4*>(&h[(size_t)node * H_ + c4i * 4]);
        s_ah[r * 67 + c4i * 2]     = f2h2(v.x, v.y);
        s_ah[r * 67 + c4i * 2 + 1] = f2h2(v.z, v.w);
    }
    const float* B = s_in_w + ((size_t)(li * ET_ + et) * 3 * H_ + nt * H_) * H_;
    const float* bi = s_in_b + (size_t)(li * ET_ + et) * 3 * H_ + nt * H_;
    int rg = tid >> 4, cg = tid & 15;
    int r0 = rg * 4;
    float4 alo[4], ahi[4];
    #pragma unroll
    for (int rr = 0; rr < 4; ++rr) { alo[rr] = f4zero(); ahi[rr] = f4zero(); }
    for (int kci = 0; kci < 4; ++kci) {
        __syncthreads();
        #pragma unroll
        for (int i = 0; i < 4; ++i) {
            int idx = i * 256 + tid;
            int jj = idx >> 3, k4 = (idx & 7) * 4;
            float4 w = *reinterpret_cast<const float4*>(&B[(size_t)jj * H_ + kci * 32 + k4]);
            int k2 = k4 >> 1;
            s_bh[k2 * 132 + jj]       = f2h2(w.x, w.y);
            s_bh[(k2 + 1) * 132 + jj] = f2h2(w.z, w.w);
        }
        __syncthreads();
        #pragma unroll
        for (int k2 = 0; k2 < 16; ++k2) {
            hh2 a2[4];
            #pragma unroll
            for (int rr = 0; rr < 4; ++rr) a2[rr] = s_ah[(r0 + rr) * 67 + kci * 16 + k2];
            U4H2 bl, bh_;
            bl.f  = *reinterpret_cast<const float4*>(&s_bh[k2 * 132 + cg * 4]);
            bh_.f = *reinterpret_cast<const float4*>(&s_bh[k2 * 132 + 64 + cg * 4]);
            #pragma unroll
            for (int rr = 0; rr < 4; ++rr) {
                alo[rr].x = FDOT2(a2[rr], bl.h[0], alo[rr].x);
                alo[rr].y = FDOT2(a2[rr], bl.h[1], alo[rr].y);
                alo[rr].z = FDOT2(a2[rr], bl.h[2], alo[rr].z);
                alo[rr].w = FDOT2(a2[rr], bl.h[3], alo[rr].w);
                ahi[rr].x = FDOT2(a2[rr], bh_.h[0], ahi[rr].x);
                ahi[rr].y = FDOT2(a2[rr], bh_.h[1], ahi[rr].y);
                ahi[rr].z = FDOT2(a2[rr], bh_.h[2], ahi[rr].z);
                ahi[rr].w = FDOT2(a2[rr], bh_.h[3], ahi[rr].w);
            }
        }
    }
    float4 blo = *reinterpret_cast<const float4*>(&bi[cg * 4]);
    float4 bhi = *reinterpret_cast<const float4*>(&bi[64 + cg * 4]);
    #pragma unroll
    for (int rr = 0; rr < 4; ++rr) {
        int row = r0 + rr;
        if (row < qcnt) {
            float4 lo = alo[rr], hi = ahi[rr];
            lo.x += blo.x; lo.y += blo.y; lo.z += blo.z; lo.w += blo.w;
            hi.x += bhi.x; hi.y += bhi.y; hi.z += bhi.z; hi.w += bhi.w;
            __half* base = (nt == 0) ? (qh + (size_t)(qbase + row) * 128)
                                     : (kvh + (size_t)(qbase + row) * 256 + (nt - 1) * 128);
            PK2 p0, p1;
            p0.h[0] = __floats2half2_rn(lo.x, lo.y);
            p0.h[1] = __floats2half2_rn(lo.z, lo.w);
            p1.h[0] = __floats2half2_rn(hi.x, hi.y);
            p1.h[1] = __floats2half2_rn(hi.z, hi.w);
            *reinterpret_cast<float2*>(base + cg * 4)      = p0.f2;
            *reinterpret_cast<float2*>(base + 64 + cg * 4) = p1.f2;
        }
    }
}

// ---------------- grouped spatial attention + out-proj + scatter ----------------

__global__ __launch_bounds__(256, 2) void k_gattn(
    const __half* __restrict__ qh, const __half* __restrict__ kvh, const int* __restrict__ sorted,
    const int* __restrict__ offs, const int* __restrict__ edge_index,
    const int2* __restrict__ desc, const int* __restrict__ ndesc,
    const float* __restrict__ s_out_w, const float* __restrict__ s_out_b,
    float* __restrict__ h_new, int li) {
    int bx = blockIdx.x;
    if (bx >= ndesc[0]) return;
    int2 dd = desc[bx];
    int g = dd.x, qs = dd.y;
    int start = offs[g], end = offs[g + 1];
    int qbase = start + qs;
    int qcnt = min(64, end - qbase);
    int et = g / NT_;

    __shared__ __half2 s_kh[32 * 64];
    __shared__ __half2 s_vh[32 * 64];
    __shared__ float  s_o[64 * 132];
    __shared__ int    s_dn[64];
    int tid = threadIdx.x;
    int head = tid >> 6, qi = tid & 63;

    if (tid < 64) s_dn[tid] = edge_index[E_ + sorted[qbase + min(tid, qcnt - 1)]];

    int p0 = qbase + min(qi, qcnt - 1);
    __half2 q2[16];
    {
        const float4* qr = reinterpret_cast<const float4*>(qh + (size_t)p0 * 128 + head * DH_);
        F4H t0, t1, t2, t3;
        t0.f = qr[0]; t1.f = qr[1]; t2.f = qr[2]; t3.f = qr[3];
        #pragma unroll
        for (int i = 0; i < 4; ++i) {
            q2[i] = t0.h[i]; q2[4 + i] = t1.h[i]; q2[8 + i] = t2.h[i]; q2[12 + i] = t3.h[i];
        }
    }
    float m = -1e30f, ssum = 0.0f;
    __half2 o2[16];
    #pragma unroll
    for (int i = 0; i < 16; ++i) o2[i] = __floats2half2_rn(0.f, 0.f);

    int nkt = (end - start + 31) >> 5;
    for (int kt = 0; kt < nkt; ++kt) {
        int kb = start + kt * 32;
        int kcnt = min(32, end - kb);
        __syncthreads();
        #pragma unroll
        for (int i = 0; i < 4; ++i) {
            int idx = i * 256 + tid;
            int row = idx >> 5, seg = idx & 31;
            if (row < kcnt) {
                float4 w = *reinterpret_cast<const float4*>(kvh + (size_t)(kb + row) * 256 + seg * 8);
                __half2* dp = (seg < 16) ? &s_kh[row * 64 + seg * 4] : &s_vh[row * 64 + (seg - 16) * 4];
                *reinterpret_cast<float4*>(dp) = w;
            }
        }
        __syncthreads();
        if (kcnt == 32) {
            float sc[32];
            float tmax = -1e30f;
            #pragma unroll
            for (int t2 = 0; t2 < 32; ++t2) {
                const float4* kr = reinterpret_cast<const float4*>(&s_kh[t2 * 64 + head * 16]);
                F4H k0, k1, k2, k3;
                k0.f = kr[0]; k1.f = kr[1]; k2.f = kr[2]; k3.f = kr[3];
                __half2 a0 = __hmul2(q2[0], k0.h[0]), a1 = __hmul2(q2[1], k0.h[1]),
                        a2 = __hmul2(q2[2], k0.h[2]), a3 = __hmul2(q2[3], k0.h[3]);
                a0 = __hfma2(q2[4], k1.h[0], a0); a1 = __hfma2(q2[5], k1.h[1], a1);
                a2 = __hfma2(q2[6], k1.h[2], a2); a3 = __hfma2(q2[7], k1.h[3], a3);
                a0 = __hfma2(q2[8], k2.h[0], a0); a1 = __hfma2(q2[9], k2.h[1], a1);
                a2 = __hfma2(q2[10], k2.h[2], a2); a3 = __hfma2(q2[11], k2.h[3], a3);
                a0 = __hfma2(q2[12], k3.h[0], a0); a1 = __hfma2(q2[13], k3.h[1], a1);
                a2 = __hfma2(q2[14], k3.h[2], a2); a3 = __hfma2(q2[15], k3.h[3], a3);
                __half2 sh = __hadd2(__hadd2(a0, a1), __hadd2(a2, a3));
                float dot = (__low2float(sh) + __high2float(sh)) * SCALE_;
                sc[t2] = dot;
                tmax = fmaxf(tmax, dot);
            }
            float mn = fmaxf(m, tmax);
            float f = __expf(m - mn);
            ssum *= f;
            __half2 f2 = __float2half2_rn(f);
            #pragma unroll
            for (int i = 0; i < 16; ++i) o2[i] = __hmul2(o2[i], f2);
            #pragma unroll
            for (int t2 = 0; t2 < 32; ++t2) {
                float p = __expf(sc[t2] - mn);
                ssum += p;
                __half2 p2 = __float2half2_rn(p);
                const float4* vr = reinterpret_cast<const float4*>(&s_vh[t2 * 64 + head * 16]);
                F4H v0, v1, v2, v3;
                v0.f = vr[0]; v1.f = vr[1]; v2.f = vr[2]; v3.f = vr[3];
                #pragma unroll
                for (int i = 0; i < 4; ++i) o2[i]      = __hfma2(p2, v0.h[i], o2[i]);
                #pragma unroll
                for (int i = 0; i < 4; ++i) o2[4 + i]  = __hfma2(p2, v1.h[i], o2[4 + i]);
                #pragma unroll
                for (int i = 0; i < 4; ++i) o2[8 + i]  = __hfma2(p2, v2.h[i], o2[8 + i]);
                #pragma unroll
                for (int i = 0; i < 4; ++i) o2[12 + i] = __hfma2(p2, v3.h[i], o2[12 + i]);
            }
            m = mn;
        } else {
            float tmax = -1e30f;
            for (int t2 = 0; t2 < kcnt; ++t2) {
                const float4* kr = reinterpret_cast<const float4*>(&s_kh[t2 * 64 + head * 16]);
                F4H k0, k1, k2, k3;
                k0.f = kr[0]; k1.f = kr[1]; k2.f = kr[2]; k3.f = kr[3];
                __half2 a0 = __hmul2(q2[0], k0.h[0]), a1 = __hmul2(q2[1], k0.h[1]),
                        a2 = __hmul2(q2[2], k0.h[2]), a3 = __hmul2(q2[3], k0.h[3]);
                a0 = __hfma2(q2[4], k1.h[0], a0); a1 = __hfma2(q2[5], k1.h[1], a1);
                a2 = __hfma2(q2[6], k1.h[2], a2); a3 = __hfma2(q2[7], k1.h[3], a3);
                a0 = __hfma2(q2[8], k2.h[0], a0); a1 = __hfma2(q2[9], k2.h[1], a1);
                a2 = __hfma2(q2[10], k2.h[2], a2); a3 = __hfma2(q2[11], k2.h[3], a3);
                a0 = __hfma2(q2[12], k3.h[0], a0); a1 = __hfma2(q2[13], k3.h[1], a1);
                a2 = __hfma2(q2[14], k3.h[2], a2); a3 = __hfma2(q2[15], k3.h[3], a3);
                __half2 sh = __hadd2(__hadd2(a0, a1), __hadd2(a2, a3));
                tmax = fmaxf(tmax, (__low2float(sh) + __high2float(sh)) * SCALE_);
            }
            float mn = fmaxf(m, tmax);
            float f = __expf(m - mn);
            ssum *= f;
            __half2 f2 = __float2half2_rn(f);
            #pragma unroll
            for (int i = 0; i < 16; ++i) o2[i] = __hmul2(o2[i], f2);
            for (int t2 = 0; t2 < kcnt; ++t2) {
                const float4* kr = reinterpret_cast<const float4*>(&s_kh[t2 * 64 + head * 16]);
                F4H k0, k1, k2, k3;
                k0.f = kr[0]; k1.f = kr[1]; k2.f = kr[2]; k3.f = kr[3];
                __half2 a0 = __hmul2(q2[0], k0.h[0]), a1 = __hmul2(q2[1], k0.h[1]),
                        a2 = __hmul2(q2[2], k0.h[2]), a3 = __hmul2(q2[3], k0.h[3]);
                a0 = __hfma2(q2[4], k1.h[0], a0); a1 = __hfma2(q2[5], k1.h[1], a1);
                a2 = __hfma2(q2[6], k1.h[2], a2); a3 = __hfma2(q2[7], k1.h[3], a3);
                a0 = __hfma2(q2[8], k2.h[0], a0); a1 = __hfma2(q2[9], k2.h[1], a1);
                a2 = __hfma2(q2[10], k2.h[2], a2); a3 = __hfma2(q2[11], k2.h[3], a3);
                a0 = __hfma2(q2[12], k3.h[0], a0); a1 = __hfma2(q2[13], k3.h[1], a1);
                a2 = __hfma2(q2[14], k3.h[2], a2); a3 = __hfma2(q2[15], k3.h[3], a3);
                __half2 sh = __hadd2(__hadd2(a0, a1), __hadd2(a2, a3));
                float p = __expf((__low2float(sh) + __high2float(sh)) * SCALE_ - mn);
                ssum += p;
                __half2 p2 = __float2half2_rn(p);
                const float4* vr = reinterpret_cast<const float4*>(&s_vh[t2 * 64 + head * 16]);
                F4H v0, v1, v2, v3;
                v0.f = vr[0]; v1.f = vr[1]; v2.f = vr[2]; v3.f = vr[3];
                #pragma unroll
                for (int i = 0; i < 4; ++i) o2[i]      = __hfma2(p2, v0.h[i], o2[i]);
                #pragma unroll
                for (int i = 0; i < 4; ++i) o2[4 + i]  = __hfma2(p2, v1.h[i], o2[4 + i]);
                #pragma unroll
                for (int i = 0; i < 4; ++i) o2[8 + i]  = __hfma2(p2, v2.h[i], o2[8 + i]);
                #pragma unroll
                for (int i = 0; i < 4; ++i) o2[12 + i] = __hfma2(p2, v3.h[i], o2[12 + i]);
            }
            m = mn;
        }
    }
    __syncthreads();
    if (qi < qcnt) {
        float inv = 1.0f / ssum;
        #pragma unroll
        for (int i = 0; i < 16; ++i) {
            float2 of = __half22float2(o2[i]);
            s_o[qi * 132 + head * DH_ + 2 * i]     = of.x * inv;
            s_o[qi * 132 + head * DH_ + 2 * i + 1] = of.y * inv;
        }
    }
    __syncthreads();
    {
        int j = tid & 127, half = tid >> 7;
        const float* Wo = s_out_w + ((size_t)(li * ET_ + et) * H_ + j) * H_;
        float bo = s_out_b[(size_t)(li * ET_ + et) * H_ + j];
        float acc[32];
        #pragma unroll
        for (int qq = 0; qq < 32; ++qq) acc[qq] = bo;
        #pragma unroll 8
        for (int k4 = 0; k4 < 32; ++k4) {
            float4 w = *reinterpret_cast<const float4*>(&Wo[k4 * 4]);
            #pragma unroll
            for (int qq = 0; qq < 32; ++qq) {
                float4 ov = *reinterpret_cast<const float4*>(&s_o[(half * 32 + qq) * 132 + k4 * 4]);
                acc[qq] += w.x * ov.x + w.y * ov.y + w.z * ov.z + w.w * ov.w;
            }
        }
        #pragma unroll
        for (int qq = 0; qq < 32; ++qq) {
            int qrow = half * 32 + qq;
            if (qrow < qcnt) {
                atomicAdd(&h_new[(size_t)s_dn[qrow] * H_ + j], acc[qq]);
            }
        }
    }
}

// ---------------- LN + exact GELU + residual (spatial); 4 nodes/block; re-zeroes h_new ----------------

__global__ __launch_bounds__(256) void k_lngelu(float* __restrict__ h_new, float* __restrict__ h,
                                                const float* __restrict__ ln_g, const float* __restrict__ ln_b, int li) {
    int n = blockIdx.x * 4 + (threadIdx.x >> 6);
    int l = threadIdx.x & 63;
    float v0 = h_new[(size_t)n * H_ + l];
    float v1 = h_new[(size_t)n * H_ + 64 + l];
    h_new[(size_t)n * H_ + l] = 0.0f;
    h_new[(size_t)n * H_ + 64 + l] = 0.0f;
    float s = v0 + v1;
    #pragma unroll
    for (int off = 32; off; off >>= 1) s += __shfl_xor(s, off);
    float mean = s * (1.0f / H_);
    float d0 = v0 - mean, d1 = v1 - mean;
    float vs = d0 * d0 + d1 * d1;
    #pragma unroll
    for (int off = 32; off; off >>= 1) vs += __shfl_xor(vs, off);
    float rstd = rsqrtf(vs * (1.0f / H_) + 1e-5f);
    const float* gg = ln_g + (size_t)li * H_;
    const float* bb = ln_b + (size_t)li * H_;
    float t0 = gelu_exact(d0 * rstd * gg[l] + bb[l]);
    float t1 = gelu_exact(d1 * rstd * gg[64 + l] + bb[64 + l]);
    size_t o = (size_t)n * H_;
    if (li == 0) { h[o + l] = t0; h[o + 64 + l] = t1; }
    else         { h[o + l] += t0; h[o + 64 + l] += t1; }
}

// ---------------- temporal: positional encoding add ----------------

__global__ void k_peadd(float* __restrict__ h) {
    int i = blockIdx.x * blockDim.x + threadIdx.x;
    int stride = gridDim.x * blockDim.x;
    for (; i < N_ * H_; i += stride) {
        int j = i & 127;
        int t = (i >> 7) & 63;
        float dv = __expf((float)(j & ~1) * (-0.0719557841560639f));
        float ang = (float)t * dv;
        float pe = (j & 1) ? cosf(ang) : sinf(ang);
        h[i] += pe;
    }
}

// ---------------- temporal qkv GEMM (fp16/fdot2) ----------------

__global__ __launch_bounds__(256) void k_tqkv(const float* __restrict__ hs,
                                              const float* __restrict__ t_in_w, const float* __restrict__ t_in_b,
                                              float* __restrict__ qc, float* __restrict__ kc, float* __restrict__ vc,
                                              int li, int c0) {
    int nb = blockIdx.x;
    int nt = blockIdx.y;
    int node = c0 + nb;
    __shared__ hh2 s_ah[64 * 67];
    __shared__ hh2 s_bh[16 * 132];
    int tid = threadIdx.x;
    #pragma unroll
    for (int i = 0; i < 8; ++i) {
        int idx = i * 256 + tid;
        int r = idx >> 5, c4i = idx & 31;
        float4 v = *reinterpret_cast<const float4*>(&hs[((size_t)node * 64 + r) * 128 + c4i * 4]);
        s_ah[r * 67 + c4i * 2]     = f2h2(v.x, v.y);
        s_ah[r * 67 + c4i * 2 + 1] = f2h2(v.z, v.w);
    }
    const float* B = t_in_w + ((size_t)li * 384 + nt * 128) * 128;
    const float* bi = t_in_b + (size_t)li * 384 + nt * 128;
    int rg = tid >> 4, cg = tid & 15;
    int r0 = rg * 4;
    float4 alo[4], ahi[4];
    #pragma unroll
    for (int rr = 0; rr < 4; ++rr) { alo[rr] = f4zero(); ahi[rr] = f4zero(); }
    for (int kci = 0; kci < 4; ++kci) {
        __syncthreads();
        #pragma unroll
        for (int i = 0; i < 4; ++i) {
            int idx = i * 256 + tid;
            int jj = idx >> 3, k4 = (idx & 7) * 4;
            float4 w = *reinterpret_cast<const float4*>(&B[(size_t)jj * 128 + kci * 32 + k4]);
            int k2 = k4 >> 1;
            s_bh[k2 * 132 + jj]       = f2h2(w.x, w.y);
            s_bh[(k2 + 1) * 132 + jj] = f2h2(w.z, w.w);
        }
        __syncthreads();
        #pragma unroll
        for (int k2 = 0; k2 < 16; ++k2) {
            hh2 a2[4];
            #pragma unroll
            for (int rr = 0; rr < 4; ++rr) a2[rr] = s_ah[(r0 + rr) * 67 + kci * 16 + k2];
            U4H2 bl, bh_;
            bl.f  = *reinterpret_cast<const float4*>(&s_bh[k2 * 132 + cg * 4]);
            bh_.f = *reinterpret_cast<const float4*>(&s_bh[k2 * 132 + 64 + cg * 4]);
            #pragma unroll
            for (int rr = 0; rr < 4; ++rr) {
                alo[rr].x = FDOT2(a2[rr], bl.h[0], alo[rr].x);
                alo[rr].y = FDOT2(a2[rr], bl.h[1], alo[rr].y);
                alo[rr].z = FDOT2(a2[rr], bl.h[2], alo[rr].z);
                alo[rr].w = FDOT2(a2[rr], bl.h[3], alo[rr].w);
                ahi[rr].x = FDOT2(a2[rr], bh_.h[0], ahi[rr].x);
                ahi[rr].y = FDOT2(a2[rr], bh_.h[1], ahi[rr].y);
                ahi[rr].z = FDOT2(a2[rr], bh_.h[2], ahi[rr].z);
                ahi[rr].w = FDOT2(a2[rr], bh_.h[3], ahi[rr].w);
            }
        }
    }
    float* dst = (nt == 0) ? qc : (nt == 1) ? kc : vc;
    float sc = (nt == 0) ? SCALE_ : 1.0f;
    float4 blo = *reinterpret_cast<const float4*>(&bi[cg * 4]);
    float4 bhi = *reinterpret_cast<const float4*>(&bi[64 + cg * 4]);
    #pragma unroll
    for (int rr = 0; rr < 4; ++rr) {
        float4 lo = alo[rr], hi = ahi[rr];
        lo.x = (lo.x + blo.x) * sc; lo.y = (lo.y + blo.y) * sc; lo.z = (lo.z + blo.z) * sc; lo.w = (lo.w + blo.w) * sc;
        hi.x = (hi.x + bhi.x) * sc; hi.y = (hi.y + bhi.y) * sc; hi.z = (hi.z + bhi.z) * sc; hi.w = (hi.w + bhi.w) * sc;
        size_t row = (size_t)nb * 64 + r0 + rr;
        *reinterpret_cast<float4*>(&dst[row * 128 + cg * 4]) = lo;
        *reinterpret_cast<float4*>(&dst[row * 128 + 64 + cg * 4]) = hi;
    }
}

// ---------------- temporal attention (fp32) ----------------

__global__ __launch_bounds__(64) void k_tattn(float* __restrict__ qc, const float* __restrict__ kc,
                                              const float* __restrict__ vc) {
    int nb = blockIdx.x, head = blockIdx.y;
    __shared__ float s_k[64 * 36];
    __shared__ float s_v[64 * 36];
    int t = threadIdx.x;
    #pragma unroll
    for (int i = 0; i < 8; ++i) {
        int idx = i * 64 + t;
        int row = idx >> 3, d4 = (idx & 7) * 4;
        *reinterpret_cast<float4*>(&s_k[row * 36 + d4]) =
            *reinterpret_cast<const float4*>(&kc[((size_t)nb * 64 + row) * 128 + head * DH_ + d4]);
        *reinterpret_cast<float4*>(&s_v[row * 36 + d4]) =
            *reinterpret_cast<const float4*>(&vc[((size_t)nb * 64 + row) * 128 + head * DH_ + d4]);
    }
    float4 q[8];
    {
        const float4* qr = reinterpret_cast<const float4*>(&qc[((size_t)nb * 64 + t) * 128 + head * DH_]);
        #pragma unroll
        for (int i = 0; i < 8; ++i) q[i] = qr[i];
    }
    __syncthreads();
    float m = -1e30f;
    for (int t2 = 0; t2 < 64; ++t2) {
        const float4* kr = reinterpret_cast<const float4*>(&s_k[t2 * 36]);
        float s0 = 0, s1 = 0, s2 = 0, s3 = 0;
        #pragma unroll
        for (int i = 0; i < 8; ++i) {
            float4 kk = kr[i];
            s0 += q[i].x * kk.x; s1 += q[i].y * kk.y; s2 += q[i].z * kk.z; s3 += q[i].w * kk.w;
        }
        m = fmaxf(m, (s0 + s1) + (s2 + s3));
    }
    float ssum = 0.0f;
    float4 o[8];
    #pragma unroll
    for (int i = 0; i < 8; ++i) o[i] = f4zero();
    for (int t2 = 0; t2 < 64; ++t2) {
        const float4* kr = reinterpret_cast<const float4*>(&s_k[t2 * 36]);
        float s0 = 0, s1 = 0, s2 = 0, s3 = 0;
        #pragma unroll
        for (int i = 0; i < 8; ++i) {
            float4 kk = kr[i];
            s0 += q[i].x * kk.x; s1 += q[i].y * kk.y; s2 += q[i].z * kk.z; s3 += q[i].w * kk.w;
        }
        float p = __expf((s0 + s1) + (s2 + s3) - m);
        ssum += p;
        const float4* vr = reinterpret_cast<const float4*>(&s_v[t2 * 36]);
        #pragma unroll
        for (int i = 0; i < 8; ++i) f4fma(o[i], p, vr[i]);
    }
    float inv = 1.0f / ssum;
    float4* orow = reinterpret_cast<float4*>(&qc[((size_t)nb * 64 + t) * 128 + head * DH_]);
    #pragma unroll
    for (int i = 0; i < 8; ++i) { float4 v = o[i]; f4scale(v, inv); orow[i] = v; }
}

// ---------------- temporal out-proj (fp16/fdot2) + residual + LN1 ----------------

__global__ __launch_bounds__(256) void k_toutln(const float* __restrict__ oc, float* __restrict__ hs,
                                                const float* __restrict__ t_out_w, const float* __restrict__ t_out_b,
                                                const float* __restrict__ ln_g, const float* __restrict__ ln_b,
                                                int li, int c0) {
    int nb = blockIdx.x;
    int node = c0 + nb;
    __shared__ hh2 s_ah[64 * 67];
    __shared__ hh2 s_bh[16 * 132];
    int tid = threadIdx.x;
    #pragma unroll
    for (int i = 0; i < 8; ++i) {
        int idx = i * 256 + tid;
        int r = idx >> 5, c4i = idx & 31;
        float4 v = *reinterpret_cast<const float4*>(&oc[((size_t)nb * 64 + r) * 128 + c4i * 4]);
        s_ah[r * 67 + c4i * 2]     = f2h2(v.x, v.y);
        s_ah[r * 67 + c4i * 2 + 1] = f2h2(v.z, v.w);
    }
    const float* B = t_out_w + (size_t)li * 128 * 128;
    const float* bo = t_out_b + (size_t)li * 128;
    int rg = tid >> 4, cg = tid & 15;
    int r0 = rg * 4;
    float4 alo[4], ahi[4];
    #pragma unroll
    for (int rr = 0; rr < 4; ++rr) { alo[rr] = f4zero(); ahi[rr] = f4zero(); }
    for (int kci = 0; kci < 4; ++kci) {
        __syncthreads();
        #pragma unroll
        for (int i = 0; i < 4; ++i) {
            int idx = i * 256 + tid;
            int jj = idx >> 3, k4 = (idx & 7) * 4;
            float4 w = *reinterpret_cast<const float4*>(&B[(size_t)jj * 128 + kci * 32 + k4]);
            int k2 = k4 >> 1;
            s_bh[k2 * 132 + jj]       = f2h2(w.x, w.y);
            s_bh[(k2 + 1) * 132 + jj] = f2h2(w.z, w.w);
        }
        __syncthreads();
        #pragma unroll
        for (int k2 = 0; k2 < 16; ++k2) {
            hh2 a2[4];
            #pragma unroll
            for (int rr = 0; rr < 4; ++rr) a2[rr] = s_ah[(r0 + rr) * 67 + kci * 16 + k2];
            U4H2 bl, bh_;
            bl.f  = *reinterpret_cast<const float4*>(&s_bh[k2 * 132 + cg * 4]);
            bh_.f = *reinterpret_cast<const float4*>(&s_bh[k2 * 132 + 64 + cg * 4]);
            #pragma unroll
            for (int rr = 0; rr < 4; ++rr) {
                alo[rr].x = FDOT2(a2[rr], bl.h[0], alo[rr].x);
                alo[rr].y = FDOT2(a2[rr], bl.h[1], alo[rr].y);
                alo[rr].z = FDOT2(a2[rr], bl.h[2], alo[rr].z);
                alo[rr].w = FDOT2(a2[rr], bl.h[3], alo[rr].w);
                ahi[rr].x = FDOT2(a2[rr], bh_.h[0], ahi[rr].x);
                ahi[rr].y = FDOT2(a2[rr], bh_.h[1], ahi[rr].y);
                ahi[rr].z = FDOT2(a2[rr], bh_.h[2], ahi[rr].z);
                ahi[rr].w = FDOT2(a2[rr], bh_.h[3], ahi[rr].w);
            }
        }
    }
    float4 bblo = *reinterpret_cast<const float4*>(&bo[cg * 4]);
    float4 bbhi = *reinterpret_cast<const float4*>(&bo[64 + cg * 4]);
    float4 glo = *reinterpret_cast<const float4*>(&ln_g[(size_t)li * 128 + cg * 4]);
    float4 ghi = *reinterpret_cast<const float4*>(&ln_g[(size_t)li * 128 + 64 + cg * 4]);
    float4 lblo = *reinterpret_cast<const float4*>(&ln_b[(size_t)li * 128 + cg * 4]);
    float4 lbhi = *reinterpret_cast<const float4*>(&ln_b[(size_t)li * 128 + 64 + cg * 4]);
    #pragma unroll
    for (int rr = 0; rr < 4; ++rr) {
        size_t row = (size_t)node * 64 + r0 + rr;
        float4 rlo = *reinterpret_cast<const float4*>(&hs[row * 128 + cg * 4]);
        float4 rhi = *reinterpret_cast<const float4*>(&hs[row * 128 + 64 + cg * 4]);
        float4 lo = alo[rr], hi = ahi[rr];
        lo.x += bblo.x + rlo.x; lo.y += bblo.y + rlo.y; lo.z += bblo.z + rlo.z; lo.w += bblo.w + rlo.w;
        hi.x += bbhi.x + rhi.x; hi.y += bbhi.y + rhi.y; hi.z += bbhi.z + rhi.z; hi.w += bbhi.w + rhi.w;
        float s = lo.x + lo.y + lo.z + lo.w + hi.x + hi.y + hi.z + hi.w;
        s += __shfl_xor(s, 1); s += __shfl_xor(s, 2); s += __shfl_xor(s, 4); s += __shfl_xor(s, 8);
        float mean = s * (1.0f / 128.0f);
        float4 dlo = make_float4(lo.x - mean, lo.y - mean, lo.z - mean, lo.w - mean);
        float4 dhi = make_float4(hi.x - mean, hi.y - mean, hi.z - mean, hi.w - mean);
        float vx = dlo.x * dlo.x + dlo.y * dlo.y + dlo.z * dlo.z + dlo.w * dlo.w +
                   dhi.x * dhi.x + dhi.y * dhi.y + dhi.z * dhi.z + dhi.w * dhi.w;
        vx += __shfl_xor(vx, 1); vx += __shfl_xor(vx, 2); vx += __shfl_xor(vx, 4); vx += __shfl_xor(vx, 8);
        float rstd = rsqrtf(vx * (1.0f / 128.0f) + 1e-5f);
        float4 olo = make_float4(dlo.x * rstd * glo.x + lblo.x, dlo.y * rstd * glo.y + lblo.y,
                                 dlo.z * rstd * glo.z + lblo.z, dlo.w * rstd * glo.w + lblo.w);
        float4 ohi = make_float4(dhi.x * rstd * ghi.x + lbhi.x, dhi.y * rstd * ghi.y + lbhi.y,
                                 dhi.z * rstd * ghi.z + lbhi.z, dhi.w * rstd * ghi.w + lbhi.w);
        *reinterpret_cast<float4*>(&hs[row * 128 + cg * 4]) = olo;
        *reinterpret_cast<float4*>(&hs[row * 128 + 64 + cg * 4]) = ohi;
    }
}

// ---------------- temporal fused FF via MFMA (f16 in, fp32 accum) + residual + LN2 ----------------
// block = 256 threads = 4 waves; wave w owns rows w*16..w*16+15 of the 64-row node tile.
// mfma_f32_16x16x32_f16 fragments: A row=lane&15, k=(lane>>4)*8+i; B col=lane&15, same k;
// D col=lane&15, row=(lane>>4)*4+reg (m89-verified mapping).

__global__ __launch_bounds__(256) void k_tff(float* __restrict__ hs,
                                             const float* __restrict__ t_w1, const float* __restrict__ t_b1,
                                             const float* __restrict__ t_w2, const float* __restrict__ t_b2,
                                             const float* __restrict__ ln_g, const float* __restrict__ ln_b,
                                             int li) {
    int node = blockIdx.x;
    __shared__ __half s_xh[64 * 136];    // X fp16 (input + residual source), row stride 136
    __shared__ __half s_wh[128 * 136];   // staged weight chunk fp16
    __shared__ __half s_fh[64 * 136];    // gelu(f1) chunk fp16
    int tid = threadIdx.x;
    int w = tid >> 6, l = tid & 63;
    int lr = l & 15, lk = l >> 4;

    // stage X: 64x128 fp32 -> fp16
    #pragma unroll
    for (int i = 0; i < 8; ++i) {
        int idx = i * 256 + tid;
        int r = idx >> 5, c4 = idx & 31;
        float4 v = *reinterpret_cast<const float4*>(&hs[((size_t)node * 64 + r) * 128 + c4 * 4]);
        __half2* dst = reinterpret_cast<__half2*>(&s_xh[r * 136 + c4 * 4]);
        dst[0] = __floats2half2_rn(v.x, v.y);
        dst[1] = __floats2half2_rn(v.z, v.w);
    }
    const float* W1 = t_w1 + (size_t)li * FF_ * 128;
    const float* b1 = t_b1 + (size_t)li * FF_;
    const float* W2 = t_w2 + (size_t)li * 128 * FF_;
    const float* b2 = t_b2 + (size_t)li * 128;

    f32x4 c2[8];
    #pragma unroll
    for (int ct = 0; ct < 8; ++ct) c2[ct] = (f32x4){0.f, 0.f, 0.f, 0.f};

    for (int nt = 0; nt < 4; ++nt) {
        __syncthreads();   // prev iteration's reads of s_wh/s_fh done; X staging visible (nt=0)
        // stage W1 chunk [128 ff-rows][128 k] fp32 -> fp16
        #pragma unroll
        for (int i = 0; i < 16; ++i) {
            int idx = i * 256 + tid;
            int r = idx >> 5, c4 = idx & 31;
            float4 v = *reinterpret_cast<const float4*>(&W1[(size_t)(nt * 128 + r) * 128 + c4 * 4]);
            __half2* dst = reinterpret_cast<__half2*>(&s_wh[r * 136 + c4 * 4]);
            dst[0] = __floats2half2_rn(v.x, v.y);
            dst[1] = __floats2half2_rn(v.z, v.w);
        }
        __syncthreads();
        // GEMM1: c1[64][128chunk] = X @ W1chunk^T
        f32x4 c1[8];
        #pragma unroll
        for (int ct = 0; ct < 8; ++ct) c1[ct] = (f32x4){0.f, 0.f, 0.f, 0.f};
        #pragma unroll
        for (int kk = 0; kk < 4; ++kk) {
            U4V8 a;
            a.f = *reinterpret_cast<const float4*>(&s_xh[(w * 16 + lr) * 136 + kk * 32 + lk * 8]);
            #pragma unroll
            for (int ct = 0; ct < 8; ++ct) {
                U4V8 b;
                b.f = *reinterpret_cast<const float4*>(&s_wh[(ct * 16 + lr) * 136 + kk * 32 + lk * 8]);
                c1[ct] = __builtin_amdgcn_mfma_f32_16x16x32_f16(a.v, b.v, c1[ct], 0, 0, 0);
            }
        }
        __syncthreads();   // all waves done reading s_wh (restage next) and s_xh stable
        // bias + gelu -> s_fh (each wave writes its own 16 rows)
        #pragma unroll
        for (int ct = 0; ct < 8; ++ct) {
            float bb = b1[nt * 128 + ct * 16 + lr];
            #pragma unroll
            for (int reg = 0; reg < 4; ++reg) {
                float gv = gelu_exact(c1[ct][reg] + bb);
                s_fh[(w * 16 + lk * 4 + reg) * 136 + ct * 16 + lr] = (__half)gv;
            }
        }
        // stage W2 chunk [128 j][128 k] fp32 -> fp16
        #pragma unroll
        for (int i = 0; i < 16; ++i) {
            int idx = i * 256 + tid;
            int r = idx >> 5, c4 = idx & 31;
            float4 v = *reinterpret_cast<const float4*>(&W2[(size_t)r * FF_ + nt * 128 + c4 * 4]);
            __half2* dst = reinterpret_cast<__half2*>(&s_wh[r * 136 + c4 * 4]);
            dst[0] = __floats2half2_rn(v.x, v.y);
            dst[1] = __floats2half2_rn(v.z, v.w);
        }
        __syncthreads();
        // GEMM2: c2 += gelu_chunk @ W2chunk^T (wave reads only its own s_fh rows)
        #pragma unroll
        for (int kk = 0; kk < 4; ++kk) {
            U4V8 a;
            a.f = *reinterpret_cast<const float4*>(&s_fh[(w * 16 + lr) * 136 + kk * 32 + lk * 8]);
            #pragma unroll
            for (int ct = 0; ct < 8; ++ct) {
                U4V8 b;
                b.f = *reinterpret_cast<const float4*>(&s_wh[(ct * 16 + lr) * 136 + kk * 32 + lk * 8]);
                c2[ct] = __builtin_amdgcn_mfma_f32_16x16x32_f16(a.v, b.v, c2[ct], 0, 0, 0);
            }
        }
    }
    // epilogue: bias + residual (fp16 X) + LN2 -> hs
    float gval[8], lbv[8], b2v[8];
    #pragma unroll
    for (int ct = 0; ct < 8; ++ct) {
        int col = ct * 16 + lr;
        gval[ct] = ln_g[(size_t)li * 128 + col];
        lbv[ct]  = ln_b[(size_t)li * 128 + col];
        b2v[ct]  = b2[col];
    }
    #pragma unroll
    for (int reg = 0; reg < 4; ++reg) {
        int row = w * 16 + lk * 4 + reg;
        float vals[8];
        float s = 0.0f;
        #pragma unroll
        for (int ct = 0; ct < 8; ++ct) {
            float v = c2[ct][reg] + b2v[ct] + (float)s_xh[row * 136 + ct * 16 + lr];
            vals[ct] = v;
            s += v;
        }
        s += __shfl_xor(s, 1); s += __shfl_xor(s, 2); s += __shfl_xor(s, 4); s += __shfl_xor(s, 8);
        float mean = s * (1.0f / 128.0f);
        float vv = 0.0f;
        #pragma unroll
        for (int ct = 0; ct < 8; ++ct) { float d = vals[ct] - mean; vv += d * d; }
        vv += __shfl_xor(vv, 1); vv += __shfl_xor(vv, 2); vv += __shfl_xor(vv, 4); vv += __shfl_xor(vv, 8);
        float rstd = rsqrtf(vv * (1.0f / 128.0f) + 1e-5f);
        #pragma unroll
        for (int ct = 0; ct < 8; ++ct) {
            int col = ct * 16 + lr;
            hs[((size_t)node * 64 + row) * 128 + col] = (vals[ct] - mean) * rstd * gval[ct] + lbv[ct];
        }
    }
}

// ---------------- final LN -> out ----------------

__global__ __launch_bounds__(256) void k_fln(const float* __restrict__ hs, float* __restrict__ out,
                                             const float* __restrict__ g, const float* __restrict__ b) {
    int row = blockIdx.x * 4 + (threadIdx.x >> 6);
    int l = threadIdx.x & 63;
    float v0 = hs[(size_t)row * H_ + l];
    float v1 = hs[(size_t)row * H_ + 64 + l];
    float s = v0 + v1;
    #pragma unroll
    for (int off = 32; off; off >>= 1) s += __shfl_xor(s, off);
    float mean = s * (1.0f / H_);
    float d0 = v0 - mean, d1 = v1 - mean;
    float vs = d0 * d0 + d1 * d1;
    #pragma unroll
    for (int off = 32; off; off >>= 1) vs += __shfl_xor(vs, off);
    float rstd = rsqrtf(vs * (1.0f / H_) + 1e-5f);
    out[(size_t)row * H_ + l] = d0 * rstd * g[l] + b[l];
    out[(size_t)row * H_ + 64 + l] = d1 * rstd * g[64 + l] + b[64 + l];
}

// ---------------- launch ----------------

extern "C" void kernel_launch(void* const* d_in, const int* in_sizes, int n_in,
                              void* d_out, int out_size, void* d_ws, size_t ws_size,
                              hipStream_t stream) {
    const float* x          = (const float*)d_in[0];
    const int*   edge_index = (const int*)d_in[1];
    const int*   edge_type  = (const int*)d_in[2];
    const int*   node_type  = (const int*)d_in[3];
    const float* W_in    = (const float*)d_in[6];
    const float* b_in    = (const float*)d_in[7];
    const float* s_in_w  = (const float*)d_in[8];
    const float* s_in_b  = (const float*)d_in[9];
    const float* s_out_w = (const float*)d_in[10];
    const float* s_out_b = (const float*)d_in[11];
    const float* ln_s_g  = (const float*)d_in[12];
    const float* ln_s_b  = (const float*)d_in[13];
    const float* t_in_w  = (const float*)d_in[14];
    const float* t_in_b  = (const float*)d_in[15];
    const float* t_out_w = (const float*)d_in[16];
    const float* t_out_b = (const float*)d_in[17];
    const float* t_ln1_g = (const float*)d_in[18];
    const float* t_ln1_b = (const float*)d_in[19];
    const float* t_w1    = (const float*)d_in[20];
    const float* t_b1    = (const float*)d_in[21];
    const float* t_w2    = (const float*)d_in[22];
    const float* t_b2    = (const float*)d_in[23];
    const float* t_ln2_g = (const float*)d_in[24];
    const float* t_ln2_b = (const float*)d_in[25];
    const float* fin_g   = (const float*)d_in[26];
    const float* fin_b   = (const float*)d_in[27];
    float* out = (float*)d_out;

    // workspace layout (floats)
    float* h     = (float*)d_ws;                       // N*H = 8388608
    float* h_new = h + (size_t)N_ * H_;                // 8388608
    float* spat  = h_new + (size_t)N_ * H_;            // 11520000 float region
    __half* qh   = (__half*)spat;                      // E*128 halves
    __half* kvh  = (__half*)spat + (size_t)E_ * 128;   // E*256 halves
    int* sorted  = (int*)(spat + (size_t)E_ * 384);    // E
    int* gpos    = sorted + E_;                        // E
    int* gedge   = gpos + E_;                          // E
    int* cnt     = gedge + E_;                         // 64
    int* offs    = cnt + 64;                           // 64
    int* curs    = offs + 64;                          // 64
    int* nd64    = curs + 64;                          // 16
    int2* desc64 = (int2*)(nd64 + 16);                 // 544 int2

    // temporal chunk buffers (alias spat region + h_new, used after spatial completes)
    float* qc = spat;                                  // CH*64*128 = 4194304
    float* kc = spat + (size_t)CH_ * 64 * 128;         // 4194304
    float* vc = h_new;                                 // 4194304

    k_zero_cnt<<<1, 64, 0, stream>>>(cnt);
    k_hist<<<(E_ + 255) / 256, 256, 0, stream>>>(edge_index, edge_type, node_type, gedge, cnt);
    k_scan<<<1, 1, 0, stream>>>(cnt, offs, curs);
    k_scatter<<<(E_ + 255) / 256, 256, 0, stream>>>(gedge, curs, sorted, gpos);
    k_desc<<<1, 1, 0, stream>>>(offs, desc64, nd64);

    k_inproj<<<N_, 128, 0, stream>>>(x, node_type, W_in, b_in, h);

    k_zero<<<2048, 256, 0, stream>>>(h_new, N_ * H_);   // layer 0; later layers zeroed by k_lngelu
    for (int li = 0; li < L_; ++li) {
        k_sqkv_gemm<<<dim3(GATTN_GRID, 3), 256, 0, stream>>>(h, s_in_w, s_in_b, sorted, offs, edge_index,
                                                             desc64, nd64, qh, kvh, li);
        k_gattn<<<GATTN_GRID, 256, 0, stream>>>(qh, kvh, sorted, offs, edge_index, desc64, nd64,
                                                s_out_w, s_out_b, h_new, li);
        k_lngelu<<<N_ / 4, 256, 0, stream>>>(h_new, h, ln_s_g, ln_s_b, li);
    }

    // temporal: hs = h + PE (in place)
    k_peadd<<<2048, 256, 0, stream>>>(h);
    for (int li = 0; li < TL_; ++li) {
        for (int c = 0; c < NB_ / CH_; ++c) {
            int c0 = c * CH_;
            k_tqkv<<<dim3(CH_, 3), 256, 0, stream>>>(h, t_in_w, t_in_b, qc, kc, vc, li, c0);
            k_tattn<<<dim3(CH_, NH_), 64, 0, stream>>>(qc, kc, vc);
            k_toutln<<<CH_, 256, 0, stream>>>(qc, h, t_out_w, t_out_b, t_ln1_g, t_ln1_b, li, c0);
        }
        k_tff<<<NB_, 256, 0, stream>>>(h, t_w1, t_b1, t_w2, t_b2, t_ln2_g, t_ln2_b, li);
    }
    k_fln<<<N_ / 4, 256, 0, stream>>>(h, out, fin_g, fin_b);
}

// Round 14
// 1437.252 us; speedup vs baseline: 1.6716x; 1.0481x over previous
//
#include <hip/hip_runtime.h>
#include <hip/hip_bf16.h>
#include <hip/hip_fp16.h>
#include <math.h>

// Problem constants (fixed by reference)
#define N_   65536
#define F_   64
#define H_   128
#define E_   30000
#define NT_  5
#define ET_  10
#define NG_  50
#define L_   3
#define TL_  2
#define NH_  4
#define DH_  32
#define NB_  1024
#define TT_  64
#define FF_  512
#define CH_  512         // temporal node chunk
#define GATTN_GRID 544

#define SCALE_ 0.17677669529663687f   // 1/sqrt(32)

typedef _Float16 hh2 __attribute__((ext_vector_type(2)));
typedef _Float16 f16x8 __attribute__((ext_vector_type(8)));
typedef float f32x4 __attribute__((ext_vector_type(4)));

__device__ __forceinline__ float gelu_exact(float x) {
    return 0.5f * x * (1.0f + erff(x * 0.70710678118654752f));
}
__device__ __forceinline__ void f4fma(float4& a, float s, const float4& b) {
    a.x += s * b.x; a.y += s * b.y; a.z += s * b.z; a.w += s * b.w;
}
__device__ __forceinline__ void f4scale(float4& a, float s) {
    a.x *= s; a.y *= s; a.z *= s; a.w *= s;
}
__device__ __forceinline__ float4 f4zero() { return make_float4(0.f, 0.f, 0.f, 0.f); }
__device__ __forceinline__ hh2 f2h2(float a, float b) {
    hh2 r; r[0] = (_Float16)a; r[1] = (_Float16)b; return r;
}
#define FDOT2(a, b, c) __builtin_amdgcn_fdot2((a), (b), (c), false)

union F4H { float4 f; __half2 h[4]; };   // float4 = 4 half2
union U4H2 { float4 f; hh2 h[4]; };
union PK2 { float2 f2; __half2 h[2]; };  // 8-byte fp16 store helper
union U4V8 { float4 f; f16x8 v; };       // 16B LDS read as 8 fp16 (MFMA fragment)

// ---------------- grouping ----------------

__global__ void k_zero_cnt(int* cnt) {
    if (threadIdx.x < NG_) cnt[threadIdx.x] = 0;
}

__global__ void k_hist(const int* __restrict__ edge_index, const int* __restrict__ edge_type,
                       const int* __restrict__ node_type, int* __restrict__ gedge, int* __restrict__ cnt) {
    int e = blockIdx.x * blockDim.x + threadIdx.x;
    if (e >= E_) return;
    int dn = edge_index[E_ + e];
    int g = edge_type[e] * NT_ + node_type[dn];
    gedge[e] = g;
    atomicAdd(&cnt[g], 1);
}

__global__ void k_scan(const int* __restrict__ cnt, int* __restrict__ offs, int* __restrict__ curs) {
    if (threadIdx.x == 0 && blockIdx.x == 0) {
        int acc = 0;
        for (int g = 0; g < NG_; ++g) { offs[g] = acc; curs[g] = acc; acc += cnt[g]; }
        offs[NG_] = acc;
    }
}

__global__ void k_scatter(const int* __restrict__ gedge, int* __restrict__ curs,
                          int* __restrict__ sorted, int* __restrict__ gpos) {
    int e = blockIdx.x * blockDim.x + threadIdx.x;
    if (e >= E_) return;
    int g = gedge[e];
    int pos = atomicAdd(&curs[g], 1);
    sorted[pos] = e;
    gpos[pos] = g;
}

__global__ void k_desc(const int* __restrict__ offs, int2* __restrict__ desc64, int* __restrict__ nd64) {
    if (threadIdx.x || blockIdx.x) return;
    int n64 = 0;
    for (int g = 0; g < NG_; ++g) {
        int sz = offs[g + 1] - offs[g];
        for (int qs = 0; qs < sz; qs += 64) desc64[n64++] = make_int2(g, qs);
    }
    nd64[0] = n64;
}

// ---------------- input projection ----------------

__global__ void k_inproj(const float* __restrict__ x, const int* __restrict__ node_type,
                         const float* __restrict__ W_in, const float* __restrict__ b_in,
                         float* __restrict__ h) {
    int n = blockIdx.x;
    int j = threadIdx.x;  // 0..127
    __shared__ float sx[F_];
    if (j < F_) sx[j] = x[(size_t)n * F_ + j];
    __syncthreads();
    int nt = node_type[n];
    const float* W = W_in + (size_t)nt * F_ * H_;
    float acc = b_in[(size_t)nt * H_ + j];
    #pragma unroll 8
    for (int f = 0; f < F_; ++f) acc += sx[f] * W[(size_t)f * H_ + j];
    h[(size_t)n * H_ + j] = acc;
}

__global__ void k_zero(float* __restrict__ p, int n) {
    int i = blockIdx.x * blockDim.x + threadIdx.x;
    int stride = gridDim.x * blockDim.x;
    for (; i < n; i += stride) p[i] = 0.0f;
}

// ---------------- spatial qkv projection: fp16/fdot2 tiled GEMM over 64-edge tiles ----------------

__global__ __launch_bounds__(256) void k_sqkv_gemm(
    const float* __restrict__ h, const float* __restrict__ s_in_w, const float* __restrict__ s_in_b,
    const int* __restrict__ sorted, const int* __restrict__ offs, const int* __restrict__ edge_index,
    const int2* __restrict__ desc64, const int* __restrict__ nd64,
    __half* __restrict__ qh, __half* __restrict__ kvh, int li) {
    int bx = blockIdx.x;
    if (bx >= nd64[0]) return;
    int2 dd = desc64[bx];
    int g = dd.x, qs = dd.y;
    int qbase = offs[g] + qs;
    int qcnt = min(64, offs[g + 1] - qbase);
    int et = g / NT_;
    int nt = blockIdx.y;
    __shared__ hh2 s_ah[64 * 67];
    __shared__ hh2 s_bh[16 * 132];
    int tid = threadIdx.x;
    #pragma unroll
    for (int i = 0; i < 8; ++i) {
        int idx = i * 256 + tid;
        int r = idx >> 5, c4i = idx & 31;
        int p = qbase + min(r, qcnt - 1);
        int e = sorted[p];
        int node = (nt == 0) ? edge_index[E_ + e] : edge_index[e];
        float4 v = *reinterpret_cast<const float4*>(&h[(size_t)node * H_ + c4i * 4]);
        s_ah[r * 67 + c4i * 2]     = f2h2(v.x, v.y);
        s_ah[r * 67 + c4i * 2 + 1] = f2h2(v.z, v.w);
    }
    const float* B = s_in_w + ((size_t)(li * ET_ + et) * 3 * H_ + nt * H_) * H_;
    const float* bi = s_in_b + (size_t)(li * ET_ + et) * 3 * H_ + nt * H_;
    int rg = tid >> 4, cg = tid & 15;
    int r0 = rg * 4;
    float4 alo[4], ahi[4];
    #pragma unroll
    for (int rr = 0; rr < 4; ++rr) { alo[rr] = f4zero(); ahi[rr] = f4zero(); }
    for (int kci = 0; kci < 4; ++kci) {
        __syncthreads();
        #pragma unroll
        for (int i = 0; i < 4; ++i) {
            int idx = i * 256 + tid;
            int jj = idx >> 3, k4 = (idx & 7) * 4;
            float4 w = *reinterpret_cast<const float4*>(&B[(size_t)jj * H_ + kci * 32 + k4]);
            int k2 = k4 >> 1;
            s_bh[k2 * 132 + jj]       = f2h2(w.x, w.y);
            s_bh[(k2 + 1) * 132 + jj] = f2h2(w.z, w.w);
        }
        __syncthreads();
        #pragma unroll
        for (int k2 = 0; k2 < 16; ++k2) {
            hh2 a2[4];
            #pragma unroll
            for (int rr = 0; rr < 4; ++rr) a2[rr] = s_ah[(r0 + rr) * 67 + kci * 16 + k2];
            U4H2 bl, bh_;
            bl.f  = *reinterpret_cast<const float4*>(&s_bh[k2 * 132 + cg * 4]);
            bh_.f = *reinterpret_cast<const float4*>(&s_bh[k2 * 132 + 64 + cg * 4]);
            #pragma unroll
            for (int rr = 0; rr < 4; ++rr) {
                alo[rr].x = FDOT2(a2[rr], bl.h[0], alo[rr].x);
                alo[rr].y = FDOT2(a2[rr], bl.h[1], alo[rr].y);
                alo[rr].z = FDOT2(a2[rr], bl.h[2], alo[rr].z);
                alo[rr].w = FDOT2(a2[rr], bl.h[3], alo[rr].w);
                ahi[rr].x = FDOT2(a2[rr], bh_.h[0], ahi[rr].x);
                ahi[rr].y = FDOT2(a2[rr], bh_.h[1], ahi[rr].y);
                ahi[rr].z = FDOT2(a2[rr], bh_.h[2], ahi[rr].z);
                ahi[rr].w = FDOT2(a2[rr], bh_.h[3], ahi[rr].w);
            }
        }
    }
    float4 blo = *reinterpret_cast<const float4*>(&bi[cg * 4]);
    float4 bhi = *reinterpret_cast<const float4*>(&bi[64 + cg * 4]);
    #pragma unroll
    for (int rr = 0; rr < 4; ++rr) {
        int row = r0 + rr;
        if (row < qcnt) {
            float4 lo = alo[rr], hi = ahi[rr];
            lo.x += blo.x; lo.y += blo.y; lo.z += blo.z; lo.w += blo.w;
            hi.x += bhi.x; hi.y += bhi.y; hi.z += bhi.z; hi.w += bhi.w;
            __half* base = (nt == 0) ? (qh + (size_t)(qbase + row) * 128)
                                     : (kvh + (size_t)(qbase + row) * 256 + (nt - 1) * 128);
            PK2 p0, p1;
            p0.h[0] = __floats2half2_rn(lo.x, lo.y);
            p0.h[1] = __floats2half2_rn(lo.z, lo.w);
            p1.h[0] = __floats2half2_rn(hi.x, hi.y);
            p1.h[1] = __floats2half2_rn(hi.z, hi.w);
            *reinterpret_cast<float2*>(base + cg * 4)      = p0.f2;
            *reinterpret_cast<float2*>(base + 64 + cg * 4) = p1.f2;
        }
    }
}

// ---------------- grouped spatial attention + MFMA out-proj + scatter ----------------
// Attention: fp16 hfma2 (unchanged). Out-projection: mfma_f32_16x16x32_f16 on fp16 s_oh @ Wo^T,
// with Wo staged fp16 into the (dead) K/V LDS region.

__global__ __launch_bounds__(256, 2) void k_gattn(
    const __half* __restrict__ qh, const __half* __restrict__ kvh, const int* __restrict__ sorted,
    const int* __restrict__ offs, const int* __restrict__ edge_index,
    const int2* __restrict__ desc, const int* __restrict__ ndesc,
    const float* __restrict__ s_out_w, const float* __restrict__ s_out_b,
    float* __restrict__ h_new, int li) {
    int bx = blockIdx.x;
    if (bx >= ndesc[0]) return;
    int2 dd = desc[bx];
    int g = dd.x, qs = dd.y;
    int start = offs[g], end = offs[g + 1];
    int qbase = start + qs;
    int qcnt = min(64, end - qbase);
    int et = g / NT_;

    __shared__ __align__(16) __half s_mem[128 * 136];   // attn: K/V (16KB of it); out-proj: Wo fp16 [128][136]
    __shared__ __align__(16) __half s_oh[64 * 136];     // attention output fp16
    __shared__ int s_dn[64];
    __half2* s_kh = reinterpret_cast<__half2*>(s_mem);          // [32][64] half2 (8 KB)
    __half2* s_vh = reinterpret_cast<__half2*>(s_mem) + 2048;   // [32][64] half2 (8 KB)
    __half*  s_wh = s_mem;                                      // [128][136] half (out-proj phase)

    int tid = threadIdx.x;
    int head = tid >> 6, qi = tid & 63;

    if (tid < 64) s_dn[tid] = edge_index[E_ + sorted[qbase + min(tid, qcnt - 1)]];

    int p0 = qbase + min(qi, qcnt - 1);
    __half2 q2[16];
    {
        const float4* qr = reinterpret_cast<const float4*>(qh + (size_t)p0 * 128 + head * DH_);
        F4H t0, t1, t2, t3;
        t0.f = qr[0]; t1.f = qr[1]; t2.f = qr[2]; t3.f = qr[3];
        #pragma unroll
        for (int i = 0; i < 4; ++i) {
            q2[i] = t0.h[i]; q2[4 + i] = t1.h[i]; q2[8 + i] = t2.h[i]; q2[12 + i] = t3.h[i];
        }
    }
    float m = -1e30f, ssum = 0.0f;
    __half2 o2[16];
    #pragma unroll
    for (int i = 0; i < 16; ++i) o2[i] = __floats2half2_rn(0.f, 0.f);

    int nkt = (end - start + 31) >> 5;
    for (int kt = 0; kt < nkt; ++kt) {
        int kb = start + kt * 32;
        int kcnt = min(32, end - kb);
        __syncthreads();
        #pragma unroll
        for (int i = 0; i < 4; ++i) {
            int idx = i * 256 + tid;
            int row = idx >> 5, seg = idx & 31;
            if (row < kcnt) {
                float4 w = *reinterpret_cast<const float4*>(kvh + (size_t)(kb + row) * 256 + seg * 8);
                __half2* dp = (seg < 16) ? &s_kh[row * 64 + seg * 4] : &s_vh[row * 64 + (seg - 16) * 4];
                *reinterpret_cast<float4*>(dp) = w;
            }
        }
        __syncthreads();
        if (kcnt == 32) {
            float sc[32];
            float tmax = -1e30f;
            #pragma unroll
            for (int t2 = 0; t2 < 32; ++t2) {
                const float4* kr = reinterpret_cast<const float4*>(&s_kh[t2 * 64 + head * 16]);
                F4H k0, k1, k2, k3;
                k0.f = kr[0]; k1.f = kr[1]; k2.f = kr[2]; k3.f = kr[3];
                __half2 a0 = __hmul2(q2[0], k0.h[0]), a1 = __hmul2(q2[1], k0.h[1]),
                        a2 = __hmul2(q2[2], k0.h[2]), a3 = __hmul2(q2[3], k0.h[3]);
                a0 = __hfma2(q2[4], k1.h[0], a0); a1 = __hfma2(q2[5], k1.h[1], a1);
                a2 = __hfma2(q2[6], k1.h[2], a2); a3 = __hfma2(q2[7], k1.h[3], a3);
                a0 = __hfma2(q2[8], k2.h[0], a0); a1 = __hfma2(q2[9], k2.h[1], a1);
                a2 = __hfma2(q2[10], k2.h[2], a2); a3 = __hfma2(q2[11], k2.h[3], a3);
                a0 = __hfma2(q2[12], k3.h[0], a0); a1 = __hfma2(q2[13], k3.h[1], a1);
                a2 = __hfma2(q2[14], k3.h[2], a2); a3 = __hfma2(q2[15], k3.h[3], a3);
                __half2 sh = __hadd2(__hadd2(a0, a1), __hadd2(a2, a3));
                float dot = (__low2float(sh) + __high2float(sh)) * SCALE_;
                sc[t2] = dot;
                tmax = fmaxf(tmax, dot);
            }
            float mn = fmaxf(m, tmax);
            float f = __expf(m - mn);
            ssum *= f;
            __half2 f2 = __float2half2_rn(f);
            #pragma unroll
            for (int i = 0; i < 16; ++i) o2[i] = __hmul2(o2[i], f2);
            #pragma unroll
            for (int t2 = 0; t2 < 32; ++t2) {
                float p = __expf(sc[t2] - mn);
                ssum += p;
                __half2 p2 = __float2half2_rn(p);
                const float4* vr = reinterpret_cast<const float4*>(&s_vh[t2 * 64 + head * 16]);
                F4H v0, v1, v2, v3;
                v0.f = vr[0]; v1.f = vr[1]; v2.f = vr[2]; v3.f = vr[3];
                #pragma unroll
                for (int i = 0; i < 4; ++i) o2[i]      = __hfma2(p2, v0.h[i], o2[i]);
                #pragma unroll
                for (int i = 0; i < 4; ++i) o2[4 + i]  = __hfma2(p2, v1.h[i], o2[4 + i]);
                #pragma unroll
                for (int i = 0; i < 4; ++i) o2[8 + i]  = __hfma2(p2, v2.h[i], o2[8 + i]);
                #pragma unroll
                for (int i = 0; i < 4; ++i) o2[12 + i] = __hfma2(p2, v3.h[i], o2[12 + i]);
            }
            m = mn;
        } else {
            float tmax = -1e30f;
            for (int t2 = 0; t2 < kcnt; ++t2) {
                const float4* kr = reinterpret_cast<const float4*>(&s_kh[t2 * 64 + head * 16]);
                F4H k0, k1, k2, k3;
                k0.f = kr[0]; k1.f = kr[1]; k2.f = kr[2]; k3.f = kr[3];
                __half2 a0 = __hmul2(q2[0], k0.h[0]), a1 = __hmul2(q2[1], k0.h[1]),
                        a2 = __hmul2(q2[2], k0.h[2]), a3 = __hmul2(q2[3], k0.h[3]);
                a0 = __hfma2(q2[4], k1.h[0], a0); a1 = __hfma2(q2[5], k1.h[1], a1);
                a2 = __hfma2(q2[6], k1.h[2], a2); a3 = __hfma2(q2[7], k1.h[3], a3);
                a0 = __hfma2(q2[8], k2.h[0], a0); a1 = __hfma2(q2[9], k2.h[1], a1);
                a2 = __hfma2(q2[10], k2.h[2], a2); a3 = __hfma2(q2[11], k2.h[3], a3);
                a0 = __hfma2(q2[12], k3.h[0], a0); a1 = __hfma2(q2[13], k3.h[1], a1);
                a2 = __hfma2(q2[14], k3.h[2], a2); a3 = __hfma2(q2[15], k3.h[3], a3);
                __half2 sh = __hadd2(__hadd2(a0, a1), __hadd2(a2, a3));
                tmax = fmaxf(tmax, (__low2float(sh) + __high2float(sh)) * SCALE_);
            }
            float mn = fmaxf(m, tmax);
            float f = __expf(m - mn);
            ssum *= f;
            __half2 f2 = __float2half2_rn(f);
            #pragma unroll
            for (int i = 0; i < 16; ++i) o2[i] = __hmul2(o2[i], f2);
            for (int t2 = 0; t2 < kcnt; ++t2) {
                const float4* kr = reinterpret_cast<const float4*>(&s_kh[t2 * 64 + head * 16]);
                F4H k0, k1, k2, k3;
                k0.f = kr[0]; k1.f = kr[1]; k2.f = kr[2]; k3.f = kr[3];
                __half2 a0 = __hmul2(q2[0], k0.h[0]), a1 = __hmul2(q2[1], k0.h[1]),
                        a2 = __hmul2(q2[2], k0.h[2]), a3 = __hmul2(q2[3], k0.h[3]);
                a0 = __hfma2(q2[4], k1.h[0], a0); a1 = __hfma2(q2[5], k1.h[1], a1);
                a2 = __hfma2(q2[6], k1.h[2], a2); a3 = __hfma2(q2[7], k1.h[3], a3);
                a0 = __hfma2(q2[8], k2.h[0], a0); a1 = __hfma2(q2[9], k2.h[1], a1);
                a2 = __hfma2(q2[10], k2.h[2], a2); a3 = __hfma2(q2[11], k2.h[3], a3);
                a0 = __hfma2(q2[12], k3.h[0], a0); a1 = __hfma2(q2[13], k3.h[1], a1);
                a2 = __hfma2(q2[14], k3.h[2], a2); a3 = __hfma2(q2[15], k3.h[3], a3);
                __half2 sh = __hadd2(__hadd2(a0, a1), __hadd2(a2, a3));
                float p = __expf((__low2float(sh) + __high2float(sh)) * SCALE_ - mn);
                ssum += p;
                __half2 p2 = __float2half2_rn(p);
                const float4* vr = reinterpret_cast<const float4*>(&s_vh[t2 * 64 + head * 16]);
                F4H v0, v1, v2, v3;
                v0.f = vr[0]; v1.f = vr[1]; v2.f = vr[2]; v3.f = vr[3];
                #pragma unroll
                for (int i = 0; i < 4; ++i) o2[i]      = __hfma2(p2, v0.h[i], o2[i]);
                #pragma unroll
                for (int i = 0; i < 4; ++i) o2[4 + i]  = __hfma2(p2, v1.h[i], o2[4 + i]);
                #pragma unroll
                for (int i = 0; i < 4; ++i) o2[8 + i]  = __hfma2(p2, v2.h[i], o2[8 + i]);
                #pragma unroll
                for (int i = 0; i < 4; ++i) o2[12 + i] = __hfma2(p2, v3.h[i], o2[12 + i]);
            }
            m = mn;
        }
    }
    __syncthreads();   // all K/V reads done; K/V region reusable for Wo
    // publish normalized attention output as fp16 (all 64 rows; rows >= qcnt masked at scatter)
    {
        float inv = 1.0f / ssum;
        #pragma unroll
        for (int i = 0; i < 16; ++i) {
            float2 of = __half22float2(o2[i]);
            *reinterpret_cast<__half2*>(&s_oh[qi * 136 + head * DH_ + 2 * i]) =
                __floats2half2_rn(of.x * inv, of.y * inv);
        }
    }
    // stage Wo fp16 into s_wh (aliases K/V region)
    {
        const float* Wo = s_out_w + (size_t)(li * ET_ + et) * H_ * H_;
        #pragma unroll
        for (int i = 0; i < 16; ++i) {
            int idx = i * 256 + tid;
            int r = idx >> 5, c4 = idx & 31;
            float4 v = *reinterpret_cast<const float4*>(&Wo[(size_t)r * H_ + c4 * 4]);
            __half2* dst = reinterpret_cast<__half2*>(&s_wh[r * 136 + c4 * 4]);
            dst[0] = __floats2half2_rn(v.x, v.y);
            dst[1] = __floats2half2_rn(v.z, v.w);
        }
    }
    __syncthreads();
    // MFMA out-projection: out[64 q][128 col] = s_oh @ Wo^T
    {
        int wv = head;            // wave id; wave owns q-rows wv*16..wv*16+15
        int lr = qi & 15, lk = qi >> 4;
        f32x4 c[8];
        #pragma unroll
        for (int ct = 0; ct < 8; ++ct) c[ct] = (f32x4){0.f, 0.f, 0.f, 0.f};
        #pragma unroll
        for (int kk = 0; kk < 4; ++kk) {
            U4V8 a;
            a.f = *reinterpret_cast<const float4*>(&s_oh[(wv * 16 + lr) * 136 + kk * 32 + lk * 8]);
            #pragma unroll
            for (int ct = 0; ct < 8; ++ct) {
                U4V8 b;
                b.f = *reinterpret_cast<const float4*>(&s_wh[(ct * 16 + lr) * 136 + kk * 32 + lk * 8]);
                c[ct] = __builtin_amdgcn_mfma_f32_16x16x32_f16(a.v, b.v, c[ct], 0, 0, 0);
            }
        }
        const float* bo = s_out_b + (size_t)(li * ET_ + et) * H_;
        #pragma unroll
        for (int ct = 0; ct < 8; ++ct) {
            int col = ct * 16 + lr;
            float bb = bo[col];
            #pragma unroll
            for (int reg = 0; reg < 4; ++reg) {
                int qrow = wv * 16 + lk * 4 + reg;
                if (qrow < qcnt) {
                    atomicAdd(&h_new[(size_t)s_dn[qrow] * H_ + col], c[ct][reg] + bb);
                }
            }
        }
    }
}

// ---------------- LN + exact GELU + residual (spatial); 4 nodes/block; re-zeroes h_new ----------------

__global__ __launch_bounds__(256) void k_lngelu(float* __restrict__ h_new, float* __restrict__ h,
                                                const float* __restrict__ ln_g, const float* __restrict__ ln_b, int li) {
    int n = blockIdx.x * 4 + (threadIdx.x >> 6);
    int l = threadIdx.x & 63;
    float v0 = h_new[(size_t)n * H_ + l];
    float v1 = h_new[(size_t)n * H_ + 64 + l];
    h_new[(size_t)n * H_ + l] = 0.0f;
    h_new[(size_t)n * H_ + 64 + l] = 0.0f;
    float s = v0 + v1;
    #pragma unroll
    for (int off = 32; off; off >>= 1) s += __shfl_xor(s, off);
    float mean = s * (1.0f / H_);
    float d0 = v0 - mean, d1 = v1 - mean;
    float vs = d0 * d0 + d1 * d1;
    #pragma unroll
    for (int off = 32; off; off >>= 1) vs += __shfl_xor(vs, off);
    float rstd = rsqrtf(vs * (1.0f / H_) + 1e-5f);
    const float* gg = ln_g + (size_t)li * H_;
    const float* bb = ln_b + (size_t)li * H_;
    float t0 = gelu_exact(d0 * rstd * gg[l] + bb[l]);
    float t1 = gelu_exact(d1 * rstd * gg[64 + l] + bb[64 + l]);
    size_t o = (size_t)n * H_;
    if (li == 0) { h[o + l] = t0; h[o + 64 + l] = t1; }
    else         { h[o + l] += t0; h[o + 64 + l] += t1; }
}

// ---------------- temporal: positional encoding add ----------------

__global__ void k_peadd(float* __restrict__ h) {
    int i = blockIdx.x * blockDim.x + threadIdx.x;
    int stride = gridDim.x * blockDim.x;
    for (; i < N_ * H_; i += stride) {
        int j = i & 127;
        int t = (i >> 7) & 63;
        float dv = __expf((float)(j & ~1) * (-0.0719557841560639f));
        float ang = (float)t * dv;
        float pe = (j & 1) ? cosf(ang) : sinf(ang);
        h[i] += pe;
    }
}

// ---------------- temporal qkv GEMM (fp16/fdot2) ----------------

__global__ __launch_bounds__(256) void k_tqkv(const float* __restrict__ hs,
                                              const float* __restrict__ t_in_w, const float* __restrict__ t_in_b,
                                              float* __restrict__ qc, float* __restrict__ kc, float* __restrict__ vc,
                                              int li, int c0) {
    int nb = blockIdx.x;
    int nt = blockIdx.y;
    int node = c0 + nb;
    __shared__ hh2 s_ah[64 * 67];
    __shared__ hh2 s_bh[16 * 132];
    int tid = threadIdx.x;
    #pragma unroll
    for (int i = 0; i < 8; ++i) {
        int idx = i * 256 + tid;
        int r = idx >> 5, c4i = idx & 31;
        float4 v = *reinterpret_cast<const float4*>(&hs[((size_t)node * 64 + r) * 128 + c4i * 4]);
        s_ah[r * 67 + c4i * 2]     = f2h2(v.x, v.y);
        s_ah[r * 67 + c4i * 2 + 1] = f2h2(v.z, v.w);
    }
    const float* B = t_in_w + ((size_t)li * 384 + nt * 128) * 128;
    const float* bi = t_in_b + (size_t)li * 384 + nt * 128;
    int rg = tid >> 4, cg = tid & 15;
    int r0 = rg * 4;
    float4 alo[4], ahi[4];
    #pragma unroll
    for (int rr = 0; rr < 4; ++rr) { alo[rr] = f4zero(); ahi[rr] = f4zero(); }
    for (int kci = 0; kci < 4; ++kci) {
        __syncthreads();
        #pragma unroll
        for (int i = 0; i < 4; ++i) {
            int idx = i * 256 + tid;
            int jj = idx >> 3, k4 = (idx & 7) * 4;
            float4 w = *reinterpret_cast<const float4*>(&B[(size_t)jj * 128 + kci * 32 + k4]);
            int k2 = k4 >> 1;
            s_bh[k2 * 132 + jj]       = f2h2(w.x, w.y);
            s_bh[(k2 + 1) * 132 + jj] = f2h2(w.z, w.w);
        }
        __syncthreads();
        #pragma unroll
        for (int k2 = 0; k2 < 16; ++k2) {
            hh2 a2[4];
            #pragma unroll
            for (int rr = 0; rr < 4; ++rr) a2[rr] = s_ah[(r0 + rr) * 67 + kci * 16 + k2];
            U4H2 bl, bh_;
            bl.f  = *reinterpret_cast<const float4*>(&s_bh[k2 * 132 + cg * 4]);
            bh_.f = *reinterpret_cast<const float4*>(&s_bh[k2 * 132 + 64 + cg * 4]);
            #pragma unroll
            for (int rr = 0; rr < 4; ++rr) {
                alo[rr].x = FDOT2(a2[rr], bl.h[0], alo[rr].x);
                alo[rr].y = FDOT2(a2[rr], bl.h[1], alo[rr].y);
                alo[rr].z = FDOT2(a2[rr], bl.h[2], alo[rr].z);
                alo[rr].w = FDOT2(a2[rr], bl.h[3], alo[rr].w);
                ahi[rr].x = FDOT2(a2[rr], bh_.h[0], ahi[rr].x);
                ahi[rr].y = FDOT2(a2[rr], bh_.h[1], ahi[rr].y);
                ahi[rr].z = FDOT2(a2[rr], bh_.h[2], ahi[rr].z);
                ahi[rr].w = FDOT2(a2[rr], bh_.h[3], ahi[rr].w);
            }
        }
    }
    float* dst = (nt == 0) ? qc : (nt == 1) ? kc : vc;
    float sc = (nt == 0) ? SCALE_ : 1.0f;
    float4 blo = *reinterpret_cast<const float4*>(&bi[cg * 4]);
    float4 bhi = *reinterpret_cast<const float4*>(&bi[64 + cg * 4]);
    #pragma unroll
    for (int rr = 0; rr < 4; ++rr) {
        float4 lo = alo[rr], hi = ahi[rr];
        lo.x = (lo.x + blo.x) * sc; lo.y = (lo.y + blo.y) * sc; lo.z = (lo.z + blo.z) * sc; lo.w = (lo.w + blo.w) * sc;
        hi.x = (hi.x + bhi.x) * sc; hi.y = (hi.y + bhi.y) * sc; hi.z = (hi.z + bhi.z) * sc; hi.w = (hi.w + bhi.w) * sc;
        size_t row = (size_t)nb * 64 + r0 + rr;
        *reinterpret_cast<float4*>(&dst[row * 128 + cg * 4]) = lo;
        *reinterpret_cast<float4*>(&dst[row * 128 + 64 + cg * 4]) = hi;
    }
}

// ---------------- temporal attention (fp32) ----------------

__global__ __launch_bounds__(64) void k_tattn(float* __restrict__ qc, const float* __restrict__ kc,
                                              const float* __restrict__ vc) {
    int nb = blockIdx.x, head = blockIdx.y;
    __shared__ float s_k[64 * 36];
    __shared__ float s_v[64 * 36];
    int t = threadIdx.x;
    #pragma unroll
    for (int i = 0; i < 8; ++i) {
        int idx = i * 64 + t;
        int row = idx >> 3, d4 = (idx & 7) * 4;
        *reinterpret_cast<float4*>(&s_k[row * 36 + d4]) =
            *reinterpret_cast<const float4*>(&kc[((size_t)nb * 64 + row) * 128 + head * DH_ + d4]);
        *reinterpret_cast<float4*>(&s_v[row * 36 + d4]) =
            *reinterpret_cast<const float4*>(&vc[((size_t)nb * 64 + row) * 128 + head * DH_ + d4]);
    }
    float4 q[8];
    {
        const float4* qr = reinterpret_cast<const float4*>(&qc[((size_t)nb * 64 + t) * 128 + head * DH_]);
        #pragma unroll
        for (int i = 0; i < 8; ++i) q[i] = qr[i];
    }
    __syncthreads();
    float m = -1e30f;
    for (int t2 = 0; t2 < 64; ++t2) {
        const float4* kr = reinterpret_cast<const float4*>(&s_k[t2 * 36]);
        float s0 = 0, s1 = 0, s2 = 0, s3 = 0;
        #pragma unroll
        for (int i = 0; i < 8; ++i) {
            float4 kk = kr[i];
            s0 += q[i].x * kk.x; s1 += q[i].y * kk.y; s2 += q[i].z * kk.z; s3 += q[i].w * kk.w;
        }
        m = fmaxf(m, (s0 + s1) + (s2 + s3));
    }
    float ssum = 0.0f;
    float4 o[8];
    #pragma unroll
    for (int i = 0; i < 8; ++i) o[i] = f4zero();
    for (int t2 = 0; t2 < 64; ++t2) {
        const float4* kr = reinterpret_cast<const float4*>(&s_k[t2 * 36]);
        float s0 = 0, s1 = 0, s2 = 0, s3 = 0;
        #pragma unroll
        for (int i = 0; i < 8; ++i) {
            float4 kk = kr[i];
            s0 += q[i].x * kk.x; s1 += q[i].y * kk.y; s2 += q[i].z * kk.z; s3 += q[i].w * kk.w;
        }
        float p = __expf((s0 + s1) + (s2 + s3) - m);
        ssum += p;
        const float4* vr = reinterpret_cast<const float4*>(&s_v[t2 * 36]);
        #pragma unroll
        for (int i = 0; i < 8; ++i) f4fma(o[i], p, vr[i]);
    }
    float inv = 1.0f / ssum;
    float4* orow = reinterpret_cast<float4*>(&qc[((size_t)nb * 64 + t) * 128 + head * DH_]);
    #pragma unroll
    for (int i = 0; i < 8; ++i) { float4 v = o[i]; f4scale(v, inv); orow[i] = v; }
}

// ---------------- temporal out-proj (fp16/fdot2) + residual + LN1 ----------------

__global__ __launch_bounds__(256) void k_toutln(const float* __restrict__ oc, float* __restrict__ hs,
                                                const float* __restrict__ t_out_w, const float* __restrict__ t_out_b,
                                                const float* __restrict__ ln_g, const float* __restrict__ ln_b,
                                                int li, int c0) {
    int nb = blockIdx.x;
    int node = c0 + nb;
    __shared__ hh2 s_ah[64 * 67];
    __shared__ hh2 s_bh[16 * 132];
    int tid = threadIdx.x;
    #pragma unroll
    for (int i = 0; i < 8; ++i) {
        int idx = i * 256 + tid;
        int r = idx >> 5, c4i = idx & 31;
        float4 v = *reinterpret_cast<const float4*>(&oc[((size_t)nb * 64 + r) * 128 + c4i * 4]);
        s_ah[r * 67 + c4i * 2]     = f2h2(v.x, v.y);
        s_ah[r * 67 + c4i * 2 + 1] = f2h2(v.z, v.w);
    }
    const float* B = t_out_w + (size_t)li * 128 * 128;
    const float* bo = t_out_b + (size_t)li * 128;
    int rg = tid >> 4, cg = tid & 15;
    int r0 = rg * 4;
    float4 alo[4], ahi[4];
    #pragma unroll
    for (int rr = 0; rr < 4; ++rr) { alo[rr] = f4zero(); ahi[rr] = f4zero(); }
    for (int kci = 0; kci < 4; ++kci) {
        __syncthreads();
        #pragma unroll
        for (int i = 0; i < 4; ++i) {
            int idx = i * 256 + tid;
            int jj = idx >> 3, k4 = (idx & 7) * 4;
            float4 w = *reinterpret_cast<const float4*>(&B[(size_t)jj * 128 + kci * 32 + k4]);
            int k2 = k4 >> 1;
            s_bh[k2 * 132 + jj]       = f2h2(w.x, w.y);
            s_bh[(k2 + 1) * 132 + jj] = f2h2(w.z, w.w);
        }
        __syncthreads();
        #pragma unroll
        for (int k2 = 0; k2 < 16; ++k2) {
            hh2 a2[4];
            #pragma unroll
            for (int rr = 0; rr < 4; ++rr) a2[rr] = s_ah[(r0 + rr) * 67 + kci * 16 + k2];
            U4H2 bl, bh_;
            bl.f  = *reinterpret_cast<const float4*>(&s_bh[k2 * 132 + cg * 4]);
            bh_.f = *reinterpret_cast<const float4*>(&s_bh[k2 * 132 + 64 + cg * 4]);
            #pragma unroll
            for (int rr = 0; rr < 4; ++rr) {
                alo[rr].x = FDOT2(a2[rr], bl.h[0], alo[rr].x);
                alo[rr].y = FDOT2(a2[rr], bl.h[1], alo[rr].y);
                alo[rr].z = FDOT2(a2[rr], bl.h[2], alo[rr].z);
                alo[rr].w = FDOT2(a2[rr], bl.h[3], alo[rr].w);
                ahi[rr].x = FDOT2(a2[rr], bh_.h[0], ahi[rr].x);
                ahi[rr].y = FDOT2(a2[rr], bh_.h[1], ahi[rr].y);
                ahi[rr].z = FDOT2(a2[rr], bh_.h[2], ahi[rr].z);
                ahi[rr].w = FDOT2(a2[rr], bh_.h[3], ahi[rr].w);
            }
        }
    }
    float4 bblo = *reinterpret_cast<const float4*>(&bo[cg * 4]);
    float4 bbhi = *reinterpret_cast<const float4*>(&bo[64 + cg * 4]);
    float4 glo = *reinterpret_cast<const float4*>(&ln_g[(size_t)li * 128 + cg * 4]);
    float4 ghi = *reinterpret_cast<const float4*>(&ln_g[(size_t)li * 128 + 64 + cg * 4]);
    float4 lblo = *reinterpret_cast<const float4*>(&ln_b[(size_t)li * 128 + cg * 4]);
    float4 lbhi = *reinterpret_cast<const float4*>(&ln_b[(size_t)li * 128 + 64 + cg * 4]);
    #pragma unroll
    for (int rr = 0; rr < 4; ++rr) {
        size_t row = (size_t)node * 64 + r0 + rr;
        float4 rlo = *reinterpret_cast<const float4*>(&hs[row * 128 + cg * 4]);
        float4 rhi = *reinterpret_cast<const float4*>(&hs[row * 128 + 64 + cg * 4]);
        float4 lo = alo[rr], hi = ahi[rr];
        lo.x += bblo.x + rlo.x; lo.y += bblo.y + rlo.y; lo.z += bblo.z + rlo.z; lo.w += bblo.w + rlo.w;
        hi.x += bbhi.x + rhi.x; hi.y += bbhi.y + rhi.y; hi.z += bbhi.z + rhi.z; hi.w += bbhi.w + rhi.w;
        float s = lo.x + lo.y + lo.z + lo.w + hi.x + hi.y + hi.z + hi.w;
        s += __shfl_xor(s, 1); s += __shfl_xor(s, 2); s += __shfl_xor(s, 4); s += __shfl_xor(s, 8);
        float mean = s * (1.0f / 128.0f);
        float4 dlo = make_float4(lo.x - mean, lo.y - mean, lo.z - mean, lo.w - mean);
        float4 dhi = make_float4(hi.x - mean, hi.y - mean, hi.z - mean, hi.w - mean);
        float vx = dlo.x * dlo.x + dlo.y * dlo.y + dlo.z * dlo.z + dlo.w * dlo.w +
                   dhi.x * dhi.x + dhi.y * dhi.y + dhi.z * dhi.z + dhi.w * dhi.w;
        vx += __shfl_xor(vx, 1); vx += __shfl_xor(vx, 2); vx += __shfl_xor(vx, 4); vx += __shfl_xor(vx, 8);
        float rstd = rsqrtf(vx * (1.0f / 128.0f) + 1e-5f);
        float4 olo = make_float4(dlo.x * rstd * glo.x + lblo.x, dlo.y * rstd * glo.y + lblo.y,
                                 dlo.z * rstd * glo.z + lblo.z, dlo.w * rstd * glo.w + lblo.w);
        float4 ohi = make_float4(dhi.x * rstd * ghi.x + lbhi.x, dhi.y * rstd * ghi.y + lbhi.y,
                                 dhi.z * rstd * ghi.z + lbhi.z, dhi.w * rstd * ghi.w + lbhi.w);
        *reinterpret_cast<float4*>(&hs[row * 128 + cg * 4]) = olo;
        *reinterpret_cast<float4*>(&hs[row * 128 + 64 + cg * 4]) = ohi;
    }
}

// ---------------- temporal fused FF via MFMA (f16 in, fp32 accum) + residual + LN2 ----------------

__global__ __launch_bounds__(256) void k_tff(float* __restrict__ hs,
                                             const float* __restrict__ t_w1, const float* __restrict__ t_b1,
                                             const float* __restrict__ t_w2, const float* __restrict__ t_b2,
                                             const float* __restrict__ ln_g, const float* __restrict__ ln_b,
                                             int li) {
    int node = blockIdx.x;
    __shared__ __half s_xh[64 * 136];
    __shared__ __half s_wh[128 * 136];
    __shared__ __half s_fh[64 * 136];
    int tid = threadIdx.x;
    int w = tid >> 6, l = tid & 63;
    int lr = l & 15, lk = l >> 4;

    #pragma unroll
    for (int i = 0; i < 8; ++i) {
        int idx = i * 256 + tid;
        int r = idx >> 5, c4 = idx & 31;
        float4 v = *reinterpret_cast<const float4*>(&hs[((size_t)node * 64 + r) * 128 + c4 * 4]);
        __half2* dst = reinterpret_cast<__half2*>(&s_xh[r * 136 + c4 * 4]);
        dst[0] = __floats2half2_rn(v.x, v.y);
        dst[1] = __floats2half2_rn(v.z, v.w);
    }
    const float* W1 = t_w1 + (size_t)li * FF_ * 128;
    const float* b1 = t_b1 + (size_t)li * FF_;
    const float* W2 = t_w2 + (size_t)li * 128 * FF_;
    const float* b2 = t_b2 + (size_t)li * 128;

    f32x4 c2[8];
    #pragma unroll
    for (int ct = 0; ct < 8; ++ct) c2[ct] = (f32x4){0.f, 0.f, 0.f, 0.f};

    for (int nt = 0; nt < 4; ++nt) {
        __syncthreads();
        #pragma unroll
        for (int i = 0; i < 16; ++i) {
            int idx = i * 256 + tid;
            int r = idx >> 5, c4 = idx & 31;
            float4 v = *reinterpret_cast<const float4*>(&W1[(size_t)(nt * 128 + r) * 128 + c4 * 4]);
            __half2* dst = reinterpret_cast<__half2*>(&s_wh[r * 136 + c4 * 4]);
            dst[0] = __floats2half2_rn(v.x, v.y);
            dst[1] = __floats2half2_rn(v.z, v.w);
        }
        __syncthreads();
        f32x4 c1[8];
        #pragma unroll
        for (int ct = 0; ct < 8; ++ct) c1[ct] = (f32x4){0.f, 0.f, 0.f, 0.f};
        #pragma unroll
        for (int kk = 0; kk < 4; ++kk) {
            U4V8 a;
            a.f = *reinterpret_cast<const float4*>(&s_xh[(w * 16 + lr) * 136 + kk * 32 + lk * 8]);
            #pragma unroll
            for (int ct = 0; ct < 8; ++ct) {
                U4V8 b;
                b.f = *reinterpret_cast<const float4*>(&s_wh[(ct * 16 + lr) * 136 + kk * 32 + lk * 8]);
                c1[ct] = __builtin_amdgcn_mfma_f32_16x16x32_f16(a.v, b.v, c1[ct], 0, 0, 0);
            }
        }
        __syncthreads();
        #pragma unroll
        for (int ct = 0; ct < 8; ++ct) {
            float bb = b1[nt * 128 + ct * 16 + lr];
            #pragma unroll
            for (int reg = 0; reg < 4; ++reg) {
                float gv = gelu_exact(c1[ct][reg] + bb);
                s_fh[(w * 16 + lk * 4 + reg) * 136 + ct * 16 + lr] = (__half)gv;
            }
        }
        #pragma unroll
        for (int i = 0; i < 16; ++i) {
            int idx = i * 256 + tid;
            int r = idx >> 5, c4 = idx & 31;
            float4 v = *reinterpret_cast<const float4*>(&W2[(size_t)r * FF_ + nt * 128 + c4 * 4]);
            __half2* dst = reinterpret_cast<__half2*>(&s_wh[r * 136 + c4 * 4]);
            dst[0] = __floats2half2_rn(v.x, v.y);
            dst[1] = __floats2half2_rn(v.z, v.w);
        }
        __syncthreads();
        #pragma unroll
        for (int kk = 0; kk < 4; ++kk) {
            U4V8 a;
            a.f = *reinterpret_cast<const float4*>(&s_fh[(w * 16 + lr) * 136 + kk * 32 + lk * 8]);
            #pragma unroll
            for (int ct = 0; ct < 8; ++ct) {
                U4V8 b;
                b.f = *reinterpret_cast<const float4*>(&s_wh[(ct * 16 + lr) * 136 + kk * 32 + lk * 8]);
                c2[ct] = __builtin_amdgcn_mfma_f32_16x16x32_f16(a.v, b.v, c2[ct], 0, 0, 0);
            }
        }
    }
    float gval[8], lbv[8], b2v[8];
    #pragma unroll
    for (int ct = 0; ct < 8; ++ct) {
        int col = ct * 16 + lr;
        gval[ct] = ln_g[(size_t)li * 128 + col];
        lbv[ct]  = ln_b[(size_t)li * 128 + col];
        b2v[ct]  = b2[col];
    }
    #pragma unroll
    for (int reg = 0; reg < 4; ++reg) {
        int row = w * 16 + lk * 4 + reg;
        float vals[8];
        float s = 0.0f;
        #pragma unroll
        for (int ct = 0; ct < 8; ++ct) {
            float v = c2[ct][reg] + b2v[ct] + (float)s_xh[row * 136 + ct * 16 + lr];
            vals[ct] = v;
            s += v;
        }
        s += __shfl_xor(s, 1); s += __shfl_xor(s, 2); s += __shfl_xor(s, 4); s += __shfl_xor(s, 8);
        float mean = s * (1.0f / 128.0f);
        float vv = 0.0f;
        #pragma unroll
        for (int ct = 0; ct < 8; ++ct) { float d = vals[ct] - mean; vv += d * d; }
        vv += __shfl_xor(vv, 1); vv += __shfl_xor(vv, 2); vv += __shfl_xor(vv, 4); vv += __shfl_xor(vv, 8);
        float rstd = rsqrtf(vv * (1.0f / 128.0f) + 1e-5f);
        #pragma unroll
        for (int ct = 0; ct < 8; ++ct) {
            int col = ct * 16 + lr;
            hs[((size_t)node * 64 + row) * 128 + col] = (vals[ct] - mean) * rstd * gval[ct] + lbv[ct];
        }
    }
}

// ---------------- final LN -> out ----------------

__global__ __launch_bounds__(256) void k_fln(const float* __restrict__ hs, float* __restrict__ out,
                                             const float* __restrict__ g, const float* __restrict__ b) {
    int row = blockIdx.x * 4 + (threadIdx.x >> 6);
    int l = threadIdx.x & 63;
    float v0 = hs[(size_t)row * H_ + l];
    float v1 = hs[(size_t)row * H_ + 64 + l];
    float s = v0 + v1;
    #pragma unroll
    for (int off = 32; off; off >>= 1) s += __shfl_xor(s, off);
    float mean = s * (1.0f / H_);
    float d0 = v0 - mean, d1 = v1 - mean;
    float vs = d0 * d0 + d1 * d1;
    #pragma unroll
    for (int off = 32; off; off >>= 1) vs += __shfl_xor(vs, off);
    float rstd = rsqrtf(vs * (1.0f / H_) + 1e-5f);
    out[(size_t)row * H_ + l] = d0 * rstd * g[l] + b[l];
    out[(size_t)row * H_ + 64 + l] = d1 * rstd * g[64 + l] + b[64 + l];
}

// ---------------- launch ----------------

extern "C" void kernel_launch(void* const* d_in, const int* in_sizes, int n_in,
                              void* d_out, int out_size, void* d_ws, size_t ws_size,
                              hipStream_t stream) {
    const float* x          = (const float*)d_in[0];
    const int*   edge_index = (const int*)d_in[1];
    const int*   edge_type  = (const int*)d_in[2];
    const int*   node_type  = (const int*)d_in[3];
    const float* W_in    = (const float*)d_in[6];
    const float* b_in    = (const float*)d_in[7];
    const float* s_in_w  = (const float*)d_in[8];
    const float* s_in_b  = (const float*)d_in[9];
    const float* s_out_w = (const float*)d_in[10];
    const float* s_out_b = (const float*)d_in[11];
    const float* ln_s_g  = (const float*)d_in[12];
    const float* ln_s_b  = (const float*)d_in[13];
    const float* t_in_w  = (const float*)d_in[14];
    const float* t_in_b  = (const float*)d_in[15];
    const float* t_out_w = (const float*)d_in[16];
    const float* t_out_b = (const float*)d_in[17];
    const float* t_ln1_g = (const float*)d_in[18];
    const float* t_ln1_b = (const float*)d_in[19];
    const float* t_w1    = (const float*)d_in[20];
    const float* t_b1    = (const float*)d_in[21];
    const float* t_w2    = (const float*)d_in[22];
    const float* t_b2    = (const float*)d_in[23];
    const float* t_ln2_g = (const float*)d_in[24];
    const float* t_ln2_b = (const float*)d_in[25];
    const float* fin_g   = (const float*)d_in[26];
    const float* fin_b   = (const float*)d_in[27];
    float* out = (float*)d_out;

    // workspace layout (floats)
    float* h     = (float*)d_ws;                       // N*H = 8388608
    float* h_new = h + (size_t)N_ * H_;                // 8388608
    float* spat  = h_new + (size_t)N_ * H_;            // 11520000 float region
    __half* qh   = (__half*)spat;                      // E*128 halves
    __half* kvh  = (__half*)spat + (size_t)E_ * 128;   // E*256 halves
    int* sorted  = (int*)(spat + (size_t)E_ * 384);    // E
    int* gpos    = sorted + E_;                        // E
    int* gedge   = gpos + E_;                          // E
    int* cnt     = gedge + E_;                         // 64
    int* offs    = cnt + 64;                           // 64
    int* curs    = offs + 64;                          // 64
    int* nd64    = curs + 64;                          // 16
    int2* desc64 = (int2*)(nd64 + 16);                 // 544 int2

    // temporal chunk buffers (alias spat region + h_new, used after spatial completes)
    float* qc = spat;                                  // CH*64*128 = 4194304
    float* kc = spat + (size_t)CH_ * 64 * 128;         // 4194304
    float* vc = h_new;                                 // 4194304

    k_zero_cnt<<<1, 64, 0, stream>>>(cnt);
    k_hist<<<(E_ + 255) / 256, 256, 0, stream>>>(edge_index, edge_type, node_type, gedge, cnt);
    k_scan<<<1, 1, 0, stream>>>(cnt, offs, curs);
    k_scatter<<<(E_ + 255) / 256, 256, 0, stream>>>(gedge, curs, sorted, gpos);
    k_desc<<<1, 1, 0, stream>>>(offs, desc64, nd64);

    k_inproj<<<N_, 128, 0, stream>>>(x, node_type, W_in, b_in, h);

    k_zero<<<2048, 256, 0, stream>>>(h_new, N_ * H_);   // layer 0; later layers zeroed by k_lngelu
    for (int li = 0; li < L_; ++li) {
        k_sqkv_gemm<<<dim3(GATTN_GRID, 3), 256, 0, stream>>>(h, s_in_w, s_in_b, sorted, offs, edge_index,
                                                             desc64, nd64, qh, kvh, li);
        k_gattn<<<GATTN_GRID, 256, 0, stream>>>(qh, kvh, sorted, offs, edge_index, desc64, nd64,
                                                s_out_w, s_out_b, h_new, li);
        k_lngelu<<<N_ / 4, 256, 0, stream>>>(h_new, h, ln_s_g, ln_s_b, li);
    }

    // temporal: hs = h + PE (in place)
    k_peadd<<<2048, 256, 0, stream>>>(h);
    for (int li = 0; li < TL_; ++li) {
        for (int c = 0; c < NB_ / CH_; ++c) {
            int c0 = c * CH_;
            k_tqkv<<<dim3(CH_, 3), 256, 0, stream>>>(h, t_in_w, t_in_b, qc, kc, vc, li, c0);
            k_tattn<<<dim3(CH_, NH_), 64, 0, stream>>>(qc, kc, vc);
            k_toutln<<<CH_, 256, 0, stream>>>(qc, h, t_out_w, t_out_b, t_ln1_g, t_ln1_b, li, c0);
        }
        k_tff<<<NB_, 256, 0, stream>>>(h, t_w1, t_b1, t_w2, t_b2, t_ln2_g, t_ln2_b, li);
    }
    k_fln<<<N_ / 4, 256, 0, stream>>>(h, out, fin_g, fin_b);
}